// Round 1
// baseline (8205.270 us; speedup 1.0000x reference)
//
#include <hip/hip_runtime.h>
#include <cstdint>
#include <cstddef>

// Problem constants (match reference)
#define N_NODES 50000
#define N_EDGES 500000
// C = 128, NUM_TYPES = 32, DIM_TOK = 94, STEPS = 3, BLOCKS = 2, NUM_ET = 3

__device__ __forceinline__ float sigmoid_(float x) { return 1.f / (1.f + __expf(-x)); }
__device__ __forceinline__ float tanh_(float x) {
  float t = __expf(-2.f * fabsf(x));
  float r = (1.f - t) / (1.f + t);
  return copysignf(r, x);
}

// ---------------------------------------------------------------- features
// h[n][c]: c<32 one-hot type, 32..125 one-hot clamped token, 126..127 x_small
__global__ __launch_bounds__(256) void k_features(float* __restrict__ h,
    const int* __restrict__ xtype, const int* __restrict__ xtok,
    const float* __restrict__ xs) {
  int idx = blockIdx.x * 256 + threadIdx.x;
  if (idx >= N_NODES * 128) return;
  int n = idx >> 7, c = idx & 127;
  float v;
  if (c < 32) {
    v = (xtype[n] == c) ? 1.f : 0.f;
  } else if (c < 126) {
    int tk = xtok[n];
    tk = tk < 0 ? 0 : (tk > 93 ? 93 : tk);
    v = (tk == (c - 32)) ? 1.f : 0.f;
  } else {
    v = xs[n * 2 + (c - 126)];
  }
  h[idx] = v;
}

// ---------------------------------------------------------------- edge bucketing
// Wave-aggregated atomics: 3 atomics/wave instead of 64 (3 counters would
// otherwise serialize 500K atomic RMWs).
__global__ __launch_bounds__(256) void k_bucket(const int* __restrict__ ei,
    const int* __restrict__ et, int2* __restrict__ lists, int* __restrict__ cnt) {
  int e = blockIdx.x * 256 + threadIdx.x;
  int lane = threadIdx.x & 63;
  bool val = e < N_EDGES;
  int ty = val ? et[e] : -1;
  int2 edge = make_int2(0, 0);
  if (val) edge = make_int2(ei[e], ei[N_EDGES + e]);  // (src, dst)
  for (int tt = 0; tt < 3; ++tt) {
    unsigned long long mask = __ballot(ty == tt);
    if (mask == 0ull) continue;
    int leader = __ffsll((unsigned long long)mask) - 1;
    int cw = __popcll(mask);
    int base = 0;
    if (lane == leader) base = atomicAdd(&cnt[tt], cw);
    base = __shfl(base, leader);
    if (ty == tt) {
      int rank = __popcll(mask & ((1ull << lane) - 1ull));
      lists[(size_t)tt * N_EDGES + base + rank] = edge;
    }
  }
}

// ---------------------------------------------------------------- weight transpose
// src: count x [M][K] row-major  ->  dst: count x [K][M]  (k-major, j contiguous)
__global__ __launch_bounds__(256) void k_transpose(const float* __restrict__ src,
    float* __restrict__ dst, int M, int K, int count) {
  int idx = blockIdx.x * 256 + threadIdx.x;
  int per = M * K;
  if (idx >= count * per) return;
  int mat = idx / per, r = idx - mat * per;
  int j = r / K, k = r - j * K;
  dst[(size_t)mat * per + (size_t)k * M + j] = src[idx];
}

// ---------------------------------------------------------------- GEMM  out = A @ Wk (+bias)(+relu)
// Wk is k-major [128][128] (col j contiguous). lane = row, wave owns 32 cols.
// Weight addresses are wave-uniform (readfirstlane) -> s_load; inner loop is
// v_fmac_f32 v,s,v with no LDS.
__global__ __launch_bounds__(256) void k_gemm128(const float* __restrict__ A,
    const float* __restrict__ Wk, const float* __restrict__ bias,
    float* __restrict__ out, int nrows, int relu) {
  int wave = __builtin_amdgcn_readfirstlane((int)(threadIdx.x >> 6));
  int lane = threadIdx.x & 63;
  int n = blockIdx.x * 64 + lane;
  int jb = wave * 32;
  bool valid = n < nrows;
  const float* arow = A + (size_t)(valid ? n : 0) * 128;
  float acc[32];
#pragma unroll
  for (int j = 0; j < 32; ++j) acc[j] = 0.f;
  for (int kc = 0; kc < 128; kc += 8) {
    float a[8];
    *(float4*)(a)     = *(const float4*)(arow + kc);
    *(float4*)(a + 4) = *(const float4*)(arow + kc + 4);
#pragma unroll
    for (int kk = 0; kk < 8; ++kk) {
      const float* wr = Wk + (size_t)(kc + kk) * 128 + jb;
#pragma unroll
      for (int j = 0; j < 32; ++j) acc[j] += wr[j] * a[kk];
    }
  }
  if (valid) {
    float* orow = out + (size_t)n * 128 + jb;
#pragma unroll
    for (int j = 0; j < 32; j += 4) {
      float4 v;
      v.x = acc[j]; v.y = acc[j + 1]; v.z = acc[j + 2]; v.w = acc[j + 3];
      if (bias) { v.x += bias[jb+j]; v.y += bias[jb+j+1]; v.z += bias[jb+j+2]; v.w += bias[jb+j+3]; }
      if (relu) { v.x = fmaxf(v.x,0.f); v.y = fmaxf(v.y,0.f); v.z = fmaxf(v.z,0.f); v.w = fmaxf(v.w,0.f); }
      *(float4*)(orow + j) = v;
    }
  }
}

// ---------------------------------------------------------------- scatter-add
// agg[dst] += x[src] over this type's edge list. 2 edges per 256-thread block-iter.
__global__ __launch_bounds__(256) void k_scatter(const int2* __restrict__ list,
    const int* __restrict__ cntp, const float* __restrict__ x,
    float* __restrict__ agg) {
  int cnt = *cntp;
  int half = threadIdx.x >> 7;
  int c = threadIdx.x & 127;
  for (int i = blockIdx.x * 2 + half; i < cnt; i += gridDim.x * 2) {
    int2 e = list[i];
    float v = x[(size_t)e.x * 128 + c];
    atomicAdd(agg + (size_t)e.y * 128 + c, v);
  }
}

// ---------------------------------------------------------------- fused GRU cell
// m_new = (1-z)*tanh(gi_n + r*gh_n) + z*h_old, gates (r,z,n).
// wiT/whT are k-major [128][384]. If last step: total += m_new (m not written).
__global__ __launch_bounds__(256) void k_gru(const float* __restrict__ agg,
    const float* __restrict__ hprev, const float* __restrict__ wiT,
    const float* __restrict__ whT, const float* __restrict__ bi,
    const float* __restrict__ bh, float* __restrict__ mout,
    float* __restrict__ total, int last, int nrows) {
  int wave = __builtin_amdgcn_readfirstlane((int)(threadIdx.x >> 6));
  int lane = threadIdx.x & 63;
  int n = blockIdx.x * 64 + lane;
  int jb = wave * 32;
  bool valid = n < nrows;
  const float* ar = agg + (size_t)(valid ? n : 0) * 128;
  const float* hr = hprev + (size_t)(valid ? n : 0) * 128;

  float rg[32], zg[32];
  for (int g = 0; g < 3; ++g) {
    float ai[32], ah[32];
#pragma unroll
    for (int j = 0; j < 32; ++j) { ai[j] = 0.f; ah[j] = 0.f; }
    for (int kc = 0; kc < 128; kc += 8) {
      float a[8], bbv[8];
      *(float4*)(a)       = *(const float4*)(ar + kc);
      *(float4*)(a + 4)   = *(const float4*)(ar + kc + 4);
      *(float4*)(bbv)     = *(const float4*)(hr + kc);
      *(float4*)(bbv + 4) = *(const float4*)(hr + kc + 4);
#pragma unroll
      for (int kk = 0; kk < 8; ++kk) {
        const float* wi = wiT + (size_t)(kc + kk) * 384 + g * 128 + jb;
        const float* wh = whT + (size_t)(kc + kk) * 384 + g * 128 + jb;
#pragma unroll
        for (int j = 0; j < 32; ++j) {
          ai[j] += wi[j] * a[kk];
          ah[j] += wh[j] * bbv[kk];
        }
      }
    }
    if (g == 0) {
#pragma unroll
      for (int j = 0; j < 32; ++j)
        rg[j] = sigmoid_(ai[j] + bi[jb + j] + ah[j] + bh[jb + j]);
    } else if (g == 1) {
#pragma unroll
      for (int j = 0; j < 32; ++j)
        zg[j] = sigmoid_(ai[j] + bi[128 + jb + j] + ah[j] + bh[128 + jb + j]);
    } else {
      float hold[32];
#pragma unroll
      for (int j = 0; j < 32; j += 4)
        *(float4*)(hold + j) = *(const float4*)(hr + jb + j);
      if (valid) {
        if (!last) {
          float* orow = mout + (size_t)n * 128 + jb;
#pragma unroll
          for (int j = 0; j < 32; j += 4) {
            float4 v;
#pragma unroll
            for (int q = 0; q < 4; ++q) {
              float nt = tanh_(ai[j+q] + bi[256 + jb + j+q] + rg[j+q] * (ah[j+q] + bh[256 + jb + j+q]));
              ((float*)&v)[q] = (1.f - zg[j+q]) * nt + zg[j+q] * hold[j+q];
            }
            *(float4*)(orow + j) = v;
          }
        } else {
          float* trow = total + (size_t)n * 128 + jb;
#pragma unroll
          for (int j = 0; j < 32; ++j) {
            float nt = tanh_(ai[j] + bi[256 + jb + j] + rg[j] * (ah[j] + bh[256 + jb + j]));
            trow[j] += (1.f - zg[j]) * nt + zg[j] * hold[j];
          }
        }
      }
    }
  }
}

// ---------------------------------------------------------------- LayerNorm + ReLU (in-place on h)
// One node per wave; lane covers 2 channels; shuffle reduction (no LDS).
__global__ __launch_bounds__(256) void k_ln(float* __restrict__ h,
    const float* __restrict__ total, const float* __restrict__ gamma,
    const float* __restrict__ beta, int nrows) {
  int wave = threadIdx.x >> 6, lane = threadIdx.x & 63;
  int n = blockIdx.x * 4 + wave;
  if (n >= nrows) return;
  size_t base = (size_t)n * 128;
  float v0 = h[base + lane] + total[base + lane];
  float v1 = h[base + 64 + lane] + total[base + 64 + lane];
  float s = v0 + v1, sq = v0 * v0 + v1 * v1;
#pragma unroll
  for (int off = 32; off > 0; off >>= 1) {
    s += __shfl_xor(s, off);
    sq += __shfl_xor(sq, off);
  }
  float mu = s * 0.0078125f;                     // /128
  float var = sq * 0.0078125f - mu * mu;         // biased var (matches jnp.var)
  float rs = rsqrtf(var + 1e-5f);
  float o0 = (v0 - mu) * rs * gamma[lane] + beta[lane];
  float o1 = (v1 - mu) * rs * gamma[64 + lane] + beta[64 + lane];
  h[base + lane] = fmaxf(o0, 0.f);
  h[base + 64 + lane] = fmaxf(o1, 0.f);
}

// ---------------------------------------------------------------- head layer 2
// out[n][o] = sum_j z[n][j] * w2[o][j] + b2[o], o in {0,1}
__global__ __launch_bounds__(256) void k_head2(const float* __restrict__ z,
    const float* __restrict__ w2, const float* __restrict__ b2,
    float* __restrict__ out, int nrows) {
  __shared__ float w[256];
  w[threadIdx.x] = w2[threadIdx.x];
  __syncthreads();
  int t = blockIdx.x * 256 + threadIdx.x;
  int n = t >> 1, o = t & 1;
  if (n >= nrows) return;
  const float* zr = z + (size_t)n * 128;
  const float* wr = w + o * 128;
  float acc = 0.f;
  for (int k = 0; k < 128; k += 4) {
    float4 zv = *(const float4*)(zr + k);
    acc += zv.x * wr[k] + zv.y * wr[k+1] + zv.z * wr[k+2] + zv.w * wr[k+3];
  }
  out[(size_t)n * 2 + o] = acc + b2[o];
}

// ================================================================ launch
extern "C" void kernel_launch(void* const* d_in, const int* in_sizes, int n_in,
                              void* d_out, int out_size, void* d_ws, size_t ws_size,
                              hipStream_t stream) {
  const int*   x_type  = (const int*)d_in[0];
  const int*   x_tok   = (const int*)d_in[1];
  const float* x_small = (const float*)d_in[2];
  const int*   eidx    = (const int*)d_in[3];
  const int*   etype   = (const int*)d_in[4];
  const float* conv_w  = (const float*)d_in[5];
  const float* gwih    = (const float*)d_in[6];
  const float* gwhh    = (const float*)d_in[7];
  const float* gbih    = (const float*)d_in[8];
  const float* gbhh    = (const float*)d_in[9];
  const float* ln_g    = (const float*)d_in[10];
  const float* ln_b    = (const float*)d_in[11];
  const float* hw1     = (const float*)d_in[12];
  const float* hb1     = (const float*)d_in[13];
  const float* hw2     = (const float*)d_in[14];
  const float* hb2     = (const float*)d_in[15];
  float* out = (float*)d_out;

  const size_t NC = (size_t)N_NODES * 128;
  float* Wb    = (float*)d_ws;
  float* h     = Wb;
  float* m     = Wb + NC;
  float* xb    = Wb + 2 * NC;        // conv output; reused as head1 output
  float* agg   = Wb + 3 * NC;
  float* total = Wb + 4 * NC;
  int*   cnt   = (int*)(Wb + 5 * NC);
  int2*  lists = (int2*)(cnt + 4);                       // 3 * E int2
  float* wihT  = (float*)(cnt + 4 + 6 * N_EDGES);        // 6 x [128][384]
  float* whhT  = wihT + 6 * 384 * 128;
  float* w1T   = whhT + 6 * 384 * 128;                   // [128][128]

  // features + edge bucketing + weight transposes (once per call)
  k_features<<<(N_NODES * 128 + 255) / 256, 256, 0, stream>>>(h, x_type, x_tok, x_small);
  hipMemsetAsync(cnt, 0, 16, stream);
  k_bucket<<<(N_EDGES + 255) / 256, 256, 0, stream>>>(eidx, etype, lists, cnt);
  {
    int tot = 6 * 384 * 128;
    k_transpose<<<(tot + 255) / 256, 256, 0, stream>>>(gwih, wihT, 384, 128, 6);
    k_transpose<<<(tot + 255) / 256, 256, 0, stream>>>(gwhh, whhT, 384, 128, 6);
    k_transpose<<<(128 * 128 + 255) / 256, 256, 0, stream>>>(hw1, w1T, 128, 128, 1);
  }

  int gblk = (N_NODES + 63) / 64;
  for (int b = 0; b < 2; ++b) {
    hipMemsetAsync(total, 0, NC * sizeof(float), stream);
    for (int t = 0; t < 3; ++t) {
      for (int s = 0; s < 3; ++s) {
        const float* A = (s == 0) ? h : m;  // m = h at step 0 (no copy)
        const float* cw = conv_w + (size_t)((b * 3 + t) * 3 + s) * 16384;
        k_gemm128<<<gblk, 256, 0, stream>>>(A, cw, nullptr, xb, N_NODES, 0);
        hipMemsetAsync(agg, 0, NC * sizeof(float), stream);
        k_scatter<<<2048, 256, 0, stream>>>(lists + (size_t)t * N_EDGES, cnt + t, xb, agg);
        const float* wi = wihT + (size_t)(b * 3 + t) * 49152;
        const float* wh = whhT + (size_t)(b * 3 + t) * 49152;
        const float* bi = gbih + (size_t)(b * 3 + t) * 384;
        const float* bh = gbhh + (size_t)(b * 3 + t) * 384;
        k_gru<<<gblk, 256, 0, stream>>>(agg, A, wi, wh, bi, bh, m, total,
                                        (s == 2) ? 1 : 0, N_NODES);
      }
    }
    k_ln<<<(N_NODES + 3) / 4, 256, 0, stream>>>(h, total, ln_g + b * 128, ln_b + b * 128, N_NODES);
  }
  // head: z = relu(h @ w1.T + b1); out = z @ w2.T + b2
  k_gemm128<<<gblk, 256, 0, stream>>>(h, w1T, hb1, xb, N_NODES, 1);
  k_head2<<<(2 * N_NODES + 255) / 256, 256, 0, stream>>>(xb, hw2, hb2, out, N_NODES);
}

// Round 2
// 3879.633 us; speedup vs baseline: 2.1150x; 2.1150x over previous
//
#include <hip/hip_runtime.h>
#include <cstdint>
#include <cstddef>

// Problem constants (match reference)
#define N_NODES 50000
#define N_EDGES 500000
// C = 128, STEPS = 3, BLOCKS = 2, NUM_ET = 3

typedef _Float16 half8 __attribute__((ext_vector_type(8)));
typedef float floatx4 __attribute__((ext_vector_type(4)));

__device__ __forceinline__ float sigmoid_(float x) { return 1.f / (1.f + __expf(-x)); }
__device__ __forceinline__ float tanh_(float x) {
  float t = __expf(-2.f * fabsf(x));
  float r = (1.f - t) / (1.f + t);
  return copysignf(r, x);
}

// ---------------------------------------------------------------- features
__global__ __launch_bounds__(256) void k_features(float* __restrict__ h,
    const int* __restrict__ xtype, const int* __restrict__ xtok,
    const float* __restrict__ xs) {
  int idx = blockIdx.x * 256 + threadIdx.x;
  if (idx >= N_NODES * 128) return;
  int n = idx >> 7, c = idx & 127;
  float v;
  if (c < 32) {
    v = (xtype[n] == c) ? 1.f : 0.f;
  } else if (c < 126) {
    int tk = xtok[n];
    tk = tk < 0 ? 0 : (tk > 93 ? 93 : tk);
    v = (tk == (c - 32)) ? 1.f : 0.f;
  } else {
    v = xs[n * 2 + (c - 126)];
  }
  h[idx] = v;
}

// ---------------------------------------------------------------- edge bucketing
__global__ __launch_bounds__(256) void k_bucket(const int* __restrict__ ei,
    const int* __restrict__ et, int2* __restrict__ lists, int* __restrict__ cnt) {
  int e = blockIdx.x * 256 + threadIdx.x;
  int lane = threadIdx.x & 63;
  bool val = e < N_EDGES;
  int ty = val ? et[e] : -1;
  int2 edge = make_int2(0, 0);
  if (val) edge = make_int2(ei[e], ei[N_EDGES + e]);  // (src, dst)
  for (int tt = 0; tt < 3; ++tt) {
    unsigned long long mask = __ballot(ty == tt);
    if (mask == 0ull) continue;
    int leader = __ffsll((unsigned long long)mask) - 1;
    int cw = __popcll(mask);
    int base = 0;
    if (lane == leader) base = atomicAdd(&cnt[tt], cw);
    base = __shfl(base, leader);
    if (ty == tt) {
      int rank = __popcll(mask & ((1ull << lane) - 1ull));
      int slot = base + rank;
      if (slot < N_EDGES)  // guard against rocprof replay double-count corruption
        lists[(size_t)tt * N_EDGES + slot] = edge;
    }
  }
}

// ---------------------------------------------------------------- weight fragment prep
// B-fragment layout for v_mfma_f32_16x16x32_f16:
//   frag[(kc*CT + ct)*64 + lane][j] = W[k = kc*32 + (lane>>4)*8 + j][n = ct*16 + (lane&15)]
// Each lane's 8 halfs contiguous (16B) -> one global_load_dwordx4 per frag.

// r,z gates: combined K=256 ([wih.T ; whh.T]), N=256 (cols 0..255 of the 384 = r,z)
__global__ __launch_bounds__(256) void k_prep_rz(const float* __restrict__ wih,
    const float* __restrict__ whh, _Float16* __restrict__ dst) {
  int idx = blockIdx.x * 256 + threadIdx.x;
  if (idx >= 6 * 8 * 16 * 512) return;
  int j = idx & 7, lane = (idx >> 3) & 63, ct = (idx >> 9) & 15, kc = (idx >> 13) & 7, bt = idx >> 16;
  int k = (kc & 3) * 32 + ((lane >> 4) & 3) * 8 + j;   // local k in [0,128)
  int n = ct * 16 + (lane & 15);                       // n in [0,256): r then z cols
  const float* src = (kc < 4) ? wih : whh;             // wih.T[k][n] = wih[n][k]
  dst[idx] = (_Float16)src[((size_t)bt * 384 + n) * 128 + k];
}

// n gate: gi_n needs wih.T cols 256..383 (K=128); gh_n needs whh.T cols 256..383
__global__ __launch_bounds__(256) void k_prep_n(const float* __restrict__ wih,
    const float* __restrict__ whh, _Float16* __restrict__ di, _Float16* __restrict__ dh) {
  int idx = blockIdx.x * 256 + threadIdx.x;
  if (idx >= 6 * 4 * 8 * 512) return;
  int j = idx & 7, lane = (idx >> 3) & 63, ct = (idx >> 9) & 7, kc = (idx >> 12) & 3, bt = idx >> 14;
  int k = kc * 32 + ((lane >> 4) & 3) * 8 + j;
  int n = 256 + ct * 16 + (lane & 15);
  di[idx] = (_Float16)wih[((size_t)bt * 384 + n) * 128 + k];
  dh[idx] = (_Float16)whh[((size_t)bt * 384 + n) * 128 + k];
}

// conv weights: 18 matrices [128 k][128 n], row-major (used as m @ W)
__global__ __launch_bounds__(256) void k_prep_conv(const float* __restrict__ cw,
    _Float16* __restrict__ dst) {
  int idx = blockIdx.x * 256 + threadIdx.x;
  if (idx >= 18 * 4 * 8 * 512) return;
  int j = idx & 7, lane = (idx >> 3) & 63, ct = (idx >> 9) & 7, kc = (idx >> 12) & 3, w = idx >> 14;
  int k = kc * 32 + ((lane >> 4) & 3) * 8 + j;
  int n = ct * 16 + (lane & 15);
  dst[idx] = (_Float16)cw[(size_t)w * 16384 + k * 128 + n];
}

// head w1: z = h @ w1.T  ->  B[k][n] = hw1[n*128 + k]
__global__ __launch_bounds__(256) void k_prep_w1(const float* __restrict__ hw1,
    _Float16* __restrict__ dst) {
  int idx = blockIdx.x * 256 + threadIdx.x;
  if (idx >= 4 * 8 * 512) return;
  int j = idx & 7, lane = (idx >> 3) & 63, ct = (idx >> 9) & 7, kc = (idx >> 12) & 3;
  int k = kc * 32 + ((lane >> 4) & 3) * 8 + j;
  int n = ct * 16 + (lane & 15);
  dst[idx] = (_Float16)hw1[n * 128 + k];
}

// ---------------------------------------------------------------- MFMA GEMM [N x 128] = A(f32) @ Wfrag
// Block = 4 waves, 64 rows; wave = 16 rows x 128 cols (8 col-tiles).
// A-frag: m = lane&15, k = quad*8 + j (load 8 f32, cvt f16 in reg). No LDS.
__global__ __launch_bounds__(256, 4) void k_gemm_mfma(const float* __restrict__ A,
    const _Float16* __restrict__ Wf, const float* __restrict__ bias,
    float* __restrict__ out, int relu, int nrows) {
  int wave = threadIdx.x >> 6, lane = threadIdx.x & 63;
  int quad = lane >> 4, l16 = lane & 15;
  int rbase = blockIdx.x * 64 + wave * 16;
  int arow = rbase + l16; if (arow >= nrows) arow = nrows - 1;
  const half8* wf = (const half8*)Wf;
  floatx4 zero = {0.f, 0.f, 0.f, 0.f};
  floatx4 acc[8];
#pragma unroll
  for (int ct = 0; ct < 8; ++ct) acc[ct] = zero;
#pragma unroll
  for (int kc = 0; kc < 4; ++kc) {
    const float* ap = A + (size_t)arow * 128 + kc * 32 + quad * 8;
    floatx4 a0 = *(const floatx4*)ap;
    floatx4 a1 = *(const floatx4*)(ap + 4);
    half8 af;
#pragma unroll
    for (int i = 0; i < 4; ++i) { af[i] = (_Float16)a0[i]; af[4 + i] = (_Float16)a1[i]; }
#pragma unroll
    for (int ct = 0; ct < 8; ++ct)
      acc[ct] = __builtin_amdgcn_mfma_f32_16x16x32_f16(af, wf[(kc * 8 + ct) * 64 + lane], acc[ct], 0, 0, 0);
  }
  // C layout: row = quad*4 + q, col = ct*16 + l16
  int orow = rbase + quad * 4;
#pragma unroll
  for (int q = 0; q < 4; ++q) {
    if (orow + q < nrows) {
      float* op = out + (size_t)(orow + q) * 128 + l16;
#pragma unroll
      for (int ct = 0; ct < 8; ++ct) {
        float v = acc[ct][q];
        if (bias) v += bias[ct * 16 + l16];
        if (relu) v = fmaxf(v, 0.f);
        op[ct * 16] = v;
      }
    }
  }
}

// ---------------------------------------------------------------- fused GRU (MFMA)
// rz: K=256 over [agg|h] x 256 cols; n-gate: gi_n (K=128, agg) and gh_n (K=128, h)
// kept separate because r multiplies only gh_n. Epilogue fused.
__global__ __launch_bounds__(256, 2) void k_gru_mfma(const float* __restrict__ agg,
    const float* __restrict__ h, const _Float16* __restrict__ Wrz,
    const _Float16* __restrict__ Wni, const _Float16* __restrict__ Wnh,
    const float* __restrict__ bi, const float* __restrict__ bh,
    float* __restrict__ mout, float* __restrict__ total, int last, int nrows) {
  int wave = threadIdx.x >> 6, lane = threadIdx.x & 63;
  int quad = lane >> 4, l16 = lane & 15;
  int rbase = blockIdx.x * 64 + wave * 16;
  int arow = rbase + l16; if (arow >= nrows) arow = nrows - 1;
  const half8* wrz = (const half8*)Wrz;
  const half8* wni = (const half8*)Wni;
  const half8* wnh = (const half8*)Wnh;
  floatx4 zero = {0.f, 0.f, 0.f, 0.f};
  floatx4 arz[16], ani[8], anh[8];
#pragma unroll
  for (int ct = 0; ct < 16; ++ct) arz[ct] = zero;
#pragma unroll
  for (int ct = 0; ct < 8; ++ct) { ani[ct] = zero; anh[ct] = zero; }
#pragma unroll
  for (int kc = 0; kc < 8; ++kc) {
    const float* src = (kc < 4) ? agg : h;
    const float* ap = src + (size_t)arow * 128 + (kc & 3) * 32 + quad * 8;
    floatx4 a0 = *(const floatx4*)ap;
    floatx4 a1 = *(const floatx4*)(ap + 4);
    half8 af;
#pragma unroll
    for (int i = 0; i < 4; ++i) { af[i] = (_Float16)a0[i]; af[4 + i] = (_Float16)a1[i]; }
#pragma unroll
    for (int ct = 0; ct < 16; ++ct)
      arz[ct] = __builtin_amdgcn_mfma_f32_16x16x32_f16(af, wrz[(kc * 16 + ct) * 64 + lane], arz[ct], 0, 0, 0);
    if (kc < 4) {
#pragma unroll
      for (int ct = 0; ct < 8; ++ct)
        ani[ct] = __builtin_amdgcn_mfma_f32_16x16x32_f16(af, wni[(kc * 8 + ct) * 64 + lane], ani[ct], 0, 0, 0);
    } else {
#pragma unroll
      for (int ct = 0; ct < 8; ++ct)
        anh[ct] = __builtin_amdgcn_mfma_f32_16x16x32_f16(af, wnh[((kc - 4) * 8 + ct) * 64 + lane], anh[ct], 0, 0, 0);
    }
  }
  // epilogue: row = rbase + quad*4 + q, col = cc*16 + l16
  int orow = rbase + quad * 4;
#pragma unroll
  for (int cc = 0; cc < 8; ++cc) {
    int col = cc * 16 + l16;
    float br = bi[col] + bh[col];
    float bz = bi[128 + col] + bh[128 + col];
    float bin = bi[256 + col], bhn = bh[256 + col];
#pragma unroll
    for (int q = 0; q < 4; ++q) {
      int row = orow + q;
      if (row < nrows) {
        float r = sigmoid_(arz[cc][q] + br);
        float z = sigmoid_(arz[8 + cc][q] + bz);
        float nt = tanh_(ani[cc][q] + bin + r * (anh[cc][q] + bhn));
        size_t o = (size_t)row * 128 + col;
        float hold = h[o];
        float val = (1.f - z) * nt + z * hold;
        if (last) total[o] += val; else mout[o] = val;
      }
    }
  }
}

// ---------------------------------------------------------------- scatter-add
__global__ __launch_bounds__(256) void k_scatter(const int2* __restrict__ list,
    const int* __restrict__ cntp, const float* __restrict__ x,
    float* __restrict__ agg) {
  int cnt = *cntp;
  if (cnt > N_EDGES) cnt = N_EDGES;  // rocprof-replay safety
  int half = threadIdx.x >> 7;
  int c = threadIdx.x & 127;
  for (int i = blockIdx.x * 2 + half; i < cnt; i += gridDim.x * 2) {
    int2 e = list[i];
    unsigned s = (unsigned)e.x, d = (unsigned)e.y;
    if (s >= N_NODES || d >= N_NODES) continue;  // replay safety
    float v = x[(size_t)s * 128 + c];
    atomicAdd(agg + (size_t)d * 128 + c, v);
  }
}

// ---------------------------------------------------------------- LayerNorm + ReLU (in-place on h)
__global__ __launch_bounds__(256) void k_ln(float* __restrict__ h,
    const float* __restrict__ total, const float* __restrict__ gamma,
    const float* __restrict__ beta, int nrows) {
  int wave = threadIdx.x >> 6, lane = threadIdx.x & 63;
  int n = blockIdx.x * 4 + wave;
  if (n >= nrows) return;
  size_t base = (size_t)n * 128;
  float v0 = h[base + lane] + total[base + lane];
  float v1 = h[base + 64 + lane] + total[base + 64 + lane];
  float s = v0 + v1, sq = v0 * v0 + v1 * v1;
#pragma unroll
  for (int off = 32; off > 0; off >>= 1) {
    s += __shfl_xor(s, off);
    sq += __shfl_xor(sq, off);
  }
  float mu = s * 0.0078125f;
  float var = sq * 0.0078125f - mu * mu;
  float rs = rsqrtf(var + 1e-5f);
  float o0 = (v0 - mu) * rs * gamma[lane] + beta[lane];
  float o1 = (v1 - mu) * rs * gamma[64 + lane] + beta[64 + lane];
  h[base + lane] = fmaxf(o0, 0.f);
  h[base + 64 + lane] = fmaxf(o1, 0.f);
}

// ---------------------------------------------------------------- head layer 2
__global__ __launch_bounds__(256) void k_head2(const float* __restrict__ z,
    const float* __restrict__ w2, const float* __restrict__ b2,
    float* __restrict__ out, int nrows) {
  __shared__ float w[256];
  w[threadIdx.x] = w2[threadIdx.x];
  __syncthreads();
  int t = blockIdx.x * 256 + threadIdx.x;
  int n = t >> 1, o = t & 1;
  if (n >= nrows) return;
  const float* zr = z + (size_t)n * 128;
  const float* wr = w + o * 128;
  float acc = 0.f;
  for (int k = 0; k < 128; k += 4) {
    float4 zv = *(const float4*)(zr + k);
    acc += zv.x * wr[k] + zv.y * wr[k+1] + zv.z * wr[k+2] + zv.w * wr[k+3];
  }
  out[(size_t)n * 2 + o] = acc + b2[o];
}

// ================================================================ launch
extern "C" void kernel_launch(void* const* d_in, const int* in_sizes, int n_in,
                              void* d_out, int out_size, void* d_ws, size_t ws_size,
                              hipStream_t stream) {
  const int*   x_type  = (const int*)d_in[0];
  const int*   x_tok   = (const int*)d_in[1];
  const float* x_small = (const float*)d_in[2];
  const int*   eidx    = (const int*)d_in[3];
  const int*   etype   = (const int*)d_in[4];
  const float* conv_w  = (const float*)d_in[5];
  const float* gwih    = (const float*)d_in[6];
  const float* gwhh    = (const float*)d_in[7];
  const float* gbih    = (const float*)d_in[8];
  const float* gbhh    = (const float*)d_in[9];
  const float* ln_g    = (const float*)d_in[10];
  const float* ln_b    = (const float*)d_in[11];
  const float* hw1     = (const float*)d_in[12];
  const float* hb1     = (const float*)d_in[13];
  const float* hw2     = (const float*)d_in[14];
  const float* hb2     = (const float*)d_in[15];
  float* out = (float*)d_out;

  const size_t NCb = (size_t)N_NODES * 128 * sizeof(float);  // 25.6 MB
  char* W = (char*)d_ws;
  float* h     = (float*)(W);
  float* m     = (float*)(W + NCb);
  float* xb    = (float*)(W + 2 * NCb);
  float* agg   = (float*)(W + 3 * NCb);
  float* total = (float*)(W + 4 * NCb);
  int*   cnt   = (int*)  (W + 5 * NCb);
  int2*  lists = (int2*) (W + 5 * NCb + 256);
  char*  FB    = W + 5 * NCb + 256 + (size_t)3 * N_EDGES * 8;
  _Float16* WRZ = (_Float16*)FB;                 // 6 * 65536 halfs
  _Float16* WNI = WRZ + 6 * 65536;               // 6 * 16384
  _Float16* WNH = WNI + 6 * 16384;               // 6 * 16384
  _Float16* WC  = WNH + 6 * 16384;               // 18 * 16384
  _Float16* W1F = WC + 18 * 16384;               // 16384

  // per-call prep (ws is re-poisoned before every launch)
  k_features<<<(N_NODES * 128 + 255) / 256, 256, 0, stream>>>(h, x_type, x_tok, x_small);
  hipMemsetAsync(cnt, 0, 16, stream);
  k_bucket<<<(N_EDGES + 255) / 256, 256, 0, stream>>>(eidx, etype, lists, cnt);
  k_prep_rz<<<(6 * 8 * 16 * 512 + 255) / 256, 256, 0, stream>>>(gwih, gwhh, WRZ);
  k_prep_n<<<(6 * 4 * 8 * 512 + 255) / 256, 256, 0, stream>>>(gwih, gwhh, WNI, WNH);
  k_prep_conv<<<(18 * 4 * 8 * 512 + 255) / 256, 256, 0, stream>>>(conv_w, WC);
  k_prep_w1<<<(4 * 8 * 512 + 255) / 256, 256, 0, stream>>>(hw1, W1F);

  int gblk = (N_NODES + 63) / 64;
  for (int b = 0; b < 2; ++b) {
    hipMemsetAsync(total, 0, NCb, stream);
    for (int t = 0; t < 3; ++t) {
      int bt = b * 3 + t;
      for (int s = 0; s < 3; ++s) {
        const float* A = (s == 0) ? h : m;  // m = h at step 0
        k_gemm_mfma<<<gblk, 256, 0, stream>>>(A, WC + (size_t)(bt * 3 + s) * 16384,
                                              nullptr, xb, 0, N_NODES);
        hipMemsetAsync(agg, 0, NCb, stream);
        k_scatter<<<2048, 256, 0, stream>>>(lists + (size_t)t * N_EDGES, cnt + t, xb, agg);
        k_gru_mfma<<<gblk, 256, 0, stream>>>(agg, A,
            WRZ + (size_t)bt * 65536, WNI + (size_t)bt * 16384, WNH + (size_t)bt * 16384,
            gbih + (size_t)bt * 384, gbhh + (size_t)bt * 384,
            m, total, (s == 2) ? 1 : 0, N_NODES);
      }
    }
    k_ln<<<(N_NODES + 3) / 4, 256, 0, stream>>>(h, total, ln_g + b * 128, ln_b + b * 128, N_NODES);
  }
  // head
  k_gemm_mfma<<<gblk, 256, 0, stream>>>(h, W1F, hb1, xb, 1, N_NODES);
  k_head2<<<(2 * N_NODES + 255) / 256, 256, 0, stream>>>(xb, hw2, hb2, out, N_NODES);
}

// Round 3
// 2323.288 us; speedup vs baseline: 3.5317x; 1.6699x over previous
//
#include <hip/hip_runtime.h>
#include <cstdint>
#include <cstddef>

// Problem constants (match reference)
#define N_NODES 50000
#define N_EDGES 500000
#define NB 782              // ceil(N_NODES/64) row-blocks per type
// C = 128, STEPS = 3, BLOCKS = 2, NUM_ET = 3

typedef _Float16 half8 __attribute__((ext_vector_type(8)));
typedef _Float16 half2v __attribute__((ext_vector_type(2)));
typedef float floatx4 __attribute__((ext_vector_type(4)));

__device__ __forceinline__ float sigmoid_(float x) { return 1.f / (1.f + __expf(-x)); }
__device__ __forceinline__ float tanh_(float x) {
  float t = __expf(-2.f * fabsf(x));
  float r = (1.f - t) / (1.f + t);
  return copysignf(r, x);
}

// ---------------------------------------------------------------- features
__global__ __launch_bounds__(256) void k_features(float* __restrict__ h,
    const int* __restrict__ xtype, const int* __restrict__ xtok,
    const float* __restrict__ xs) {
  int idx = blockIdx.x * 256 + threadIdx.x;
  if (idx >= N_NODES * 128) return;
  int n = idx >> 7, c = idx & 127;
  float v;
  if (c < 32) {
    v = (xtype[n] == c) ? 1.f : 0.f;
  } else if (c < 126) {
    int tk = xtok[n];
    tk = tk < 0 ? 0 : (tk > 93 ? 93 : tk);
    v = (tk == (c - 32)) ? 1.f : 0.f;
  } else {
    v = xs[n * 2 + (c - 126)];
  }
  h[idx] = v;
}

// ---------------------------------------------------------------- CSR build
// hist: counts[dst]++ (spread over 50K addresses -> fast)
__global__ __launch_bounds__(256) void k_hist(const int* __restrict__ ei,
    int* __restrict__ counts) {
  int e = blockIdx.x * 256 + threadIdx.x;
  if (e >= N_EDGES) return;
  int d = ei[N_EDGES + e];
  if ((unsigned)d < N_NODES) atomicAdd(&counts[d], 1);
}

// single-block exclusive scan of counts[0..N) -> ptr, fill (fill = working copy)
__global__ __launch_bounds__(256) void k_scan(const int* __restrict__ counts,
    int* __restrict__ ptr, int* __restrict__ fill) {
  __shared__ int wsum[4];
  __shared__ int running_s;
  if (threadIdx.x == 0) running_s = 0;
  __syncthreads();
  int lane = threadIdx.x & 63, wv = threadIdx.x >> 6;
  for (int base = 0; base < N_NODES; base += 256) {
    int i = base + threadIdx.x;
    int v = (i < N_NODES) ? counts[i] : 0;
    int s = v;
#pragma unroll
    for (int off = 1; off < 64; off <<= 1) {
      int u = __shfl_up(s, off);
      if (lane >= off) s += u;
    }
    if (lane == 63) wsum[wv] = s;
    __syncthreads();
    int woff = 0;
#pragma unroll
    for (int w = 0; w < 4; ++w) woff += (w < wv) ? wsum[w] : 0;
    int run = running_s;
    int excl = run + woff + s - v;
    if (i < N_NODES) { ptr[i] = excl; fill[i] = excl; }
    __syncthreads();
    if (threadIdx.x == 255) running_s = run + woff + s;
    __syncthreads();
  }
  if (threadIdx.x == 0) ptr[N_NODES] = running_s;
}

// place: csr[slot(dst)] = src | (type<<16)   (src < 50000 < 2^16)
__global__ __launch_bounds__(256) void k_place(const int* __restrict__ ei,
    const int* __restrict__ et, int* __restrict__ fill, int* __restrict__ csr) {
  int e = blockIdx.x * 256 + threadIdx.x;
  if (e >= N_EDGES) return;
  int srcv = ei[e], d = ei[N_EDGES + e], ty = et[e];
  if ((unsigned)d >= N_NODES || (unsigned)srcv >= N_NODES) return;
  int pos = atomicAdd(&fill[d], 1);
  if ((unsigned)pos < N_EDGES) csr[pos] = (srcv & 0xFFFF) | ((ty & 3) << 16);
}

// ---------------------------------------------------------------- weight fragment prep
// B-frag for v_mfma_f32_16x16x32_f16:
//   frag[(kc*CT+ct)*64 + lane][j] = W[k = kc*32 + (lane>>4)*8 + j][n = ct*16 + (lane&15)]
__global__ __launch_bounds__(256) void k_prep_rz(const float* __restrict__ wih,
    const float* __restrict__ whh, _Float16* __restrict__ dst) {
  int idx = blockIdx.x * 256 + threadIdx.x;
  if (idx >= 6 * 8 * 16 * 512) return;
  int j = idx & 7, lane = (idx >> 3) & 63, ct = (idx >> 9) & 15, kc = (idx >> 13) & 7, bt = idx >> 16;
  int k = (kc & 3) * 32 + ((lane >> 4) & 3) * 8 + j;
  int n = ct * 16 + (lane & 15);
  const float* src = (kc < 4) ? wih : whh;
  dst[idx] = (_Float16)src[((size_t)bt * 384 + n) * 128 + k];
}

__global__ __launch_bounds__(256) void k_prep_n(const float* __restrict__ wih,
    const float* __restrict__ whh, _Float16* __restrict__ di, _Float16* __restrict__ dh) {
  int idx = blockIdx.x * 256 + threadIdx.x;
  if (idx >= 6 * 4 * 8 * 512) return;
  int j = idx & 7, lane = (idx >> 3) & 63, ct = (idx >> 9) & 7, kc = (idx >> 12) & 3, bt = idx >> 14;
  int k = kc * 32 + ((lane >> 4) & 3) * 8 + j;
  int n = 256 + ct * 16 + (lane & 15);
  di[idx] = (_Float16)wih[((size_t)bt * 384 + n) * 128 + k];
  dh[idx] = (_Float16)whh[((size_t)bt * 384 + n) * 128 + k];
}

__global__ __launch_bounds__(256) void k_prep_conv(const float* __restrict__ cw,
    _Float16* __restrict__ dst) {
  int idx = blockIdx.x * 256 + threadIdx.x;
  if (idx >= 18 * 4 * 8 * 512) return;
  int j = idx & 7, lane = (idx >> 3) & 63, ct = (idx >> 9) & 7, kc = (idx >> 12) & 3, w = idx >> 14;
  int k = kc * 32 + ((lane >> 4) & 3) * 8 + j;
  int n = ct * 16 + (lane & 15);
  dst[idx] = (_Float16)cw[(size_t)w * 16384 + k * 128 + n];
}

__global__ __launch_bounds__(256) void k_prep_w1(const float* __restrict__ hw1,
    _Float16* __restrict__ dst) {
  int idx = blockIdx.x * 256 + threadIdx.x;
  if (idx >= 4 * 8 * 512) return;
  int j = idx & 7, lane = (idx >> 3) & 63, ct = (idx >> 9) & 7, kc = (idx >> 12) & 3;
  int k = kc * 32 + ((lane >> 4) & 3) * 8 + j;
  int n = ct * 16 + (lane & 15);
  dst[idx] = (_Float16)hw1[n * 128 + k];
}

// ---------------------------------------------------------------- batched conv GEMM (fp16 out)
// X[t] = A_t @ convW[t], A_t = (astride==0 ? h : S+t*NC). grid = 3*NB.
__global__ __launch_bounds__(256, 4) void k_conv(const float* __restrict__ Abase,
    const size_t astride, const _Float16* __restrict__ Wc, _Float16* __restrict__ X) {
  int t = blockIdx.x / NB, blk = blockIdx.x - t * NB;
  int wave = threadIdx.x >> 6, lane = threadIdx.x & 63;
  int quad = lane >> 4, l16 = lane & 15;
  int rbase = blk * 64 + wave * 16;
  int arow = rbase + l16; if (arow >= N_NODES) arow = N_NODES - 1;
  const float* A = Abase + astride * t;
  const half8* wf = (const half8*)(Wc + (size_t)t * 49152);
  floatx4 zero = {0.f, 0.f, 0.f, 0.f};
  floatx4 acc[8];
#pragma unroll
  for (int ct = 0; ct < 8; ++ct) acc[ct] = zero;
#pragma unroll
  for (int kc = 0; kc < 4; ++kc) {
    const float* ap = A + (size_t)arow * 128 + kc * 32 + quad * 8;
    floatx4 a0 = *(const floatx4*)ap;
    floatx4 a1 = *(const floatx4*)(ap + 4);
    half8 af;
#pragma unroll
    for (int i = 0; i < 4; ++i) { af[i] = (_Float16)a0[i]; af[4 + i] = (_Float16)a1[i]; }
#pragma unroll
    for (int ct = 0; ct < 8; ++ct)
      acc[ct] = __builtin_amdgcn_mfma_f32_16x16x32_f16(af, wf[(kc * 8 + ct) * 64 + lane], acc[ct], 0, 0, 0);
  }
  int orow = rbase + quad * 4;
  _Float16* Xp = X + (size_t)t * (N_NODES * 128);
#pragma unroll
  for (int q = 0; q < 4; ++q) {
    if (orow + q < N_NODES) {
      _Float16* op = Xp + (size_t)(orow + q) * 128 + l16;
#pragma unroll
      for (int ct = 0; ct < 8; ++ct) op[ct * 16] = (_Float16)acc[ct][q];
    }
  }
}

// ---------------------------------------------------------------- CSR gather-reduce
// G[t][n] = sum over in-edges of type t of X[t][src]. One wave per node,
// lane = 2 channels; per-edge branch is wave-uniform (whole wave shares the edge).
__global__ __launch_bounds__(256) void k_gather(const _Float16* __restrict__ X,
    const int* __restrict__ ptr, const int* __restrict__ csr,
    _Float16* __restrict__ G) {
  int wave = threadIdx.x >> 6, lane = threadIdx.x & 63;
  int n = blockIdx.x * 4 + wave;
  if (n >= N_NODES) return;
  int b0 = ptr[n], b1 = ptr[n + 1];
  if (b0 < 0) b0 = 0; if (b1 > N_EDGES) b1 = N_EDGES;  // replay safety
  const size_t NC = (size_t)N_NODES * 128;
  float a00 = 0.f, a01 = 0.f, a10 = 0.f, a11 = 0.f, a20 = 0.f, a21 = 0.f;
  for (int i = b0; i < b1; ++i) {
    int v = csr[i];
    int src = v & 0xFFFF;
    int ty = (v >> 16) & 3;
    const _Float16* xp = X + (size_t)ty * NC + (size_t)src * 128 + lane * 2;
    half2v xv = *(const half2v*)xp;
    float x0 = (float)xv[0], x1 = (float)xv[1];
    if (ty == 0)      { a00 += x0; a01 += x1; }
    else if (ty == 1) { a10 += x0; a11 += x1; }
    else              { a20 += x0; a21 += x1; }
  }
  size_t go = (size_t)n * 128 + lane * 2;
  half2v o0; o0[0] = (_Float16)a00; o0[1] = (_Float16)a01;
  half2v o1; o1[0] = (_Float16)a10; o1[1] = (_Float16)a11;
  half2v o2; o2[0] = (_Float16)a20; o2[1] = (_Float16)a21;
  *(half2v*)(G + go) = o0;
  *(half2v*)(G + NC + go) = o1;
  *(half2v*)(G + 2 * NC + go) = o2;
}

// ---------------------------------------------------------------- batched fused GRU (MFMA)
// S[t] = GRU(G[t], M_t), M_t = (mstride==0 ? h : S+t*NC) [in-place safe: each wave
// reads only its own 16 rows before writing them]. grid = 3*NB.
__global__ __launch_bounds__(256, 2) void k_gru(const _Float16* __restrict__ G,
    const float* __restrict__ Mbase, const size_t mstride, float* __restrict__ S,
    const _Float16* __restrict__ Wrz, const _Float16* __restrict__ Wni,
    const _Float16* __restrict__ Wnh, const float* __restrict__ bi2,
    const float* __restrict__ bh2) {
  int t = blockIdx.x / NB, blk = blockIdx.x - t * NB;
  int wave = threadIdx.x >> 6, lane = threadIdx.x & 63;
  int quad = lane >> 4, l16 = lane & 15;
  int rbase = blk * 64 + wave * 16;
  int arow = rbase + l16; if (arow >= N_NODES) arow = N_NODES - 1;
  const size_t NC = (size_t)N_NODES * 128;
  const float* M = Mbase + mstride * t;
  const _Float16* Gp = G + (size_t)t * NC;
  float* Sp = S + (size_t)t * NC;
  const half8* wrz = (const half8*)(Wrz + (size_t)t * 65536);
  const half8* wni = (const half8*)(Wni + (size_t)t * 16384);
  const half8* wnh = (const half8*)(Wnh + (size_t)t * 16384);
  const float* bi = bi2 + (size_t)t * 384;
  const float* bh = bh2 + (size_t)t * 384;
  floatx4 zero = {0.f, 0.f, 0.f, 0.f};
  floatx4 arz[16], ani[8], anh[8];
#pragma unroll
  for (int ct = 0; ct < 16; ++ct) arz[ct] = zero;
#pragma unroll
  for (int ct = 0; ct < 8; ++ct) { ani[ct] = zero; anh[ct] = zero; }
#pragma unroll
  for (int kc = 0; kc < 8; ++kc) {
    half8 af;
    if (kc < 4) {
      af = *(const half8*)(Gp + (size_t)arow * 128 + kc * 32 + quad * 8);
    } else {
      const float* ap = M + (size_t)arow * 128 + (kc - 4) * 32 + quad * 8;
      floatx4 a0 = *(const floatx4*)ap;
      floatx4 a1 = *(const floatx4*)(ap + 4);
#pragma unroll
      for (int i = 0; i < 4; ++i) { af[i] = (_Float16)a0[i]; af[4 + i] = (_Float16)a1[i]; }
    }
#pragma unroll
    for (int ct = 0; ct < 16; ++ct)
      arz[ct] = __builtin_amdgcn_mfma_f32_16x16x32_f16(af, wrz[(kc * 16 + ct) * 64 + lane], arz[ct], 0, 0, 0);
    if (kc < 4) {
#pragma unroll
      for (int ct = 0; ct < 8; ++ct)
        ani[ct] = __builtin_amdgcn_mfma_f32_16x16x32_f16(af, wni[(kc * 8 + ct) * 64 + lane], ani[ct], 0, 0, 0);
    } else {
#pragma unroll
      for (int ct = 0; ct < 8; ++ct)
        anh[ct] = __builtin_amdgcn_mfma_f32_16x16x32_f16(af, wnh[((kc - 4) * 8 + ct) * 64 + lane], anh[ct], 0, 0, 0);
    }
  }
  int orow = rbase + quad * 4;
#pragma unroll
  for (int cc = 0; cc < 8; ++cc) {
    int col = cc * 16 + l16;
    float br = bi[col] + bh[col];
    float bz = bi[128 + col] + bh[128 + col];
    float bin = bi[256 + col], bhn = bh[256 + col];
#pragma unroll
    for (int q = 0; q < 4; ++q) {
      int row = orow + q;
      if (row < N_NODES) {
        float r = sigmoid_(arz[cc][q] + br);
        float z = sigmoid_(arz[8 + cc][q] + bz);
        float nt = tanh_(ani[cc][q] + bin + r * (anh[cc][q] + bhn));
        size_t o = (size_t)row * 128 + col;
        float hold = M[o];
        Sp[o] = (1.f - z) * nt + z * hold;
      }
    }
  }
}

// ---------------------------------------------------------------- LayerNorm(h + S0+S1+S2) + ReLU -> h
__global__ __launch_bounds__(256) void k_ln(float* __restrict__ h,
    const float* __restrict__ S, const float* __restrict__ gamma,
    const float* __restrict__ beta) {
  int wave = threadIdx.x >> 6, lane = threadIdx.x & 63;
  int n = blockIdx.x * 4 + wave;
  if (n >= N_NODES) return;
  const size_t NC = (size_t)N_NODES * 128;
  size_t base = (size_t)n * 128;
  float v0 = h[base + lane] + S[base + lane] + S[NC + base + lane] + S[2 * NC + base + lane];
  float v1 = h[base + 64 + lane] + S[base + 64 + lane] + S[NC + base + 64 + lane] + S[2 * NC + base + 64 + lane];
  float s = v0 + v1, sq = v0 * v0 + v1 * v1;
#pragma unroll
  for (int off = 32; off > 0; off >>= 1) {
    s += __shfl_xor(s, off);
    sq += __shfl_xor(sq, off);
  }
  float mu = s * 0.0078125f;
  float var = sq * 0.0078125f - mu * mu;
  float rs = rsqrtf(var + 1e-5f);
  float o0 = (v0 - mu) * rs * gamma[lane] + beta[lane];
  float o1 = (v1 - mu) * rs * gamma[64 + lane] + beta[64 + lane];
  h[base + lane] = fmaxf(o0, 0.f);
  h[base + 64 + lane] = fmaxf(o1, 0.f);
}

// ---------------------------------------------------------------- head layer 1 (fp32 out, bias+relu)
__global__ __launch_bounds__(256, 4) void k_gemm_head(const float* __restrict__ A,
    const _Float16* __restrict__ Wf, const float* __restrict__ bias,
    float* __restrict__ out) {
  int wave = threadIdx.x >> 6, lane = threadIdx.x & 63;
  int quad = lane >> 4, l16 = lane & 15;
  int rbase = blockIdx.x * 64 + wave * 16;
  int arow = rbase + l16; if (arow >= N_NODES) arow = N_NODES - 1;
  const half8* wf = (const half8*)Wf;
  floatx4 zero = {0.f, 0.f, 0.f, 0.f};
  floatx4 acc[8];
#pragma unroll
  for (int ct = 0; ct < 8; ++ct) acc[ct] = zero;
#pragma unroll
  for (int kc = 0; kc < 4; ++kc) {
    const float* ap = A + (size_t)arow * 128 + kc * 32 + quad * 8;
    floatx4 a0 = *(const floatx4*)ap;
    floatx4 a1 = *(const floatx4*)(ap + 4);
    half8 af;
#pragma unroll
    for (int i = 0; i < 4; ++i) { af[i] = (_Float16)a0[i]; af[4 + i] = (_Float16)a1[i]; }
#pragma unroll
    for (int ct = 0; ct < 8; ++ct)
      acc[ct] = __builtin_amdgcn_mfma_f32_16x16x32_f16(af, wf[(kc * 8 + ct) * 64 + lane], acc[ct], 0, 0, 0);
  }
  int orow = rbase + quad * 4;
#pragma unroll
  for (int q = 0; q < 4; ++q) {
    if (orow + q < N_NODES) {
      float* op = out + (size_t)(orow + q) * 128 + l16;
#pragma unroll
      for (int ct = 0; ct < 8; ++ct)
        op[ct * 16] = fmaxf(acc[ct][q] + bias[ct * 16 + l16], 0.f);
    }
  }
}

// ---------------------------------------------------------------- head layer 2
__global__ __launch_bounds__(256) void k_head2(const float* __restrict__ z,
    const float* __restrict__ w2, const float* __restrict__ b2,
    float* __restrict__ out) {
  __shared__ float w[256];
  w[threadIdx.x] = w2[threadIdx.x];
  __syncthreads();
  int t = blockIdx.x * 256 + threadIdx.x;
  int n = t >> 1, o = t & 1;
  if (n >= N_NODES) return;
  const float* zr = z + (size_t)n * 128;
  const float* wr = w + o * 128;
  float acc = 0.f;
  for (int k = 0; k < 128; k += 4) {
    float4 zv = *(const float4*)(zr + k);
    acc += zv.x * wr[k] + zv.y * wr[k+1] + zv.z * wr[k+2] + zv.w * wr[k+3];
  }
  out[(size_t)n * 2 + o] = acc + b2[o];
}

// ================================================================ launch
extern "C" void kernel_launch(void* const* d_in, const int* in_sizes, int n_in,
                              void* d_out, int out_size, void* d_ws, size_t ws_size,
                              hipStream_t stream) {
  const int*   x_type  = (const int*)d_in[0];
  const int*   x_tok   = (const int*)d_in[1];
  const float* x_small = (const float*)d_in[2];
  const int*   eidx    = (const int*)d_in[3];
  const int*   etype   = (const int*)d_in[4];
  const float* conv_w  = (const float*)d_in[5];
  const float* gwih    = (const float*)d_in[6];
  const float* gwhh    = (const float*)d_in[7];
  const float* gbih    = (const float*)d_in[8];
  const float* gbhh    = (const float*)d_in[9];
  const float* ln_g    = (const float*)d_in[10];
  const float* ln_b    = (const float*)d_in[11];
  const float* hw1     = (const float*)d_in[12];
  const float* hb1     = (const float*)d_in[13];
  const float* hw2     = (const float*)d_in[14];
  const float* hb2     = (const float*)d_in[15];
  float* out = (float*)d_out;

  const size_t NC = (size_t)N_NODES * 128;
  char* W = (char*)d_ws;
  size_t off = 0;
  float* h = (float*)(W + off);             off += NC * 4;            // 25.6 MB
  float* S = (float*)(W + off);             off += 3 * NC * 4;        // 76.8 MB
  _Float16* X = (_Float16*)(W + off);       off += 3 * NC * 2;        // 38.4 MB
  _Float16* G = (_Float16*)(W + off);       off += 3 * NC * 2;        // 38.4 MB
  int* counts = (int*)(W + off);            off += (N_NODES + 1) * 4;
  int* ptrv   = (int*)(W + off);            off += (N_NODES + 1) * 4;
  int* fill   = (int*)(W + off);            off += (N_NODES + 1) * 4;
  int* csr    = (int*)(W + off);            off += (size_t)N_EDGES * 4;
  _Float16* WRZ = (_Float16*)(W + off);     off += (size_t)6 * 65536 * 2;
  _Float16* WNI = (_Float16*)(W + off);     off += (size_t)6 * 16384 * 2;
  _Float16* WNH = (_Float16*)(W + off);     off += (size_t)6 * 16384 * 2;
  _Float16* WC  = (_Float16*)(W + off);     off += (size_t)18 * 16384 * 2;
  _Float16* W1F = (_Float16*)(W + off);     off += (size_t)16384 * 2;

  // ---- per-call prep
  k_features<<<(N_NODES * 128 + 255) / 256, 256, 0, stream>>>(h, x_type, x_tok, x_small);
  hipMemsetAsync(counts, 0, (size_t)N_NODES * 4, stream);
  k_hist<<<(N_EDGES + 255) / 256, 256, 0, stream>>>(eidx, counts);
  k_scan<<<1, 256, 0, stream>>>(counts, ptrv, fill);
  k_place<<<(N_EDGES + 255) / 256, 256, 0, stream>>>(eidx, etype, fill, csr);
  k_prep_rz<<<(6 * 8 * 16 * 512 + 255) / 256, 256, 0, stream>>>(gwih, gwhh, WRZ);
  k_prep_n<<<(6 * 4 * 8 * 512 + 255) / 256, 256, 0, stream>>>(gwih, gwhh, WNI, WNH);
  k_prep_conv<<<(18 * 4 * 8 * 512 + 255) / 256, 256, 0, stream>>>(conv_w, WC);
  k_prep_w1<<<(4 * 8 * 512 + 255) / 256, 256, 0, stream>>>(hw1, W1F);

  // ---- main loop: 2 blocks x 3 steps, 3 edge-types batched per dispatch
  for (int b = 0; b < 2; ++b) {
    for (int s = 0; s < 3; ++s) {
      const float* Ab = (s == 0) ? h : S;
      size_t astr = (s == 0) ? 0 : NC;
      k_conv<<<3 * NB, 256, 0, stream>>>(Ab, astr, WC + (size_t)(b * 9 + s) * 16384, X);
      k_gather<<<(N_NODES + 3) / 4, 256, 0, stream>>>(X, ptrv, csr, G);
      k_gru<<<3 * NB, 256, 0, stream>>>(G, Ab, astr, S,
          WRZ + (size_t)b * 3 * 65536, WNI + (size_t)b * 3 * 16384, WNH + (size_t)b * 3 * 16384,
          gbih + (size_t)b * 3 * 384, gbhh + (size_t)b * 3 * 384);
    }
    k_ln<<<(N_NODES + 3) / 4, 256, 0, stream>>>(h, S, ln_g + b * 128, ln_b + b * 128);
  }
  // ---- head (z stored in S, which is dead after the last LN)
  k_gemm_head<<<NB, 256, 0, stream>>>(h, W1F, hb1, S);
  k_head2<<<(2 * N_NODES + 255) / 256, 256, 0, stream>>>(S, hw2, hb2, out);
}

// Round 4
// 1705.152 us; speedup vs baseline: 4.8120x; 1.3625x over previous
//
#include <hip/hip_runtime.h>
#include <cstdint>
#include <cstddef>

// Problem constants (match reference)
#define N_NODES 50000
#define N_EDGES 500000
#define NB 782              // ceil(N_NODES/64) row-blocks
#define NCHUNK 196          // ceil(N_NODES/256) scan chunks
// C = 128, STEPS = 3, BLOCKS = 2, NUM_ET = 3

typedef _Float16 half8 __attribute__((ext_vector_type(8)));
typedef _Float16 half2v __attribute__((ext_vector_type(2)));
typedef float floatx4 __attribute__((ext_vector_type(4)));

__device__ __forceinline__ float sigmoid_(float x) { return 1.f / (1.f + __expf(-x)); }
__device__ __forceinline__ float tanh_(float x) {
  float t = __expf(-2.f * fabsf(x));
  float r = (1.f - t) / (1.f + t);
  return copysignf(r, x);
}

// ---------------------------------------------------------------- features
__global__ __launch_bounds__(256) void k_features(float* __restrict__ h,
    const int* __restrict__ xtype, const int* __restrict__ xtok,
    const float* __restrict__ xs) {
  int idx = blockIdx.x * 256 + threadIdx.x;
  if (idx >= N_NODES * 128) return;
  int n = idx >> 7, c = idx & 127;
  float v;
  if (c < 32) {
    v = (xtype[n] == c) ? 1.f : 0.f;
  } else if (c < 126) {
    int tk = xtok[n];
    tk = tk < 0 ? 0 : (tk > 93 ? 93 : tk);
    v = (tk == (c - 32)) ? 1.f : 0.f;
  } else {
    v = xs[n * 2 + (c - 126)];
  }
  h[idx] = v;
}

// ---------------------------------------------------------------- CSR build
__global__ __launch_bounds__(256) void k_hist(const int* __restrict__ ei,
    int* __restrict__ counts) {
  int e = blockIdx.x * 256 + threadIdx.x;
  if (e >= N_EDGES) return;
  int d = ei[N_EDGES + e];
  if ((unsigned)d < N_NODES) atomicAdd(&counts[d], 1);
}

// 3-phase scan (replaces single-block serial scan over 50K elems)
__global__ __launch_bounds__(256) void k_scan_a(const int* __restrict__ counts,
    int* __restrict__ bsum) {
  int i = blockIdx.x * 256 + threadIdx.x;
  int v = (i < N_NODES) ? counts[i] : 0;
  int lane = threadIdx.x & 63, wv = threadIdx.x >> 6;
#pragma unroll
  for (int off = 32; off > 0; off >>= 1) v += __shfl_xor(v, off);
  __shared__ int ws[4];
  if (lane == 0) ws[wv] = v;
  __syncthreads();
  if (threadIdx.x == 0) bsum[blockIdx.x] = ws[0] + ws[1] + ws[2] + ws[3];
}

__global__ __launch_bounds__(256) void k_scan_b(const int* __restrict__ bsum,
    int* __restrict__ boff) {
  int i = threadIdx.x;
  int v = (i < NCHUNK) ? bsum[i] : 0;
  int lane = i & 63, wv = i >> 6;
  int s = v;
#pragma unroll
  for (int off = 1; off < 64; off <<= 1) { int u = __shfl_up(s, off); if (lane >= off) s += u; }
  __shared__ int ws[4];
  if (lane == 63) ws[wv] = s;
  __syncthreads();
  int woff = 0;
#pragma unroll
  for (int w = 0; w < 4; ++w) woff += (w < wv) ? ws[w] : 0;
  if (i < NCHUNK) boff[i] = woff + s - v;
  if (i == 255) boff[NCHUNK] = ws[0] + ws[1] + ws[2] + ws[3];
}

__global__ __launch_bounds__(256) void k_scan_c(const int* __restrict__ counts,
    const int* __restrict__ boff, int* __restrict__ ptr, int* __restrict__ fill) {
  int i = blockIdx.x * 256 + threadIdx.x;
  int v = (i < N_NODES) ? counts[i] : 0;
  int lane = threadIdx.x & 63, wv = threadIdx.x >> 6;
  int s = v;
#pragma unroll
  for (int off = 1; off < 64; off <<= 1) { int u = __shfl_up(s, off); if (lane >= off) s += u; }
  __shared__ int ws[4];
  if (lane == 63) ws[wv] = s;
  __syncthreads();
  int woff = 0;
#pragma unroll
  for (int w = 0; w < 4; ++w) woff += (w < wv) ? ws[w] : 0;
  int excl = boff[blockIdx.x] + woff + s - v;
  if (i < N_NODES) { ptr[i] = excl; fill[i] = excl; }
  if (blockIdx.x == 0 && threadIdx.x == 0) ptr[N_NODES] = boff[NCHUNK];
}

__global__ __launch_bounds__(256) void k_place(const int* __restrict__ ei,
    const int* __restrict__ et, int* __restrict__ fill, int* __restrict__ csr) {
  int e = blockIdx.x * 256 + threadIdx.x;
  if (e >= N_EDGES) return;
  int srcv = ei[e], d = ei[N_EDGES + e], ty = et[e];
  if ((unsigned)d >= N_NODES || (unsigned)srcv >= N_NODES) return;
  int pos = atomicAdd(&fill[d], 1);
  if ((unsigned)pos < N_EDGES) csr[pos] = (srcv & 0xFFFF) | ((ty & 3) << 16);
}

// ---------------------------------------------------------------- weight fragment prep
// B-frag for v_mfma_f32_16x16x32_f16:
//   frag[(kc*CT+ct)*64 + lane][j] = W[k = kc*32 + (lane>>4)*8 + j][n = ct*16 + (lane&15)]
__global__ __launch_bounds__(256) void k_prep_rz(const float* __restrict__ wih,
    const float* __restrict__ whh, _Float16* __restrict__ dst) {
  int idx = blockIdx.x * 256 + threadIdx.x;
  if (idx >= 6 * 8 * 16 * 512) return;
  int j = idx & 7, lane = (idx >> 3) & 63, ct = (idx >> 9) & 15, kc = (idx >> 13) & 7, bt = idx >> 16;
  int k = (kc & 3) * 32 + ((lane >> 4) & 3) * 8 + j;
  int n = ct * 16 + (lane & 15);
  const float* src = (kc < 4) ? wih : whh;
  dst[idx] = (_Float16)src[((size_t)bt * 384 + n) * 128 + k];
}

__global__ __launch_bounds__(256) void k_prep_n(const float* __restrict__ wih,
    const float* __restrict__ whh, _Float16* __restrict__ di, _Float16* __restrict__ dh) {
  int idx = blockIdx.x * 256 + threadIdx.x;
  if (idx >= 6 * 4 * 8 * 512) return;
  int j = idx & 7, lane = (idx >> 3) & 63, ct = (idx >> 9) & 7, kc = (idx >> 12) & 3, bt = idx >> 14;
  int k = kc * 32 + ((lane >> 4) & 3) * 8 + j;
  int n = 256 + ct * 16 + (lane & 15);
  di[idx] = (_Float16)wih[((size_t)bt * 384 + n) * 128 + k];
  dh[idx] = (_Float16)whh[((size_t)bt * 384 + n) * 128 + k];
}

__global__ __launch_bounds__(256) void k_prep_conv(const float* __restrict__ cw,
    _Float16* __restrict__ dst) {
  int idx = blockIdx.x * 256 + threadIdx.x;
  if (idx >= 18 * 4 * 8 * 512) return;
  int j = idx & 7, lane = (idx >> 3) & 63, ct = (idx >> 9) & 7, kc = (idx >> 12) & 3, w = idx >> 14;
  int k = kc * 32 + ((lane >> 4) & 3) * 8 + j;
  int n = ct * 16 + (lane & 15);
  dst[idx] = (_Float16)cw[(size_t)w * 16384 + k * 128 + n];
}

__global__ __launch_bounds__(256) void k_prep_w1(const float* __restrict__ hw1,
    _Float16* __restrict__ dst) {
  int idx = blockIdx.x * 256 + threadIdx.x;
  if (idx >= 4 * 8 * 512) return;
  int j = idx & 7, lane = (idx >> 3) & 63, ct = (idx >> 9) & 7, kc = (idx >> 12) & 3;
  int k = kc * 32 + ((lane >> 4) & 3) * 8 + j;
  int n = ct * 16 + (lane & 15);
  dst[idx] = (_Float16)hw1[n * 128 + k];
}

// ---------------------------------------------------------------- batched conv GEMM (fp16 out)
// X[t] = A_t @ convW[t]. grid = 3*NB. Wave = 64 rows x 32 cols (ct {2w,2w+1});
// each B-fragment reused 4x across row-tiles.
__global__ __launch_bounds__(256, 4) void k_conv(const float* __restrict__ Abase,
    const size_t astride, const _Float16* __restrict__ Wc, _Float16* __restrict__ X) {
  int t = blockIdx.x / NB, blk = blockIdx.x - t * NB;
  int wave = threadIdx.x >> 6, lane = threadIdx.x & 63;
  int quad = lane >> 4, l16 = lane & 15;
  int rowbase = blk * 64;
  const float* A = Abase + astride * t;
  const half8* wf = (const half8*)(Wc + (size_t)t * 49152);
  int ar[4];
#pragma unroll
  for (int rt = 0; rt < 4; ++rt) {
    int r = rowbase + rt * 16 + l16;
    ar[rt] = r < N_NODES ? r : N_NODES - 1;
  }
  floatx4 zero = {0.f, 0.f, 0.f, 0.f};
  floatx4 acc[4][2];
#pragma unroll
  for (int rt = 0; rt < 4; ++rt) { acc[rt][0] = zero; acc[rt][1] = zero; }
#pragma unroll
  for (int kc = 0; kc < 4; ++kc) {
    half8 af[4];
#pragma unroll
    for (int rt = 0; rt < 4; ++rt) {
      const float* ap = A + (size_t)ar[rt] * 128 + kc * 32 + quad * 8;
      floatx4 a0 = *(const floatx4*)ap;
      floatx4 a1 = *(const floatx4*)(ap + 4);
#pragma unroll
      for (int i = 0; i < 4; ++i) { af[rt][i] = (_Float16)a0[i]; af[rt][4 + i] = (_Float16)a1[i]; }
    }
    half8 b0 = wf[(kc * 8 + 2 * wave) * 64 + lane];
    half8 b1 = wf[(kc * 8 + 2 * wave + 1) * 64 + lane];
#pragma unroll
    for (int rt = 0; rt < 4; ++rt) {
      acc[rt][0] = __builtin_amdgcn_mfma_f32_16x16x32_f16(af[rt], b0, acc[rt][0], 0, 0, 0);
      acc[rt][1] = __builtin_amdgcn_mfma_f32_16x16x32_f16(af[rt], b1, acc[rt][1], 0, 0, 0);
    }
  }
  _Float16* Xp = X + (size_t)t * ((size_t)N_NODES * 128);
  int col = wave * 32 + l16;
#pragma unroll
  for (int rt = 0; rt < 4; ++rt) {
#pragma unroll
    for (int q = 0; q < 4; ++q) {
      int row = rowbase + rt * 16 + quad * 4 + q;
      if (row < N_NODES) {
        Xp[(size_t)row * 128 + col] = (_Float16)acc[rt][0][q];
        Xp[(size_t)row * 128 + col + 16] = (_Float16)acc[rt][1][q];
      }
    }
  }
}

// ---------------------------------------------------------------- CSR gather-reduce
__global__ __launch_bounds__(256) void k_gather(const _Float16* __restrict__ X,
    const int* __restrict__ ptr, const int* __restrict__ csr,
    _Float16* __restrict__ G) {
  int wave = threadIdx.x >> 6, lane = threadIdx.x & 63;
  int n = blockIdx.x * 4 + wave;
  if (n >= N_NODES) return;
  int b0 = ptr[n], b1 = ptr[n + 1];
  if (b0 < 0) b0 = 0; if (b1 > N_EDGES) b1 = N_EDGES;  // replay safety
  const size_t NC = (size_t)N_NODES * 128;
  float a00 = 0.f, a01 = 0.f, a10 = 0.f, a11 = 0.f, a20 = 0.f, a21 = 0.f;
  for (int i = b0; i < b1; ++i) {
    int v = csr[i];
    int src = v & 0xFFFF;
    int ty = (v >> 16) & 3;
    const _Float16* xp = X + (size_t)ty * NC + (size_t)src * 128 + lane * 2;
    half2v xv = *(const half2v*)xp;
    float x0 = (float)xv[0], x1 = (float)xv[1];
    if (ty == 0)      { a00 += x0; a01 += x1; }
    else if (ty == 1) { a10 += x0; a11 += x1; }
    else              { a20 += x0; a21 += x1; }
  }
  size_t go = (size_t)n * 128 + lane * 2;
  half2v o0; o0[0] = (_Float16)a00; o0[1] = (_Float16)a01;
  half2v o1; o1[0] = (_Float16)a10; o1[1] = (_Float16)a11;
  half2v o2; o2[0] = (_Float16)a20; o2[1] = (_Float16)a21;
  *(half2v*)(G + go) = o0;
  *(half2v*)(G + NC + go) = o1;
  *(half2v*)(G + 2 * NC + go) = o2;
}

// ---------------------------------------------------------------- batched fused GRU (MFMA)
// Sout[t] = GRU(G[t], M_t). grid = 3 * NB * 2 (col-space split in half).
// Wave = 64 rows x 16 cols: unit u = half*4+wave owns r-ct u, z-ct 8+u, n-ct u.
// Per kc: 3 B-frag loads reused across 4 row-tiles (12 MFMAs). Ping-pong S
// buffers (Mbase != Sout) so no cross-block in-place hazard.
__global__ __launch_bounds__(256, 3) void k_gru(const _Float16* __restrict__ G,
    const float* __restrict__ Mbase, const size_t mstride, float* __restrict__ Sout,
    const _Float16* __restrict__ Wrz, const _Float16* __restrict__ Wni,
    const _Float16* __restrict__ Wnh, const float* __restrict__ bi2,
    const float* __restrict__ bh2) {
  int bid = blockIdx.x;
  int t = bid / (2 * NB);
  int rem = bid - t * 2 * NB;
  int blk = rem >> 1, half = rem & 1;
  int wave = threadIdx.x >> 6, lane = threadIdx.x & 63;
  int quad = lane >> 4, l16 = lane & 15;
  int u = half * 4 + wave;
  int rowbase = blk * 64;
  const size_t NC = (size_t)N_NODES * 128;
  const float* M = Mbase + mstride * t;
  const _Float16* Gp = G + (size_t)t * NC;
  float* Sp = Sout + (size_t)t * NC;
  const half8* wrz = (const half8*)(Wrz + (size_t)t * 65536);
  const half8* wni = (const half8*)(Wni + (size_t)t * 16384);
  const half8* wnh = (const half8*)(Wnh + (size_t)t * 16384);
  const float* bi = bi2 + (size_t)t * 384;
  const float* bh = bh2 + (size_t)t * 384;
  int ar[4];
#pragma unroll
  for (int rt = 0; rt < 4; ++rt) {
    int r = rowbase + rt * 16 + l16;
    ar[rt] = r < N_NODES ? r : N_NODES - 1;
  }
  floatx4 zero = {0.f, 0.f, 0.f, 0.f};
  floatx4 aR[4], aZ[4], aNI[4], aNH[4];
#pragma unroll
  for (int rt = 0; rt < 4; ++rt) { aR[rt] = zero; aZ[rt] = zero; aNI[rt] = zero; aNH[rt] = zero; }
#pragma unroll
  for (int kc = 0; kc < 8; ++kc) {
    half8 af[4];
    if (kc < 4) {
#pragma unroll
      for (int rt = 0; rt < 4; ++rt)
        af[rt] = *(const half8*)(Gp + (size_t)ar[rt] * 128 + kc * 32 + quad * 8);
    } else {
#pragma unroll
      for (int rt = 0; rt < 4; ++rt) {
        const float* ap = M + (size_t)ar[rt] * 128 + (kc - 4) * 32 + quad * 8;
        floatx4 a0 = *(const floatx4*)ap;
        floatx4 a1 = *(const floatx4*)(ap + 4);
#pragma unroll
        for (int i = 0; i < 4; ++i) { af[rt][i] = (_Float16)a0[i]; af[rt][4 + i] = (_Float16)a1[i]; }
      }
    }
    half8 br = wrz[(kc * 16 + u) * 64 + lane];
    half8 bz = wrz[(kc * 16 + 8 + u) * 64 + lane];
    half8 bn = (kc < 4) ? wni[(kc * 8 + u) * 64 + lane] : wnh[((kc - 4) * 8 + u) * 64 + lane];
    if (kc < 4) {
#pragma unroll
      for (int rt = 0; rt < 4; ++rt) {
        aR[rt] = __builtin_amdgcn_mfma_f32_16x16x32_f16(af[rt], br, aR[rt], 0, 0, 0);
        aZ[rt] = __builtin_amdgcn_mfma_f32_16x16x32_f16(af[rt], bz, aZ[rt], 0, 0, 0);
        aNI[rt] = __builtin_amdgcn_mfma_f32_16x16x32_f16(af[rt], bn, aNI[rt], 0, 0, 0);
      }
    } else {
#pragma unroll
      for (int rt = 0; rt < 4; ++rt) {
        aR[rt] = __builtin_amdgcn_mfma_f32_16x16x32_f16(af[rt], br, aR[rt], 0, 0, 0);
        aZ[rt] = __builtin_amdgcn_mfma_f32_16x16x32_f16(af[rt], bz, aZ[rt], 0, 0, 0);
        aNH[rt] = __builtin_amdgcn_mfma_f32_16x16x32_f16(af[rt], bn, aNH[rt], 0, 0, 0);
      }
    }
  }
  int col = u * 16 + l16;
  float br_ = bi[col] + bh[col];
  float bz_ = bi[128 + col] + bh[128 + col];
  float bin = bi[256 + col], bhn = bh[256 + col];
#pragma unroll
  for (int rt = 0; rt < 4; ++rt) {
#pragma unroll
    for (int q = 0; q < 4; ++q) {
      int row = rowbase + rt * 16 + quad * 4 + q;
      if (row < N_NODES) {
        float r = sigmoid_(aR[rt][q] + br_);
        float z = sigmoid_(aZ[rt][q] + bz_);
        float nt = tanh_(aNI[rt][q] + bin + r * (aNH[rt][q] + bhn));
        size_t o = (size_t)row * 128 + col;
        float hold = M[o];
        Sp[o] = (1.f - z) * nt + z * hold;
      }
    }
  }
}

// ---------------------------------------------------------------- LayerNorm(h + S0+S1+S2) + ReLU -> h
__global__ __launch_bounds__(256) void k_ln(float* __restrict__ h,
    const float* __restrict__ S, const float* __restrict__ gamma,
    const float* __restrict__ beta) {
  int wave = threadIdx.x >> 6, lane = threadIdx.x & 63;
  int n = blockIdx.x * 4 + wave;
  if (n >= N_NODES) return;
  const size_t NC = (size_t)N_NODES * 128;
  size_t base = (size_t)n * 128;
  float v0 = h[base + lane] + S[base + lane] + S[NC + base + lane] + S[2 * NC + base + lane];
  float v1 = h[base + 64 + lane] + S[base + 64 + lane] + S[NC + base + 64 + lane] + S[2 * NC + base + 64 + lane];
  float s = v0 + v1, sq = v0 * v0 + v1 * v1;
#pragma unroll
  for (int off = 32; off > 0; off >>= 1) {
    s += __shfl_xor(s, off);
    sq += __shfl_xor(sq, off);
  }
  float mu = s * 0.0078125f;
  float var = sq * 0.0078125f - mu * mu;
  float rs = rsqrtf(var + 1e-5f);
  float o0 = (v0 - mu) * rs * gamma[lane] + beta[lane];
  float o1 = (v1 - mu) * rs * gamma[64 + lane] + beta[64 + lane];
  h[base + lane] = fmaxf(o0, 0.f);
  h[base + 64 + lane] = fmaxf(o1, 0.f);
}

// ---------------------------------------------------------------- head layer 1 (fp32 out, bias+relu)
__global__ __launch_bounds__(256, 4) void k_gemm_head(const float* __restrict__ A,
    const _Float16* __restrict__ Wf, const float* __restrict__ bias,
    float* __restrict__ out) {
  int blk = blockIdx.x;
  int wave = threadIdx.x >> 6, lane = threadIdx.x & 63;
  int quad = lane >> 4, l16 = lane & 15;
  int rowbase = blk * 64;
  const half8* wf = (const half8*)Wf;
  int ar[4];
#pragma unroll
  for (int rt = 0; rt < 4; ++rt) {
    int r = rowbase + rt * 16 + l16;
    ar[rt] = r < N_NODES ? r : N_NODES - 1;
  }
  floatx4 zero = {0.f, 0.f, 0.f, 0.f};
  floatx4 acc[4][2];
#pragma unroll
  for (int rt = 0; rt < 4; ++rt) { acc[rt][0] = zero; acc[rt][1] = zero; }
#pragma unroll
  for (int kc = 0; kc < 4; ++kc) {
    half8 af[4];
#pragma unroll
    for (int rt = 0; rt < 4; ++rt) {
      const float* ap = A + (size_t)ar[rt] * 128 + kc * 32 + quad * 8;
      floatx4 a0 = *(const floatx4*)ap;
      floatx4 a1 = *(const floatx4*)(ap + 4);
#pragma unroll
      for (int i = 0; i < 4; ++i) { af[rt][i] = (_Float16)a0[i]; af[rt][4 + i] = (_Float16)a1[i]; }
    }
    half8 b0 = wf[(kc * 8 + 2 * wave) * 64 + lane];
    half8 b1 = wf[(kc * 8 + 2 * wave + 1) * 64 + lane];
#pragma unroll
    for (int rt = 0; rt < 4; ++rt) {
      acc[rt][0] = __builtin_amdgcn_mfma_f32_16x16x32_f16(af[rt], b0, acc[rt][0], 0, 0, 0);
      acc[rt][1] = __builtin_amdgcn_mfma_f32_16x16x32_f16(af[rt], b1, acc[rt][1], 0, 0, 0);
    }
  }
  int col = wave * 32 + l16;
#pragma unroll
  for (int rt = 0; rt < 4; ++rt) {
#pragma unroll
    for (int q = 0; q < 4; ++q) {
      int row = rowbase + rt * 16 + quad * 4 + q;
      if (row < N_NODES) {
        float* op = out + (size_t)row * 128;
        op[col] = fmaxf(acc[rt][0][q] + bias[col], 0.f);
        op[col + 16] = fmaxf(acc[rt][1][q] + bias[col + 16], 0.f);
      }
    }
  }
}

// ---------------------------------------------------------------- head layer 2
__global__ __launch_bounds__(256) void k_head2(const float* __restrict__ z,
    const float* __restrict__ w2, const float* __restrict__ b2,
    float* __restrict__ out) {
  __shared__ float w[256];
  w[threadIdx.x] = w2[threadIdx.x];
  __syncthreads();
  int t = blockIdx.x * 256 + threadIdx.x;
  int n = t >> 1, o = t & 1;
  if (n >= N_NODES) return;
  const float* zr = z + (size_t)n * 128;
  const float* wr = w + o * 128;
  float acc = 0.f;
  for (int k = 0; k < 128; k += 4) {
    float4 zv = *(const float4*)(zr + k);
    acc += zv.x * wr[k] + zv.y * wr[k+1] + zv.z * wr[k+2] + zv.w * wr[k+3];
  }
  out[(size_t)n * 2 + o] = acc + b2[o];
}

// ================================================================ launch
extern "C" void kernel_launch(void* const* d_in, const int* in_sizes, int n_in,
                              void* d_out, int out_size, void* d_ws, size_t ws_size,
                              hipStream_t stream) {
  const int*   x_type  = (const int*)d_in[0];
  const int*   x_tok   = (const int*)d_in[1];
  const float* x_small = (const float*)d_in[2];
  const int*   eidx    = (const int*)d_in[3];
  const int*   etype   = (const int*)d_in[4];
  const float* conv_w  = (const float*)d_in[5];
  const float* gwih    = (const float*)d_in[6];
  const float* gwhh    = (const float*)d_in[7];
  const float* gbih    = (const float*)d_in[8];
  const float* gbhh    = (const float*)d_in[9];
  const float* ln_g    = (const float*)d_in[10];
  const float* ln_b    = (const float*)d_in[11];
  const float* hw1     = (const float*)d_in[12];
  const float* hb1     = (const float*)d_in[13];
  const float* hw2     = (const float*)d_in[14];
  const float* hb2     = (const float*)d_in[15];
  float* out = (float*)d_out;

  const size_t NC = (size_t)N_NODES * 128;
  char* W = (char*)d_ws;
  size_t off = 0;
  float* h  = (float*)(W + off);            off += NC * 4;            // 25.6 MB
  float* S0 = (float*)(W + off);            off += 3 * NC * 4;        // 76.8 MB
  float* S1 = (float*)(W + off);            off += 3 * NC * 4;        // 76.8 MB
  _Float16* X = (_Float16*)(W + off);       off += 3 * NC * 2;        // 38.4 MB
  _Float16* G = (_Float16*)(W + off);       off += 3 * NC * 2;        // 38.4 MB
  int* counts = (int*)(W + off);            off += (N_NODES + 1) * 4;
  int* ptrv   = (int*)(W + off);            off += (N_NODES + 1) * 4;
  int* fill   = (int*)(W + off);            off += (N_NODES + 1) * 4;
  int* bsum   = (int*)(W + off);            off += (NCHUNK + 1) * 4;
  int* boff   = (int*)(W + off);            off += (NCHUNK + 1) * 4;
  int* csr    = (int*)(W + off);            off += (size_t)N_EDGES * 4;
  _Float16* WRZ = (_Float16*)(W + off);     off += (size_t)6 * 65536 * 2;
  _Float16* WNI = (_Float16*)(W + off);     off += (size_t)6 * 16384 * 2;
  _Float16* WNH = (_Float16*)(W + off);     off += (size_t)6 * 16384 * 2;
  _Float16* WC  = (_Float16*)(W + off);     off += (size_t)18 * 16384 * 2;
  _Float16* W1F = (_Float16*)(W + off);     off += (size_t)16384 * 2;

  // ---- per-call prep
  k_features<<<(N_NODES * 128 + 255) / 256, 256, 0, stream>>>(h, x_type, x_tok, x_small);
  hipMemsetAsync(counts, 0, (size_t)N_NODES * 4, stream);
  k_hist<<<(N_EDGES + 255) / 256, 256, 0, stream>>>(eidx, counts);
  k_scan_a<<<NCHUNK, 256, 0, stream>>>(counts, bsum);
  k_scan_b<<<1, 256, 0, stream>>>(bsum, boff);
  k_scan_c<<<NCHUNK, 256, 0, stream>>>(counts, boff, ptrv, fill);
  k_place<<<(N_EDGES + 255) / 256, 256, 0, stream>>>(eidx, etype, fill, csr);
  k_prep_rz<<<(6 * 8 * 16 * 512 + 255) / 256, 256, 0, stream>>>(gwih, gwhh, WRZ);
  k_prep_n<<<(6 * 4 * 8 * 512 + 255) / 256, 256, 0, stream>>>(gwih, gwhh, WNI, WNH);
  k_prep_conv<<<(18 * 4 * 8 * 512 + 255) / 256, 256, 0, stream>>>(conv_w, WC);
  k_prep_w1<<<(4 * 8 * 512 + 255) / 256, 256, 0, stream>>>(hw1, W1F);

  // ---- main loop: 2 blocks x 3 steps; types batched; ping-pong S0/S1
  for (int b = 0; b < 2; ++b) {
    for (int s = 0; s < 3; ++s) {
      const float* Ab = (s == 0) ? h : ((s == 1) ? S0 : S1);
      size_t astr = (s == 0) ? 0 : NC;
      float* Sout = (s == 1) ? S1 : S0;
      k_conv<<<3 * NB, 256, 0, stream>>>(Ab, astr, WC + (size_t)(b * 9 + s) * 16384, X);
      k_gather<<<(N_NODES + 3) / 4, 256, 0, stream>>>(X, ptrv, csr, G);
      k_gru<<<3 * NB * 2, 256, 0, stream>>>(G, Ab, astr, Sout,
          WRZ + (size_t)b * 3 * 65536, WNI + (size_t)b * 3 * 16384, WNH + (size_t)b * 3 * 16384,
          gbih + (size_t)b * 3 * 384, gbhh + (size_t)b * 3 * 384);
    }
    k_ln<<<(N_NODES + 3) / 4, 256, 0, stream>>>(h, S0, ln_g + b * 128, ln_b + b * 128);
  }
  // ---- head (z stored in S0, dead after last LN)
  k_gemm_head<<<NB, 256, 0, stream>>>(h, W1F, hb1, S0);
  k_head2<<<(2 * N_NODES + 255) / 256, 256, 0, stream>>>(S0, hw2, hb2, out);
}

// Round 5
// 1126.153 us; speedup vs baseline: 7.2861x; 1.5141x over previous
//
#include <hip/hip_runtime.h>
#include <cstdint>
#include <cstddef>

// Problem constants (match reference)
#define N_NODES 50000
#define N_EDGES 500000
#define NB 782              // ceil(N_NODES/64) row-blocks
#define NCHUNK 196          // ceil(N_NODES/256) scan chunks
#define FS 49152            // frag halfs per [128x384] matrix (4*24*512)
// C = 128, STEPS = 3, BLOCKS = 2, NUM_ET = 3

typedef _Float16 half8 __attribute__((ext_vector_type(8)));
typedef _Float16 half2v __attribute__((ext_vector_type(2)));
typedef float floatx4 __attribute__((ext_vector_type(4)));

__device__ __forceinline__ float sigmoid_(float x) { return 1.f / (1.f + __expf(-x)); }
__device__ __forceinline__ float tanh_(float x) {
  float t = __expf(-2.f * fabsf(x));
  float r = (1.f - t) / (1.f + t);
  return copysignf(r, x);
}

// ---------------------------------------------------------------- features (fp16 h)
__global__ __launch_bounds__(256) void k_features(_Float16* __restrict__ h,
    const int* __restrict__ xtype, const int* __restrict__ xtok,
    const float* __restrict__ xs) {
  int idx = blockIdx.x * 256 + threadIdx.x;
  if (idx >= N_NODES * 128) return;
  int n = idx >> 7, c = idx & 127;
  float v;
  if (c < 32) {
    v = (xtype[n] == c) ? 1.f : 0.f;
  } else if (c < 126) {
    int tk = xtok[n];
    tk = tk < 0 ? 0 : (tk > 93 ? 93 : tk);
    v = (tk == (c - 32)) ? 1.f : 0.f;
  } else {
    v = xs[n * 2 + (c - 126)];
  }
  h[idx] = (_Float16)v;
}

// ---------------------------------------------------------------- CSR build
__global__ __launch_bounds__(256) void k_hist(const int* __restrict__ ei,
    int* __restrict__ counts) {
  int e = blockIdx.x * 256 + threadIdx.x;
  if (e >= N_EDGES) return;
  int d = ei[N_EDGES + e];
  if ((unsigned)d < N_NODES) atomicAdd(&counts[d], 1);
}

__global__ __launch_bounds__(256) void k_scan_a(const int* __restrict__ counts,
    int* __restrict__ bsum) {
  int i = blockIdx.x * 256 + threadIdx.x;
  int v = (i < N_NODES) ? counts[i] : 0;
  int lane = threadIdx.x & 63, wv = threadIdx.x >> 6;
#pragma unroll
  for (int off = 32; off > 0; off >>= 1) v += __shfl_xor(v, off);
  __shared__ int ws[4];
  if (lane == 0) ws[wv] = v;
  __syncthreads();
  if (threadIdx.x == 0) bsum[blockIdx.x] = ws[0] + ws[1] + ws[2] + ws[3];
}

__global__ __launch_bounds__(256) void k_scan_b(const int* __restrict__ bsum,
    int* __restrict__ boff) {
  int i = threadIdx.x;
  int v = (i < NCHUNK) ? bsum[i] : 0;
  int lane = i & 63, wv = i >> 6;
  int s = v;
#pragma unroll
  for (int off = 1; off < 64; off <<= 1) { int u = __shfl_up(s, off); if (lane >= off) s += u; }
  __shared__ int ws[4];
  if (lane == 63) ws[wv] = s;
  __syncthreads();
  int woff = 0;
#pragma unroll
  for (int w = 0; w < 4; ++w) woff += (w < wv) ? ws[w] : 0;
  if (i < NCHUNK) boff[i] = woff + s - v;
  if (i == 255) boff[NCHUNK] = ws[0] + ws[1] + ws[2] + ws[3];
}

__global__ __launch_bounds__(256) void k_scan_c(const int* __restrict__ counts,
    const int* __restrict__ boff, int* __restrict__ ptr, int* __restrict__ fill) {
  int i = blockIdx.x * 256 + threadIdx.x;
  int v = (i < N_NODES) ? counts[i] : 0;
  int lane = threadIdx.x & 63, wv = threadIdx.x >> 6;
  int s = v;
#pragma unroll
  for (int off = 1; off < 64; off <<= 1) { int u = __shfl_up(s, off); if (lane >= off) s += u; }
  __shared__ int ws[4];
  if (lane == 63) ws[wv] = s;
  __syncthreads();
  int woff = 0;
#pragma unroll
  for (int w = 0; w < 4; ++w) woff += (w < wv) ? ws[w] : 0;
  int excl = boff[blockIdx.x] + woff + s - v;
  if (i < N_NODES) { ptr[i] = excl; fill[i] = excl; }
  if (blockIdx.x == 0 && threadIdx.x == 0) ptr[N_NODES] = boff[NCHUNK];
}

__global__ __launch_bounds__(256) void k_place(const int* __restrict__ ei,
    const int* __restrict__ et, int* __restrict__ fill, int* __restrict__ csr) {
  int e = blockIdx.x * 256 + threadIdx.x;
  if (e >= N_EDGES) return;
  int srcv = ei[e], d = ei[N_EDGES + e], ty = et[e];
  if ((unsigned)d >= N_NODES || (unsigned)srcv >= N_NODES) return;
  int pos = atomicAdd(&fill[d], 1);
  if ((unsigned)pos < N_EDGES) csr[pos] = (srcv & 0xFFFF) | ((ty & 3) << 16);
}

// ---------------------------------------------------------------- weight prep
// B-frag layout (384-col matrices, CT=24):
//   frag[((kc*24+ct)*64 + lane)*8 + j] = W[k = kc*32+(lane>>4)*8+j][n = ct*16+(lane&15)]

// Wcomb[mat][k][n] = sum_j conv_w[mat][k][j] * wih[bt][n][j]   (mat = (b*3+t)*3+s, bt = mat/3)
__global__ __launch_bounds__(256) void k_prep_comb(const float* __restrict__ cw,
    const float* __restrict__ wih, _Float16* __restrict__ dst) {
  int idx = blockIdx.x * 256 + threadIdx.x;
  if (idx >= 18 * 4 * 24 * 512) return;
  int j = idx & 7, lane = (idx >> 3) & 63;
  int r = idx >> 9;
  int ct = r % 24;
  int r2 = r / 24;
  int kc = r2 & 3, mat = r2 >> 2;
  int bt = mat / 3;
  int k = kc * 32 + ((lane >> 4) & 3) * 8 + j;
  int n = ct * 16 + (lane & 15);
  const float* wrow = cw + ((size_t)mat * 128 + k) * 128;
  const float* irow = wih + ((size_t)bt * 384 + n) * 128;
  float acc = 0.f;
#pragma unroll
  for (int q = 0; q < 128; q += 4) {
    floatx4 a = *(const floatx4*)(wrow + q);
    floatx4 b = *(const floatx4*)(irow + q);
    acc += a[0] * b[0] + a[1] * b[1] + a[2] * b[2] + a[3] * b[3];
  }
  dst[idx] = (_Float16)acc;
}

// whh frag (all 384 cols)
__global__ __launch_bounds__(256) void k_prep_whh(const float* __restrict__ whh,
    _Float16* __restrict__ dst) {
  int idx = blockIdx.x * 256 + threadIdx.x;
  if (idx >= 6 * 4 * 24 * 512) return;
  int j = idx & 7, lane = (idx >> 3) & 63;
  int r = idx >> 9;
  int ct = r % 24;
  int r2 = r / 24;
  int kc = r2 & 3, bt = r2 >> 2;
  int k = kc * 32 + ((lane >> 4) & 3) * 8 + j;
  int n = ct * 16 + (lane & 15);
  dst[idx] = (_Float16)whh[((size_t)bt * 384 + n) * 128 + k];
}

// head w1 frag (128 cols, CT=8)
__global__ __launch_bounds__(256) void k_prep_w1(const float* __restrict__ hw1,
    _Float16* __restrict__ dst) {
  int idx = blockIdx.x * 256 + threadIdx.x;
  if (idx >= 4 * 8 * 512) return;
  int j = idx & 7, lane = (idx >> 3) & 63, ct = (idx >> 9) & 7, kc = (idx >> 12) & 3;
  int k = kc * 32 + ((lane >> 4) & 3) * 8 + j;
  int n = ct * 16 + (lane & 15);
  dst[idx] = (_Float16)hw1[n * 128 + k];
}

// ---------------------------------------------------------------- CSR gather-reduce (fp16 state)
// P[t][n] = sum over type-t in-edges of m_t[src]. Wave per node, lane = 2 ch.
__global__ __launch_bounds__(256) void k_gather(const _Float16* __restrict__ Mbase,
    const size_t mstride, const int* __restrict__ ptr, const int* __restrict__ csr,
    _Float16* __restrict__ P) {
  int wave = threadIdx.x >> 6, lane = threadIdx.x & 63;
  int n = blockIdx.x * 4 + wave;
  if (n >= N_NODES) return;
  int b0 = ptr[n], b1 = ptr[n + 1];
  if (b0 < 0) b0 = 0; if (b1 > N_EDGES) b1 = N_EDGES;  // replay safety
  const size_t NC = (size_t)N_NODES * 128;
  float a00 = 0.f, a01 = 0.f, a10 = 0.f, a11 = 0.f, a20 = 0.f, a21 = 0.f;
  int i = b0;
  for (; i + 2 <= b1; i += 2) {
    int v0 = csr[i], v1 = csr[i + 1];
    int s0 = v0 & 0xFFFF, t0 = (v0 >> 16) & 3;
    int s1 = v1 & 0xFFFF, t1 = (v1 >> 16) & 3;
    half2v x0 = *(const half2v*)(Mbase + mstride * t0 + (size_t)s0 * 128 + lane * 2);
    half2v x1 = *(const half2v*)(Mbase + mstride * t1 + (size_t)s1 * 128 + lane * 2);
    float p0 = (float)x0[0], p1 = (float)x0[1];
    float q0 = (float)x1[0], q1 = (float)x1[1];
    if (t0 == 0)      { a00 += p0; a01 += p1; }
    else if (t0 == 1) { a10 += p0; a11 += p1; }
    else              { a20 += p0; a21 += p1; }
    if (t1 == 0)      { a00 += q0; a01 += q1; }
    else if (t1 == 1) { a10 += q0; a11 += q1; }
    else              { a20 += q0; a21 += q1; }
  }
  if (i < b1) {
    int v0 = csr[i];
    int s0 = v0 & 0xFFFF, t0 = (v0 >> 16) & 3;
    half2v x0 = *(const half2v*)(Mbase + mstride * t0 + (size_t)s0 * 128 + lane * 2);
    float p0 = (float)x0[0], p1 = (float)x0[1];
    if (t0 == 0)      { a00 += p0; a01 += p1; }
    else if (t0 == 1) { a10 += p0; a11 += p1; }
    else              { a20 += p0; a21 += p1; }
  }
  size_t go = (size_t)n * 128 + lane * 2;
  half2v o0; o0[0] = (_Float16)a00; o0[1] = (_Float16)a01;
  half2v o1; o1[0] = (_Float16)a10; o1[1] = (_Float16)a11;
  half2v o2; o2[0] = (_Float16)a20; o2[1] = (_Float16)a21;
  *(half2v*)(P + go) = o0;
  *(half2v*)(P + NC + go) = o1;
  *(half2v*)(P + 2 * NC + go) = o2;
}

// ---------------------------------------------------------------- batched fused GRU (MFMA, fp16 state)
// gi = P @ Wcomb + bih (conv folded in), gh = m @ whh.T + bhh.
// grid = 3*NB*2 (col-half split). Wave = 64 rows x 16 cols: unit u owns
// cts {u (r), 8+u (z), 16+u (n)} of the 24. Ping-pong S buffers.
__global__ __launch_bounds__(256, 3) void k_gru(const _Float16* __restrict__ P,
    const _Float16* __restrict__ Mbase, const size_t mstride, _Float16* __restrict__ Sout,
    const _Float16* __restrict__ WPC, const _Float16* __restrict__ WHH,
    const float* __restrict__ bi2, const float* __restrict__ bh2) {
  int bid = blockIdx.x;
  int t = bid / (2 * NB);
  int rem = bid - t * 2 * NB;
  int blk = rem >> 1, half = rem & 1;
  int wave = threadIdx.x >> 6, lane = threadIdx.x & 63;
  int quad = lane >> 4, l16 = lane & 15;
  int u = half * 4 + wave;
  int rowbase = blk * 64;
  const size_t NC = (size_t)N_NODES * 128;
  const _Float16* Mp = Mbase + mstride * t;
  const _Float16* Pp = P + (size_t)t * NC;
  _Float16* Sp = Sout + (size_t)t * NC;
  const half8* wpc = (const half8*)(WPC + (size_t)t * 3 * FS);  // mat stride 3 per t
  const half8* whh = (const half8*)(WHH + (size_t)t * FS);
  const float* bi = bi2 + (size_t)t * 384;
  const float* bh = bh2 + (size_t)t * 384;
  int ar[4];
#pragma unroll
  for (int rt = 0; rt < 4; ++rt) {
    int r = rowbase + rt * 16 + l16;
    ar[rt] = r < N_NODES ? r : N_NODES - 1;
  }
  floatx4 zero = {0.f, 0.f, 0.f, 0.f};
  floatx4 aR[4], aZ[4], aNP[4], aNM[4];
#pragma unroll
  for (int rt = 0; rt < 4; ++rt) { aR[rt] = zero; aZ[rt] = zero; aNP[rt] = zero; aNM[rt] = zero; }
#pragma unroll
  for (int kc = 0; kc < 8; ++kc) {
    half8 af[4];
    if (kc < 4) {
#pragma unroll
      for (int rt = 0; rt < 4; ++rt)
        af[rt] = *(const half8*)(Pp + (size_t)ar[rt] * 128 + kc * 32 + quad * 8);
      half8 br = wpc[(kc * 24 + u) * 64 + lane];
      half8 bz = wpc[(kc * 24 + 8 + u) * 64 + lane];
      half8 bn = wpc[(kc * 24 + 16 + u) * 64 + lane];
#pragma unroll
      for (int rt = 0; rt < 4; ++rt) {
        aR[rt] = __builtin_amdgcn_mfma_f32_16x16x32_f16(af[rt], br, aR[rt], 0, 0, 0);
        aZ[rt] = __builtin_amdgcn_mfma_f32_16x16x32_f16(af[rt], bz, aZ[rt], 0, 0, 0);
        aNP[rt] = __builtin_amdgcn_mfma_f32_16x16x32_f16(af[rt], bn, aNP[rt], 0, 0, 0);
      }
    } else {
      int kk = kc - 4;
#pragma unroll
      for (int rt = 0; rt < 4; ++rt)
        af[rt] = *(const half8*)(Mp + (size_t)ar[rt] * 128 + kk * 32 + quad * 8);
      half8 br = whh[(kk * 24 + u) * 64 + lane];
      half8 bz = whh[(kk * 24 + 8 + u) * 64 + lane];
      half8 bn = whh[(kk * 24 + 16 + u) * 64 + lane];
#pragma unroll
      for (int rt = 0; rt < 4; ++rt) {
        aR[rt] = __builtin_amdgcn_mfma_f32_16x16x32_f16(af[rt], br, aR[rt], 0, 0, 0);
        aZ[rt] = __builtin_amdgcn_mfma_f32_16x16x32_f16(af[rt], bz, aZ[rt], 0, 0, 0);
        aNM[rt] = __builtin_amdgcn_mfma_f32_16x16x32_f16(af[rt], bn, aNM[rt], 0, 0, 0);
      }
    }
  }
  int col = u * 16 + l16;
  float br_ = bi[col] + bh[col];
  float bz_ = bi[128 + col] + bh[128 + col];
  float bin = bi[256 + col], bhn = bh[256 + col];
#pragma unroll
  for (int rt = 0; rt < 4; ++rt) {
#pragma unroll
    for (int q = 0; q < 4; ++q) {
      int row = rowbase + rt * 16 + quad * 4 + q;
      if (row < N_NODES) {
        float r = sigmoid_(aR[rt][q] + br_);
        float z = sigmoid_(aZ[rt][q] + bz_);
        float nt = tanh_(aNP[rt][q] + bin + r * (aNM[rt][q] + bhn));
        size_t o = (size_t)row * 128 + col;
        float hold = (float)Mp[o];
        Sp[o] = (_Float16)((1.f - z) * nt + z * hold);
      }
    }
  }
}

// ---------------------------------------------------------------- LayerNorm(h + S0+S1+S2) + ReLU -> h (fp16)
__global__ __launch_bounds__(256) void k_ln(_Float16* __restrict__ h,
    const _Float16* __restrict__ S, const float* __restrict__ gamma,
    const float* __restrict__ beta) {
  int wave = threadIdx.x >> 6, lane = threadIdx.x & 63;
  int n = blockIdx.x * 4 + wave;
  if (n >= N_NODES) return;
  const size_t NC = (size_t)N_NODES * 128;
  size_t base = (size_t)n * 128 + lane * 2;
  half2v hv = *(const half2v*)(h + base);
  half2v s0 = *(const half2v*)(S + base);
  half2v s1 = *(const half2v*)(S + NC + base);
  half2v s2 = *(const half2v*)(S + 2 * NC + base);
  float v0 = (float)hv[0] + (float)s0[0] + (float)s1[0] + (float)s2[0];
  float v1 = (float)hv[1] + (float)s0[1] + (float)s1[1] + (float)s2[1];
  float s = v0 + v1, sq = v0 * v0 + v1 * v1;
#pragma unroll
  for (int off = 32; off > 0; off >>= 1) {
    s += __shfl_xor(s, off);
    sq += __shfl_xor(sq, off);
  }
  float mu = s * 0.0078125f;
  float var = sq * 0.0078125f - mu * mu;
  float rs = rsqrtf(var + 1e-5f);
  float o0 = (v0 - mu) * rs * gamma[lane * 2] + beta[lane * 2];
  float o1 = (v1 - mu) * rs * gamma[lane * 2 + 1] + beta[lane * 2 + 1];
  half2v ov; ov[0] = (_Float16)fmaxf(o0, 0.f); ov[1] = (_Float16)fmaxf(o1, 0.f);
  *(half2v*)(h + base) = ov;
}

// ---------------------------------------------------------------- head layer 1 (fp16 A, fp32 out, bias+relu)
__global__ __launch_bounds__(256, 4) void k_gemm_head(const _Float16* __restrict__ A,
    const _Float16* __restrict__ Wf, const float* __restrict__ bias,
    float* __restrict__ out) {
  int blk = blockIdx.x;
  int wave = threadIdx.x >> 6, lane = threadIdx.x & 63;
  int quad = lane >> 4, l16 = lane & 15;
  int rowbase = blk * 64;
  const half8* wf = (const half8*)Wf;
  int ar[4];
#pragma unroll
  for (int rt = 0; rt < 4; ++rt) {
    int r = rowbase + rt * 16 + l16;
    ar[rt] = r < N_NODES ? r : N_NODES - 1;
  }
  floatx4 zero = {0.f, 0.f, 0.f, 0.f};
  floatx4 acc[4][2];
#pragma unroll
  for (int rt = 0; rt < 4; ++rt) { acc[rt][0] = zero; acc[rt][1] = zero; }
#pragma unroll
  for (int kc = 0; kc < 4; ++kc) {
    half8 af[4];
#pragma unroll
    for (int rt = 0; rt < 4; ++rt)
      af[rt] = *(const half8*)(A + (size_t)ar[rt] * 128 + kc * 32 + quad * 8);
    half8 b0 = wf[(kc * 8 + 2 * wave) * 64 + lane];
    half8 b1 = wf[(kc * 8 + 2 * wave + 1) * 64 + lane];
#pragma unroll
    for (int rt = 0; rt < 4; ++rt) {
      acc[rt][0] = __builtin_amdgcn_mfma_f32_16x16x32_f16(af[rt], b0, acc[rt][0], 0, 0, 0);
      acc[rt][1] = __builtin_amdgcn_mfma_f32_16x16x32_f16(af[rt], b1, acc[rt][1], 0, 0, 0);
    }
  }
  int col = wave * 32 + l16;
#pragma unroll
  for (int rt = 0; rt < 4; ++rt) {
#pragma unroll
    for (int q = 0; q < 4; ++q) {
      int row = rowbase + rt * 16 + quad * 4 + q;
      if (row < N_NODES) {
        float* op = out + (size_t)row * 128;
        op[col] = fmaxf(acc[rt][0][q] + bias[col], 0.f);
        op[col + 16] = fmaxf(acc[rt][1][q] + bias[col + 16], 0.f);
      }
    }
  }
}

// ---------------------------------------------------------------- head layer 2
__global__ __launch_bounds__(256) void k_head2(const float* __restrict__ z,
    const float* __restrict__ w2, const float* __restrict__ b2,
    float* __restrict__ out) {
  __shared__ float w[256];
  w[threadIdx.x] = w2[threadIdx.x];
  __syncthreads();
  int t = blockIdx.x * 256 + threadIdx.x;
  int n = t >> 1, o = t & 1;
  if (n >= N_NODES) return;
  const float* zr = z + (size_t)n * 128;
  const float* wr = w + o * 128;
  float acc = 0.f;
  for (int k = 0; k < 128; k += 4) {
    float4 zv = *(const float4*)(zr + k);
    acc += zv.x * wr[k] + zv.y * wr[k+1] + zv.z * wr[k+2] + zv.w * wr[k+3];
  }
  out[(size_t)n * 2 + o] = acc + b2[o];
}

// ================================================================ launch
extern "C" void kernel_launch(void* const* d_in, const int* in_sizes, int n_in,
                              void* d_out, int out_size, void* d_ws, size_t ws_size,
                              hipStream_t stream) {
  const int*   x_type  = (const int*)d_in[0];
  const int*   x_tok   = (const int*)d_in[1];
  const float* x_small = (const float*)d_in[2];
  const int*   eidx    = (const int*)d_in[3];
  const int*   etype   = (const int*)d_in[4];
  const float* conv_w  = (const float*)d_in[5];
  const float* gwih    = (const float*)d_in[6];
  const float* gwhh    = (const float*)d_in[7];
  const float* gbih    = (const float*)d_in[8];
  const float* gbhh    = (const float*)d_in[9];
  const float* ln_g    = (const float*)d_in[10];
  const float* ln_b    = (const float*)d_in[11];
  const float* hw1     = (const float*)d_in[12];
  const float* hb1     = (const float*)d_in[13];
  const float* hw2     = (const float*)d_in[14];
  const float* hb2     = (const float*)d_in[15];
  float* out = (float*)d_out;

  const size_t NC = (size_t)N_NODES * 128;
  char* W = (char*)d_ws;
  size_t off = 0;
  _Float16* h16 = (_Float16*)(W + off);     off += NC * 2;            // 12.8 MB
  _Float16* S0  = (_Float16*)(W + off);     off += 3 * NC * 2;        // 38.4 MB
  _Float16* S1  = (_Float16*)(W + off);     off += 3 * NC * 2;        // 38.4 MB
  _Float16* P   = (_Float16*)(W + off);     off += 3 * NC * 2;        // 38.4 MB
  float* zbuf   = (float*)(W + off);        off += NC * 4;            // 25.6 MB
  int* counts = (int*)(W + off);            off += (N_NODES + 1) * 4;
  int* ptrv   = (int*)(W + off);            off += (N_NODES + 1) * 4;
  int* fill   = (int*)(W + off);            off += (N_NODES + 1) * 4;
  int* bsum   = (int*)(W + off);            off += (NCHUNK + 1) * 4;
  int* boff   = (int*)(W + off);            off += (NCHUNK + 1) * 4;
  int* csr    = (int*)(W + off);            off += (size_t)N_EDGES * 4;
  _Float16* WPC = (_Float16*)(W + off);     off += (size_t)18 * FS * 2;  // conv@wih.T frags
  _Float16* WHH = (_Float16*)(W + off);     off += (size_t)6 * FS * 2;
  _Float16* W1F = (_Float16*)(W + off);     off += (size_t)16384 * 2;

  // ---- per-call prep
  k_features<<<(N_NODES * 128 + 255) / 256, 256, 0, stream>>>(h16, x_type, x_tok, x_small);
  hipMemsetAsync(counts, 0, (size_t)N_NODES * 4, stream);
  k_hist<<<(N_EDGES + 255) / 256, 256, 0, stream>>>(eidx, counts);
  k_scan_a<<<NCHUNK, 256, 0, stream>>>(counts, bsum);
  k_scan_b<<<1, 256, 0, stream>>>(bsum, boff);
  k_scan_c<<<NCHUNK, 256, 0, stream>>>(counts, boff, ptrv, fill);
  k_place<<<(N_EDGES + 255) / 256, 256, 0, stream>>>(eidx, etype, fill, csr);
  k_prep_comb<<<(18 * 4 * 24 * 512 + 255) / 256, 256, 0, stream>>>(conv_w, gwih, WPC);
  k_prep_whh<<<(6 * 4 * 24 * 512 + 255) / 256, 256, 0, stream>>>(gwhh, WHH);
  k_prep_w1<<<(4 * 8 * 512 + 255) / 256, 256, 0, stream>>>(hw1, W1F);

  // ---- main loop: 2 blocks x 3 steps; conv folded into GRU via Wcomb; fp16 state
  for (int b = 0; b < 2; ++b) {
    for (int s = 0; s < 3; ++s) {
      const _Float16* Msrc = (s == 0) ? h16 : ((s == 1) ? S0 : S1);
      size_t mstr = (s == 0) ? 0 : NC;
      _Float16* Sout = (s == 1) ? S1 : S0;
      k_gather<<<(N_NODES + 3) / 4, 256, 0, stream>>>(Msrc, mstr, ptrv, csr, P);
      k_gru<<<3 * NB * 2, 256, 0, stream>>>(P, Msrc, mstr, Sout,
          WPC + (size_t)(b * 9 + s) * FS, WHH + (size_t)b * 3 * FS,
          gbih + (size_t)b * 3 * 384, gbhh + (size_t)b * 3 * 384);
    }
    k_ln<<<(N_NODES + 3) / 4, 256, 0, stream>>>(h16, S0, ln_g + b * 128, ln_b + b * 128);
  }
  // ---- head
  k_gemm_head<<<NB, 256, 0, stream>>>(h16, W1F, hb1, zbuf);
  k_head2<<<(2 * N_NODES + 255) / 256, 256, 0, stream>>>(zbuf, hw2, hb2, out);
}

// Round 6
// 967.887 us; speedup vs baseline: 8.4775x; 1.1635x over previous
//
#include <hip/hip_runtime.h>
#include <cstdint>
#include <cstddef>

// Problem constants (match reference)
#define N_NODES 50000
#define N_EDGES 500000
#define NB 782              // ceil(N_NODES/64) row-blocks
#define NT 150000           // 3 * N_NODES (typed CSR)
#define NCHUNK2 586         // ceil(NT/256) scan chunks
#define FS 49152            // frag halfs per [128x384] matrix (4*24*512)
#define PSTR 136            // LDS row stride in halfs (+8 pad -> bank-spread)
// C = 128, STEPS = 3, BLOCKS = 2, NUM_ET = 3

typedef _Float16 half8 __attribute__((ext_vector_type(8)));
typedef _Float16 half2v __attribute__((ext_vector_type(2)));
typedef float floatx4 __attribute__((ext_vector_type(4)));

__device__ __forceinline__ float sigmoid_(float x) { return 1.f / (1.f + __expf(-x)); }
__device__ __forceinline__ float tanh_(float x) {
  float t = __expf(-2.f * fabsf(x));
  float r = (1.f - t) / (1.f + t);
  return copysignf(r, x);
}

// ---------------------------------------------------------------- features (fp16 h)
__global__ __launch_bounds__(256) void k_features(_Float16* __restrict__ h,
    const int* __restrict__ xtype, const int* __restrict__ xtok,
    const float* __restrict__ xs) {
  int idx = blockIdx.x * 256 + threadIdx.x;
  if (idx >= N_NODES * 128) return;
  int n = idx >> 7, c = idx & 127;
  float v;
  if (c < 32) {
    v = (xtype[n] == c) ? 1.f : 0.f;
  } else if (c < 126) {
    int tk = xtok[n];
    tk = tk < 0 ? 0 : (tk > 93 ? 93 : tk);
    v = (tk == (c - 32)) ? 1.f : 0.f;
  } else {
    v = xs[n * 2 + (c - 126)];
  }
  h[idx] = (_Float16)v;
}

// ---------------------------------------------------------------- typed-CSR build
// key = type * N_NODES + dst; dense per-type edge lists (no filter in gather).
__global__ __launch_bounds__(256) void k_hist(const int* __restrict__ ei,
    const int* __restrict__ et, int* __restrict__ counts) {
  int e = blockIdx.x * 256 + threadIdx.x;
  if (e >= N_EDGES) return;
  int d = ei[N_EDGES + e];
  int ty = et[e] & 3;
  if ((unsigned)d < N_NODES && ty < 3) atomicAdd(&counts[ty * N_NODES + d], 1);
}

__global__ __launch_bounds__(256) void k_scan_a(const int* __restrict__ counts,
    int* __restrict__ bsum) {
  int i = blockIdx.x * 256 + threadIdx.x;
  int v = (i < NT) ? counts[i] : 0;
  int lane = threadIdx.x & 63, wv = threadIdx.x >> 6;
#pragma unroll
  for (int off = 32; off > 0; off >>= 1) v += __shfl_xor(v, off);
  __shared__ int ws[4];
  if (lane == 0) ws[wv] = v;
  __syncthreads();
  if (threadIdx.x == 0) bsum[blockIdx.x] = ws[0] + ws[1] + ws[2] + ws[3];
}

// single block, loops over NCHUNK2 entries
__global__ __launch_bounds__(256) void k_scan_b(const int* __restrict__ bsum,
    int* __restrict__ boff) {
  __shared__ int ws[4];
  __shared__ int run_s;
  if (threadIdx.x == 0) run_s = 0;
  __syncthreads();
  int lane = threadIdx.x & 63, wv = threadIdx.x >> 6;
  for (int base = 0; base < NCHUNK2; base += 256) {
    int i = base + threadIdx.x;
    int v = (i < NCHUNK2) ? bsum[i] : 0;
    int s = v;
#pragma unroll
    for (int off = 1; off < 64; off <<= 1) { int u = __shfl_up(s, off); if (lane >= off) s += u; }
    if (lane == 63) ws[wv] = s;
    __syncthreads();
    int woff = 0;
#pragma unroll
    for (int w = 0; w < 4; ++w) woff += (w < wv) ? ws[w] : 0;
    int run = run_s;
    if (i < NCHUNK2) boff[i] = run + woff + s - v;
    __syncthreads();
    if (threadIdx.x == 255) run_s = run + woff + s;
    __syncthreads();
  }
  if (threadIdx.x == 0) boff[NCHUNK2] = run_s;
}

__global__ __launch_bounds__(256) void k_scan_c(const int* __restrict__ counts,
    const int* __restrict__ boff, int* __restrict__ ptr, int* __restrict__ fill) {
  int i = blockIdx.x * 256 + threadIdx.x;
  int v = (i < NT) ? counts[i] : 0;
  int lane = threadIdx.x & 63, wv = threadIdx.x >> 6;
  int s = v;
#pragma unroll
  for (int off = 1; off < 64; off <<= 1) { int u = __shfl_up(s, off); if (lane >= off) s += u; }
  __shared__ int ws[4];
  if (lane == 63) ws[wv] = s;
  __syncthreads();
  int woff = 0;
#pragma unroll
  for (int w = 0; w < 4; ++w) woff += (w < wv) ? ws[w] : 0;
  int excl = boff[blockIdx.x] + woff + s - v;
  if (i < NT) { ptr[i] = excl; fill[i] = excl; }
  if (blockIdx.x == 0 && threadIdx.x == 0) ptr[NT] = boff[NCHUNK2];
}

__global__ __launch_bounds__(256) void k_place(const int* __restrict__ ei,
    const int* __restrict__ et, int* __restrict__ fill, int* __restrict__ csr) {
  int e = blockIdx.x * 256 + threadIdx.x;
  if (e >= N_EDGES) return;
  int srcv = ei[e], d = ei[N_EDGES + e], ty = et[e] & 3;
  if ((unsigned)d >= N_NODES || (unsigned)srcv >= N_NODES || ty >= 3) return;
  int pos = atomicAdd(&fill[ty * N_NODES + d], 1);
  if ((unsigned)pos < N_EDGES) csr[pos] = srcv;
}

// ---------------------------------------------------------------- weight prep
// B-frag layout (384-col matrices, CT=24):
//   frag[((kc*24+ct)*64 + lane)*8 + j] = W[k = kc*32+(lane>>4)*8+j][n = ct*16+(lane&15)]

// Wcomb[mat][k][n] = sum_j conv_w[mat][k][j] * wih[bt][n][j]  (mat=(b*3+t)*3+s, bt=mat/3)
__global__ __launch_bounds__(256) void k_prep_comb(const float* __restrict__ cw,
    const float* __restrict__ wih, _Float16* __restrict__ dst) {
  int idx = blockIdx.x * 256 + threadIdx.x;
  if (idx >= 18 * 4 * 24 * 512) return;
  int j = idx & 7, lane = (idx >> 3) & 63;
  int r = idx >> 9;
  int ct = r % 24;
  int r2 = r / 24;
  int kc = r2 & 3, mat = r2 >> 2;
  int bt = mat / 3;
  int k = kc * 32 + ((lane >> 4) & 3) * 8 + j;
  int n = ct * 16 + (lane & 15);
  const float* wrow = cw + ((size_t)mat * 128 + k) * 128;
  const float* irow = wih + ((size_t)bt * 384 + n) * 128;
  float acc = 0.f;
#pragma unroll
  for (int q = 0; q < 128; q += 4) {
    floatx4 a = *(const floatx4*)(wrow + q);
    floatx4 b = *(const floatx4*)(irow + q);
    acc += a[0] * b[0] + a[1] * b[1] + a[2] * b[2] + a[3] * b[3];
  }
  dst[idx] = (_Float16)acc;
}

__global__ __launch_bounds__(256) void k_prep_whh(const float* __restrict__ whh,
    _Float16* __restrict__ dst) {
  int idx = blockIdx.x * 256 + threadIdx.x;
  if (idx >= 6 * 4 * 24 * 512) return;
  int j = idx & 7, lane = (idx >> 3) & 63;
  int r = idx >> 9;
  int ct = r % 24;
  int r2 = r / 24;
  int kc = r2 & 3, bt = r2 >> 2;
  int k = kc * 32 + ((lane >> 4) & 3) * 8 + j;
  int n = ct * 16 + (lane & 15);
  dst[idx] = (_Float16)whh[((size_t)bt * 384 + n) * 128 + k];
}

__global__ __launch_bounds__(256) void k_prep_w1(const float* __restrict__ hw1,
    _Float16* __restrict__ dst) {
  int idx = blockIdx.x * 256 + threadIdx.x;
  if (idx >= 4 * 8 * 512) return;
  int j = idx & 7, lane = (idx >> 3) & 63, ct = (idx >> 9) & 7, kc = (idx >> 12) & 3;
  int k = kc * 32 + ((lane >> 4) & 3) * 8 + j;
  int n = ct * 16 + (lane & 15);
  dst[idx] = (_Float16)hw1[n * 128 + k];
}

// ---------------------------------------------------------------- fused gather + GRU step
// Block = 512 thr (8 waves), one (type, 64-row) tile, full 384 gate-cols
// (wave u owns cts u/8+u/16+u). Phase 0: stage M rows + gather P into LDS.
// Phase 1: MFMA GRU from LDS A-fragments. Epilogue hold-read from LDS-M.
__global__ __launch_bounds__(512, 4) void k_step(
    const _Float16* __restrict__ Mbase, const size_t mstride,
    _Float16* __restrict__ Sout,
    const int* __restrict__ ptr, const int* __restrict__ csr,
    const _Float16* __restrict__ WPC, const _Float16* __restrict__ WHH,
    const float* __restrict__ bi2, const float* __restrict__ bh2) {
  __shared__ __attribute__((aligned(16))) _Float16 Plds[64 * PSTR];
  __shared__ __attribute__((aligned(16))) _Float16 Mlds[64 * PSTR];
  int bid = blockIdx.x;
  int t = bid / NB, blk = bid - t * NB;
  int tid = threadIdx.x;
  int wave = tid >> 6, lane = tid & 63;
  int quad = lane >> 4, l16 = lane & 15;
  int rowbase = blk * 64;
  const size_t NC = (size_t)N_NODES * 128;
  const _Float16* Mp = Mbase + mstride * t;
  _Float16* Sp = Sout + (size_t)t * NC;

  // ---- phase 0a: stage M block rows (64 x 128 fp16) into LDS, coalesced
#pragma unroll
  for (int it = 0; it < 2; ++it) {
    int r = it * 32 + (tid >> 4);
    int c = (tid & 15) * 8;
    int gr = rowbase + r; if (gr >= N_NODES) gr = N_NODES - 1;
    half8 v = *(const half8*)(Mp + (size_t)gr * 128 + c);
    *(half8*)(&Mlds[r * PSTR + c]) = v;
  }
  // ---- phase 0b: gather P rows (type-t in-edge sum of M[src]) into LDS
  const int* ptrT = ptr + t * N_NODES;
  int nl0 = wave * 8;
  for (int nl = nl0; nl < nl0 + 8; ++nl) {
    int n = rowbase + nl;
    float a0 = 0.f, a1 = 0.f;
    if (n < N_NODES) {
      int b0 = ptrT[n], b1 = ptrT[n + 1];
      if (b0 < 0) b0 = 0;
      if (b1 > N_EDGES) b1 = N_EDGES;   // replay safety
      int i = b0;
      for (; i + 4 <= b1; i += 4) {     // 4 independent row-loads in flight
        int s0 = csr[i], s1 = csr[i + 1], s2 = csr[i + 2], s3 = csr[i + 3];
        if ((unsigned)s0 >= N_NODES) s0 = 0;
        if ((unsigned)s1 >= N_NODES) s1 = 0;
        if ((unsigned)s2 >= N_NODES) s2 = 0;
        if ((unsigned)s3 >= N_NODES) s3 = 0;
        half2v x0 = *(const half2v*)(Mp + (size_t)s0 * 128 + lane * 2);
        half2v x1 = *(const half2v*)(Mp + (size_t)s1 * 128 + lane * 2);
        half2v x2 = *(const half2v*)(Mp + (size_t)s2 * 128 + lane * 2);
        half2v x3 = *(const half2v*)(Mp + (size_t)s3 * 128 + lane * 2);
        a0 += (float)x0[0] + (float)x1[0] + (float)x2[0] + (float)x3[0];
        a1 += (float)x0[1] + (float)x1[1] + (float)x2[1] + (float)x3[1];
      }
      for (; i < b1; ++i) {
        int s0 = csr[i];
        if ((unsigned)s0 >= N_NODES) s0 = 0;
        half2v x0 = *(const half2v*)(Mp + (size_t)s0 * 128 + lane * 2);
        a0 += (float)x0[0];
        a1 += (float)x0[1];
      }
    }
    half2v o; o[0] = (_Float16)a0; o[1] = (_Float16)a1;
    *(half2v*)(&Plds[nl * PSTR + lane * 2]) = o;
  }
  __syncthreads();

  // ---- phase 1: MFMA GRU. u = wave owns cts {u (r), 8+u (z), 16+u (n)}.
  const half8* wpc = (const half8*)(WPC + (size_t)t * 3 * FS);
  const half8* whh = (const half8*)(WHH + (size_t)t * FS);
  const float* bi = bi2 + (size_t)t * 384;
  const float* bh = bh2 + (size_t)t * 384;
  int u = wave;
  floatx4 zero = {0.f, 0.f, 0.f, 0.f};
  floatx4 aR[4], aZ[4], aNP[4], aNM[4];
#pragma unroll
  for (int rt = 0; rt < 4; ++rt) { aR[rt] = zero; aZ[rt] = zero; aNP[rt] = zero; aNM[rt] = zero; }
#pragma unroll
  for (int kc = 0; kc < 4; ++kc) {   // gi part: P @ Wcomb
    half8 af[4];
#pragma unroll
    for (int rt = 0; rt < 4; ++rt)
      af[rt] = *(const half8*)(&Plds[(rt * 16 + l16) * PSTR + kc * 32 + quad * 8]);
    half8 br = wpc[(kc * 24 + u) * 64 + lane];
    half8 bz = wpc[(kc * 24 + 8 + u) * 64 + lane];
    half8 bn = wpc[(kc * 24 + 16 + u) * 64 + lane];
#pragma unroll
    for (int rt = 0; rt < 4; ++rt) {
      aR[rt] = __builtin_amdgcn_mfma_f32_16x16x32_f16(af[rt], br, aR[rt], 0, 0, 0);
      aZ[rt] = __builtin_amdgcn_mfma_f32_16x16x32_f16(af[rt], bz, aZ[rt], 0, 0, 0);
      aNP[rt] = __builtin_amdgcn_mfma_f32_16x16x32_f16(af[rt], bn, aNP[rt], 0, 0, 0);
    }
  }
#pragma unroll
  for (int kc = 0; kc < 4; ++kc) {   // gh part: M @ whh.T
    half8 af[4];
#pragma unroll
    for (int rt = 0; rt < 4; ++rt)
      af[rt] = *(const half8*)(&Mlds[(rt * 16 + l16) * PSTR + kc * 32 + quad * 8]);
    half8 br = whh[(kc * 24 + u) * 64 + lane];
    half8 bz = whh[(kc * 24 + 8 + u) * 64 + lane];
    half8 bn = whh[(kc * 24 + 16 + u) * 64 + lane];
#pragma unroll
    for (int rt = 0; rt < 4; ++rt) {
      aR[rt] = __builtin_amdgcn_mfma_f32_16x16x32_f16(af[rt], br, aR[rt], 0, 0, 0);
      aZ[rt] = __builtin_amdgcn_mfma_f32_16x16x32_f16(af[rt], bz, aZ[rt], 0, 0, 0);
      aNM[rt] = __builtin_amdgcn_mfma_f32_16x16x32_f16(af[rt], bn, aNM[rt], 0, 0, 0);
    }
  }
  // ---- epilogue (C layout: row = rt*16 + quad*4 + q, col = u*16 + l16)
  int col = u * 16 + l16;
  float br_ = bi[col] + bh[col];
  float bz_ = bi[128 + col] + bh[128 + col];
  float bin = bi[256 + col], bhn = bh[256 + col];
#pragma unroll
  for (int rt = 0; rt < 4; ++rt) {
#pragma unroll
    for (int q = 0; q < 4; ++q) {
      int lr = rt * 16 + quad * 4 + q;
      int row = rowbase + lr;
      if (row < N_NODES) {
        float r = sigmoid_(aR[rt][q] + br_);
        float z = sigmoid_(aZ[rt][q] + bz_);
        float nt = tanh_(aNP[rt][q] + bin + r * (aNM[rt][q] + bhn));
        float hold = (float)Mlds[lr * PSTR + col];
        Sp[(size_t)row * 128 + col] = (_Float16)((1.f - z) * nt + z * hold);
      }
    }
  }
}

// ---------------------------------------------------------------- LayerNorm(h + S0+S1+S2) + ReLU -> h (fp16)
__global__ __launch_bounds__(256) void k_ln(_Float16* __restrict__ h,
    const _Float16* __restrict__ S, const float* __restrict__ gamma,
    const float* __restrict__ beta) {
  int wave = threadIdx.x >> 6, lane = threadIdx.x & 63;
  int n = blockIdx.x * 4 + wave;
  if (n >= N_NODES) return;
  const size_t NC = (size_t)N_NODES * 128;
  size_t base = (size_t)n * 128 + lane * 2;
  half2v hv = *(const half2v*)(h + base);
  half2v s0 = *(const half2v*)(S + base);
  half2v s1 = *(const half2v*)(S + NC + base);
  half2v s2 = *(const half2v*)(S + 2 * NC + base);
  float v0 = (float)hv[0] + (float)s0[0] + (float)s1[0] + (float)s2[0];
  float v1 = (float)hv[1] + (float)s0[1] + (float)s1[1] + (float)s2[1];
  float s = v0 + v1, sq = v0 * v0 + v1 * v1;
#pragma unroll
  for (int off = 32; off > 0; off >>= 1) {
    s += __shfl_xor(s, off);
    sq += __shfl_xor(sq, off);
  }
  float mu = s * 0.0078125f;
  float var = sq * 0.0078125f - mu * mu;
  float rs = rsqrtf(var + 1e-5f);
  float o0 = (v0 - mu) * rs * gamma[lane * 2] + beta[lane * 2];
  float o1 = (v1 - mu) * rs * gamma[lane * 2 + 1] + beta[lane * 2 + 1];
  half2v ov; ov[0] = (_Float16)fmaxf(o0, 0.f); ov[1] = (_Float16)fmaxf(o1, 0.f);
  *(half2v*)(h + base) = ov;
}

// ---------------------------------------------------------------- head layer 1 (fp16 A, fp32 out, bias+relu)
__global__ __launch_bounds__(256, 4) void k_gemm_head(const _Float16* __restrict__ A,
    const _Float16* __restrict__ Wf, const float* __restrict__ bias,
    float* __restrict__ out) {
  int blk = blockIdx.x;
  int wave = threadIdx.x >> 6, lane = threadIdx.x & 63;
  int quad = lane >> 4, l16 = lane & 15;
  int rowbase = blk * 64;
  const half8* wf = (const half8*)Wf;
  int ar[4];
#pragma unroll
  for (int rt = 0; rt < 4; ++rt) {
    int r = rowbase + rt * 16 + l16;
    ar[rt] = r < N_NODES ? r : N_NODES - 1;
  }
  floatx4 zero = {0.f, 0.f, 0.f, 0.f};
  floatx4 acc[4][2];
#pragma unroll
  for (int rt = 0; rt < 4; ++rt) { acc[rt][0] = zero; acc[rt][1] = zero; }
#pragma unroll
  for (int kc = 0; kc < 4; ++kc) {
    half8 af[4];
#pragma unroll
    for (int rt = 0; rt < 4; ++rt)
      af[rt] = *(const half8*)(A + (size_t)ar[rt] * 128 + kc * 32 + quad * 8);
    half8 b0 = wf[(kc * 8 + 2 * wave) * 64 + lane];
    half8 b1 = wf[(kc * 8 + 2 * wave + 1) * 64 + lane];
#pragma unroll
    for (int rt = 0; rt < 4; ++rt) {
      acc[rt][0] = __builtin_amdgcn_mfma_f32_16x16x32_f16(af[rt], b0, acc[rt][0], 0, 0, 0);
      acc[rt][1] = __builtin_amdgcn_mfma_f32_16x16x32_f16(af[rt], b1, acc[rt][1], 0, 0, 0);
    }
  }
  int col = wave * 32 + l16;
#pragma unroll
  for (int rt = 0; rt < 4; ++rt) {
#pragma unroll
    for (int q = 0; q < 4; ++q) {
      int row = rowbase + rt * 16 + quad * 4 + q;
      if (row < N_NODES) {
        float* op = out + (size_t)row * 128;
        op[col] = fmaxf(acc[rt][0][q] + bias[col], 0.f);
        op[col + 16] = fmaxf(acc[rt][1][q] + bias[col + 16], 0.f);
      }
    }
  }
}

// ---------------------------------------------------------------- head layer 2
__global__ __launch_bounds__(256) void k_head2(const float* __restrict__ z,
    const float* __restrict__ w2, const float* __restrict__ b2,
    float* __restrict__ out) {
  __shared__ float w[256];
  w[threadIdx.x] = w2[threadIdx.x];
  __syncthreads();
  int t = blockIdx.x * 256 + threadIdx.x;
  int n = t >> 1, o = t & 1;
  if (n >= N_NODES) return;
  const float* zr = z + (size_t)n * 128;
  const float* wr = w + o * 128;
  float acc = 0.f;
  for (int k = 0; k < 128; k += 4) {
    float4 zv = *(const float4*)(zr + k);
    acc += zv.x * wr[k] + zv.y * wr[k+1] + zv.z * wr[k+2] + zv.w * wr[k+3];
  }
  out[(size_t)n * 2 + o] = acc + b2[o];
}

// ================================================================ launch
extern "C" void kernel_launch(void* const* d_in, const int* in_sizes, int n_in,
                              void* d_out, int out_size, void* d_ws, size_t ws_size,
                              hipStream_t stream) {
  const int*   x_type  = (const int*)d_in[0];
  const int*   x_tok   = (const int*)d_in[1];
  const float* x_small = (const float*)d_in[2];
  const int*   eidx    = (const int*)d_in[3];
  const int*   etype   = (const int*)d_in[4];
  const float* conv_w  = (const float*)d_in[5];
  const float* gwih    = (const float*)d_in[6];
  const float* gwhh    = (const float*)d_in[7];
  const float* gbih    = (const float*)d_in[8];
  const float* gbhh    = (const float*)d_in[9];
  const float* ln_g    = (const float*)d_in[10];
  const float* ln_b    = (const float*)d_in[11];
  const float* hw1     = (const float*)d_in[12];
  const float* hb1     = (const float*)d_in[13];
  const float* hw2     = (const float*)d_in[14];
  const float* hb2     = (const float*)d_in[15];
  float* out = (float*)d_out;

  const size_t NC = (size_t)N_NODES * 128;
  char* W = (char*)d_ws;
  size_t off = 0;
  _Float16* h16 = (_Float16*)(W + off);     off += NC * 2;            // 12.8 MB
  _Float16* S0  = (_Float16*)(W + off);     off += 3 * NC * 2;        // 38.4 MB
  _Float16* S1  = (_Float16*)(W + off);     off += 3 * NC * 2;        // 38.4 MB
  float* zbuf   = (float*)(W + off);        off += NC * 4;            // 25.6 MB
  int* counts = (int*)(W + off);            off += (size_t)NT * 4;
  int* ptrv   = (int*)(W + off);            off += (size_t)(NT + 1) * 4;
  int* fill   = (int*)(W + off);            off += (size_t)NT * 4;
  int* bsum   = (int*)(W + off);            off += (NCHUNK2 + 1) * 4;
  int* boff   = (int*)(W + off);            off += (NCHUNK2 + 1) * 4;
  int* csr    = (int*)(W + off);            off += (size_t)N_EDGES * 4;
  _Float16* WPC = (_Float16*)(W + off);     off += (size_t)18 * FS * 2;
  _Float16* WHH = (_Float16*)(W + off);     off += (size_t)6 * FS * 2;
  _Float16* W1F = (_Float16*)(W + off);     off += (size_t)16384 * 2;

  // ---- per-call prep
  k_features<<<(N_NODES * 128 + 255) / 256, 256, 0, stream>>>(h16, x_type, x_tok, x_small);
  hipMemsetAsync(counts, 0, (size_t)NT * 4, stream);
  k_hist<<<(N_EDGES + 255) / 256, 256, 0, stream>>>(eidx, etype, counts);
  k_scan_a<<<NCHUNK2, 256, 0, stream>>>(counts, bsum);
  k_scan_b<<<1, 256, 0, stream>>>(bsum, boff);
  k_scan_c<<<NCHUNK2, 256, 0, stream>>>(counts, boff, ptrv, fill);
  k_place<<<(N_EDGES + 255) / 256, 256, 0, stream>>>(eidx, etype, fill, csr);
  k_prep_comb<<<(18 * 4 * 24 * 512 + 255) / 256, 256, 0, stream>>>(conv_w, gwih, WPC);
  k_prep_whh<<<(6 * 4 * 24 * 512 + 255) / 256, 256, 0, stream>>>(gwhh, WHH);
  k_prep_w1<<<(4 * 8 * 512 + 255) / 256, 256, 0, stream>>>(hw1, W1F);

  // ---- main loop: 2 blocks x 3 steps; fused gather+GRU; ping-pong S0/S1
  for (int b = 0; b < 2; ++b) {
    for (int s = 0; s < 3; ++s) {
      const _Float16* Msrc = (s == 0) ? h16 : ((s == 1) ? S0 : S1);
      size_t mstr = (s == 0) ? 0 : NC;
      _Float16* Sout = (s == 1) ? S1 : S0;
      k_step<<<3 * NB, 512, 0, stream>>>(Msrc, mstr, Sout, ptrv, csr,
          WPC + (size_t)(b * 9 + s) * FS, WHH + (size_t)b * 3 * FS,
          gbih + (size_t)b * 3 * 384, gbhh + (size_t)b * 3 * 384);
    }
    k_ln<<<(N_NODES + 3) / 4, 256, 0, stream>>>(h16, S0, ln_g + b * 128, ln_b + b * 128);
  }
  // ---- head
  k_gemm_head<<<NB, 256, 0, stream>>>(h16, W1F, hb1, zbuf);
  k_head2<<<(2 * N_NODES + 255) / 256, 256, 0, stream>>>(zbuf, hw2, hb2, out);
}

// Round 7
// 839.573 us; speedup vs baseline: 9.7731x; 1.1528x over previous
//
#include <hip/hip_runtime.h>
#include <cstdint>
#include <cstddef>

// Problem constants (match reference)
#define N_NODES 50000
#define N_EDGES 500000
#define NB 782              // ceil(N_NODES/64) row-blocks
#define NT 150000           // 3 * N_NODES (typed CSR)
#define NCHUNK2 586         // ceil(NT/256) scan chunks
#define FS 49152            // frag halfs per [128x384] matrix (4*24*512)
#define PSTR 136            // LDS row stride in halfs (+8 pad -> bank-spread)
#define MAXOFF 12799744u    // (N_NODES-1)*256 byte-offset clamp
// C = 128, STEPS = 3, BLOCKS = 2, NUM_ET = 3

typedef _Float16 half8 __attribute__((ext_vector_type(8)));
typedef _Float16 half2v __attribute__((ext_vector_type(2)));
typedef float floatx4 __attribute__((ext_vector_type(4)));

__device__ __forceinline__ float sigmoid_(float x) { return 1.f / (1.f + __expf(-x)); }
__device__ __forceinline__ float tanh_(float x) {
  float t = __expf(-2.f * fabsf(x));
  float r = (1.f - t) / (1.f + t);
  return copysignf(r, x);
}

// ---------------------------------------------------------------- features (fp16 h)
__global__ __launch_bounds__(256) void k_features(_Float16* __restrict__ h,
    const int* __restrict__ xtype, const int* __restrict__ xtok,
    const float* __restrict__ xs) {
  int idx = blockIdx.x * 256 + threadIdx.x;
  if (idx >= N_NODES * 128) return;
  int n = idx >> 7, c = idx & 127;
  float v;
  if (c < 32) {
    v = (xtype[n] == c) ? 1.f : 0.f;
  } else if (c < 126) {
    int tk = xtok[n];
    tk = tk < 0 ? 0 : (tk > 93 ? 93 : tk);
    v = (tk == (c - 32)) ? 1.f : 0.f;
  } else {
    v = xs[n * 2 + (c - 126)];
  }
  h[idx] = (_Float16)v;
}

// ---------------------------------------------------------------- typed-CSR build
__global__ __launch_bounds__(256) void k_hist(const int* __restrict__ ei,
    const int* __restrict__ et, int* __restrict__ counts) {
  int e = blockIdx.x * 256 + threadIdx.x;
  if (e >= N_EDGES) return;
  int d = ei[N_EDGES + e];
  int ty = et[e] & 3;
  if ((unsigned)d < N_NODES && ty < 3) atomicAdd(&counts[ty * N_NODES + d], 1);
}

__global__ __launch_bounds__(256) void k_scan_a(const int* __restrict__ counts,
    int* __restrict__ bsum) {
  int i = blockIdx.x * 256 + threadIdx.x;
  int v = (i < NT) ? counts[i] : 0;
  int lane = threadIdx.x & 63, wv = threadIdx.x >> 6;
#pragma unroll
  for (int off = 32; off > 0; off >>= 1) v += __shfl_xor(v, off);
  __shared__ int ws[4];
  if (lane == 0) ws[wv] = v;
  __syncthreads();
  if (threadIdx.x == 0) bsum[blockIdx.x] = ws[0] + ws[1] + ws[2] + ws[3];
}

__global__ __launch_bounds__(256) void k_scan_b(const int* __restrict__ bsum,
    int* __restrict__ boff) {
  __shared__ int ws[4];
  __shared__ int run_s;
  if (threadIdx.x == 0) run_s = 0;
  __syncthreads();
  int lane = threadIdx.x & 63, wv = threadIdx.x >> 6;
  for (int base = 0; base < NCHUNK2; base += 256) {
    int i = base + threadIdx.x;
    int v = (i < NCHUNK2) ? bsum[i] : 0;
    int s = v;
#pragma unroll
    for (int off = 1; off < 64; off <<= 1) { int u = __shfl_up(s, off); if (lane >= off) s += u; }
    if (lane == 63) ws[wv] = s;
    __syncthreads();
    int woff = 0;
#pragma unroll
    for (int w = 0; w < 4; ++w) woff += (w < wv) ? ws[w] : 0;
    int run = run_s;
    if (i < NCHUNK2) boff[i] = run + woff + s - v;
    __syncthreads();
    if (threadIdx.x == 255) run_s = run + woff + s;
    __syncthreads();
  }
  if (threadIdx.x == 0) boff[NCHUNK2] = run_s;
}

__global__ __launch_bounds__(256) void k_scan_c(const int* __restrict__ counts,
    const int* __restrict__ boff, int* __restrict__ ptr, int* __restrict__ fill) {
  int i = blockIdx.x * 256 + threadIdx.x;
  int v = (i < NT) ? counts[i] : 0;
  int lane = threadIdx.x & 63, wv = threadIdx.x >> 6;
  int s = v;
#pragma unroll
  for (int off = 1; off < 64; off <<= 1) { int u = __shfl_up(s, off); if (lane >= off) s += u; }
  __shared__ int ws[4];
  if (lane == 63) ws[wv] = s;
  __syncthreads();
  int woff = 0;
#pragma unroll
  for (int w = 0; w < 4; ++w) woff += (w < wv) ? ws[w] : 0;
  int excl = boff[blockIdx.x] + woff + s - v;
  if (i < NT) { ptr[i] = excl; fill[i] = excl; }
  if (blockIdx.x == 0 && threadIdx.x == 0) ptr[NT] = boff[NCHUNK2];
}

// csr stores src row as BYTE offset (src*256) -> no shift/mul in gather
__global__ __launch_bounds__(256) void k_place(const int* __restrict__ ei,
    const int* __restrict__ et, int* __restrict__ fill, int* __restrict__ csr) {
  int e = blockIdx.x * 256 + threadIdx.x;
  if (e >= N_EDGES) return;
  int srcv = ei[e], d = ei[N_EDGES + e], ty = et[e] & 3;
  if ((unsigned)d >= N_NODES || (unsigned)srcv >= N_NODES || ty >= 3) return;
  int pos = atomicAdd(&fill[ty * N_NODES + d], 1);
  if ((unsigned)pos < N_EDGES) csr[pos] = srcv << 8;
}

// ---------------------------------------------------------------- weight prep
// B-frag layout (384-col matrices, CT=24):
//   frag[((kc*24+ct)*64 + lane)*8 + j] = W[k = kc*32+(lane>>4)*8+j][n = ct*16+(lane&15)]

// Wcomb[mat][k][n] = sum_j conv_w[mat][k][j] * wih[bt][n][j]  (mat=(b*3+t)*3+s, bt=mat/3)
__global__ __launch_bounds__(256) void k_prep_comb(const float* __restrict__ cw,
    const float* __restrict__ wih, _Float16* __restrict__ dst) {
  int idx = blockIdx.x * 256 + threadIdx.x;
  if (idx >= 18 * 4 * 24 * 512) return;
  int j = idx & 7, lane = (idx >> 3) & 63;
  int r = idx >> 9;
  int ct = r % 24;
  int r2 = r / 24;
  int kc = r2 & 3, mat = r2 >> 2;
  int bt = mat / 3;
  int k = kc * 32 + ((lane >> 4) & 3) * 8 + j;
  int n = ct * 16 + (lane & 15);
  const float* wrow = cw + ((size_t)mat * 128 + k) * 128;
  const float* irow = wih + ((size_t)bt * 384 + n) * 128;
  float acc = 0.f;
#pragma unroll
  for (int q = 0; q < 128; q += 4) {
    floatx4 a = *(const floatx4*)(wrow + q);
    floatx4 b = *(const floatx4*)(irow + q);
    acc += a[0] * b[0] + a[1] * b[1] + a[2] * b[2] + a[3] * b[3];
  }
  dst[idx] = (_Float16)acc;
}

__global__ __launch_bounds__(256) void k_prep_whh(const float* __restrict__ whh,
    _Float16* __restrict__ dst) {
  int idx = blockIdx.x * 256 + threadIdx.x;
  if (idx >= 6 * 4 * 24 * 512) return;
  int j = idx & 7, lane = (idx >> 3) & 63;
  int r = idx >> 9;
  int ct = r % 24;
  int r2 = r / 24;
  int kc = r2 & 3, bt = r2 >> 2;
  int k = kc * 32 + ((lane >> 4) & 3) * 8 + j;
  int n = ct * 16 + (lane & 15);
  dst[idx] = (_Float16)whh[((size_t)bt * 384 + n) * 128 + k];
}

__global__ __launch_bounds__(256) void k_prep_w1(const float* __restrict__ hw1,
    _Float16* __restrict__ dst) {
  int idx = blockIdx.x * 256 + threadIdx.x;
  if (idx >= 4 * 8 * 512) return;
  int j = idx & 7, lane = (idx >> 3) & 63, ct = (idx >> 9) & 7, kc = (idx >> 12) & 3;
  int k = kc * 32 + ((lane >> 4) & 3) * 8 + j;
  int n = ct * 16 + (lane & 15);
  dst[idx] = (_Float16)hw1[n * 128 + k];
}

// ---------------------------------------------------------------- fused gather + GRU step
// Block = 512 thr (8 waves), one (type, 64-row) tile.
// Phase 0a: stage M rows in LDS (coalesced). Phase 0b: gather — each 16-lane
// group owns one row (16 x 16B = full 256B row), so a wave drives 4 edge
// lists concurrently; fp16 packed accumulate; csr holds byte offsets.
// Phase 1: MFMA GRU from LDS; epilogue hold-read from LDS-M.
__global__ __launch_bounds__(512, 4) void k_step(
    const _Float16* __restrict__ Mbase, const size_t mstride,
    _Float16* __restrict__ Sout,
    const int* __restrict__ ptr, const int* __restrict__ csr,
    const _Float16* __restrict__ WPC, const _Float16* __restrict__ WHH,
    const float* __restrict__ bi2, const float* __restrict__ bh2) {
  __shared__ __attribute__((aligned(16))) _Float16 Plds[64 * PSTR];
  __shared__ __attribute__((aligned(16))) _Float16 Mlds[64 * PSTR];
  int bid = blockIdx.x;
  int t = bid / NB, blk = bid - t * NB;
  int tid = threadIdx.x;
  int wave = tid >> 6, lane = tid & 63;
  int quad = lane >> 4, l16 = lane & 15;
  int rowbase = blk * 64;
  const size_t NC = (size_t)N_NODES * 128;
  const _Float16* Mp = Mbase + mstride * t;
  const char* Mb = (const char*)Mp;
  _Float16* Sp = Sout + (size_t)t * NC;

  // ---- phase 0a: stage M block rows (64 x 128 fp16) into LDS, coalesced
#pragma unroll
  for (int it = 0; it < 2; ++it) {
    int r = it * 32 + (tid >> 4);
    int c = (tid & 15) * 8;
    int gr = rowbase + r; if (gr >= N_NODES) gr = N_NODES - 1;
    half8 v = *(const half8*)(Mp + (size_t)gr * 128 + c);
    *(half8*)(&Mlds[r * PSTR + c]) = v;
  }

  // ---- phase 0b: gather; group g = lane>>4 owns row nl = wave*8+batch*4+g
  const int* ptrT = ptr + t * N_NODES;
  int g = quad;
  int coff = l16 * 16;  // byte offset within row
#pragma unroll
  for (int batch = 0; batch < 2; ++batch) {
    int nl = wave * 8 + batch * 4 + g;
    int n = rowbase + nl;
    int b0 = 0, b1 = 0;
    if (n < N_NODES) { b0 = ptrT[n]; b1 = ptrT[n + 1]; }
    if (b0 < 0) b0 = 0;
    if (b1 > N_EDGES) b1 = N_EDGES;   // replay safety
    half8 acc = {};
    int i = b0;
    for (;;) {
      bool a0 = i < b1, a1 = (i + 1) < b1;
      if (!__any(a0)) break;
      if (a0) {
        unsigned off = (unsigned)csr[i];
        if (off > MAXOFF) off = 0;    // replay safety
        half8 x = *(const half8*)(Mb + off + coff);
        acc += x;                      // v_pk_add_f16 x4
      }
      if (a1) {
        unsigned off = (unsigned)csr[i + 1];
        if (off > MAXOFF) off = 0;
        half8 x = *(const half8*)(Mb + off + coff);
        acc += x;
      }
      i += 2;
    }
    *(half8*)(&Plds[nl * PSTR + l16 * 8]) = acc;
  }
  __syncthreads();

  // ---- phase 1: MFMA GRU. u = wave owns cts {u (r), 8+u (z), 16+u (n)}.
  const half8* wpc = (const half8*)(WPC + (size_t)t * 3 * FS);
  const half8* whh = (const half8*)(WHH + (size_t)t * FS);
  const float* bi = bi2 + (size_t)t * 384;
  const float* bh = bh2 + (size_t)t * 384;
  int u = wave;
  floatx4 zero = {0.f, 0.f, 0.f, 0.f};
  floatx4 aR[4], aZ[4], aNP[4], aNM[4];
#pragma unroll
  for (int rt = 0; rt < 4; ++rt) { aR[rt] = zero; aZ[rt] = zero; aNP[rt] = zero; aNM[rt] = zero; }
#pragma unroll
  for (int kc = 0; kc < 4; ++kc) {   // gi part: P @ Wcomb
    half8 af[4];
#pragma unroll
    for (int rt = 0; rt < 4; ++rt)
      af[rt] = *(const half8*)(&Plds[(rt * 16 + l16) * PSTR + kc * 32 + quad * 8]);
    half8 br = wpc[(kc * 24 + u) * 64 + lane];
    half8 bz = wpc[(kc * 24 + 8 + u) * 64 + lane];
    half8 bn = wpc[(kc * 24 + 16 + u) * 64 + lane];
#pragma unroll
    for (int rt = 0; rt < 4; ++rt) {
      aR[rt] = __builtin_amdgcn_mfma_f32_16x16x32_f16(af[rt], br, aR[rt], 0, 0, 0);
      aZ[rt] = __builtin_amdgcn_mfma_f32_16x16x32_f16(af[rt], bz, aZ[rt], 0, 0, 0);
      aNP[rt] = __builtin_amdgcn_mfma_f32_16x16x32_f16(af[rt], bn, aNP[rt], 0, 0, 0);
    }
  }
#pragma unroll
  for (int kc = 0; kc < 4; ++kc) {   // gh part: M @ whh.T
    half8 af[4];
#pragma unroll
    for (int rt = 0; rt < 4; ++rt)
      af[rt] = *(const half8*)(&Mlds[(rt * 16 + l16) * PSTR + kc * 32 + quad * 8]);
    half8 br = whh[(kc * 24 + u) * 64 + lane];
    half8 bz = whh[(kc * 24 + 8 + u) * 64 + lane];
    half8 bn = whh[(kc * 24 + 16 + u) * 64 + lane];
#pragma unroll
    for (int rt = 0; rt < 4; ++rt) {
      aR[rt] = __builtin_amdgcn_mfma_f32_16x16x32_f16(af[rt], br, aR[rt], 0, 0, 0);
      aZ[rt] = __builtin_amdgcn_mfma_f32_16x16x32_f16(af[rt], bz, aZ[rt], 0, 0, 0);
      aNM[rt] = __builtin_amdgcn_mfma_f32_16x16x32_f16(af[rt], bn, aNM[rt], 0, 0, 0);
    }
  }
  // ---- epilogue (C layout: row = rt*16 + quad*4 + q, col = u*16 + l16)
  int col = u * 16 + l16;
  float br_ = bi[col] + bh[col];
  float bz_ = bi[128 + col] + bh[128 + col];
  float bin = bi[256 + col], bhn = bh[256 + col];
#pragma unroll
  for (int rt = 0; rt < 4; ++rt) {
#pragma unroll
    for (int q = 0; q < 4; ++q) {
      int lr = rt * 16 + quad * 4 + q;
      int row = rowbase + lr;
      if (row < N_NODES) {
        float r = sigmoid_(aR[rt][q] + br_);
        float z = sigmoid_(aZ[rt][q] + bz_);
        float nt = tanh_(aNP[rt][q] + bin + r * (aNM[rt][q] + bhn));
        float hold = (float)Mlds[lr * PSTR + col];
        Sp[(size_t)row * 128 + col] = (_Float16)((1.f - z) * nt + z * hold);
      }
    }
  }
}

// ---------------------------------------------------------------- LayerNorm(h + S0+S1+S2) + ReLU -> h (fp16)
__global__ __launch_bounds__(256) void k_ln(_Float16* __restrict__ h,
    const _Float16* __restrict__ S, const float* __restrict__ gamma,
    const float* __restrict__ beta) {
  int wave = threadIdx.x >> 6, lane = threadIdx.x & 63;
  int n = blockIdx.x * 4 + wave;
  if (n >= N_NODES) return;
  const size_t NC = (size_t)N_NODES * 128;
  size_t base = (size_t)n * 128 + lane * 2;
  half2v hv = *(const half2v*)(h + base);
  half2v s0 = *(const half2v*)(S + base);
  half2v s1 = *(const half2v*)(S + NC + base);
  half2v s2 = *(const half2v*)(S + 2 * NC + base);
  float v0 = (float)hv[0] + (float)s0[0] + (float)s1[0] + (float)s2[0];
  float v1 = (float)hv[1] + (float)s0[1] + (float)s1[1] + (float)s2[1];
  float s = v0 + v1, sq = v0 * v0 + v1 * v1;
#pragma unroll
  for (int off = 32; off > 0; off >>= 1) {
    s += __shfl_xor(s, off);
    sq += __shfl_xor(sq, off);
  }
  float mu = s * 0.0078125f;
  float var = sq * 0.0078125f - mu * mu;
  float rs = rsqrtf(var + 1e-5f);
  float o0 = (v0 - mu) * rs * gamma[lane * 2] + beta[lane * 2];
  float o1 = (v1 - mu) * rs * gamma[lane * 2 + 1] + beta[lane * 2 + 1];
  half2v ov; ov[0] = (_Float16)fmaxf(o0, 0.f); ov[1] = (_Float16)fmaxf(o1, 0.f);
  *(half2v*)(h + base) = ov;
}

// ---------------------------------------------------------------- head layer 1 (fp16 A, fp16 z out, bias+relu)
__global__ __launch_bounds__(256, 4) void k_gemm_head(const _Float16* __restrict__ A,
    const _Float16* __restrict__ Wf, const float* __restrict__ bias,
    _Float16* __restrict__ out) {
  int blk = blockIdx.x;
  int wave = threadIdx.x >> 6, lane = threadIdx.x & 63;
  int quad = lane >> 4, l16 = lane & 15;
  int rowbase = blk * 64;
  const half8* wf = (const half8*)Wf;
  int ar[4];
#pragma unroll
  for (int rt = 0; rt < 4; ++rt) {
    int r = rowbase + rt * 16 + l16;
    ar[rt] = r < N_NODES ? r : N_NODES - 1;
  }
  floatx4 zero = {0.f, 0.f, 0.f, 0.f};
  floatx4 acc[4][2];
#pragma unroll
  for (int rt = 0; rt < 4; ++rt) { acc[rt][0] = zero; acc[rt][1] = zero; }
#pragma unroll
  for (int kc = 0; kc < 4; ++kc) {
    half8 af[4];
#pragma unroll
    for (int rt = 0; rt < 4; ++rt)
      af[rt] = *(const half8*)(A + (size_t)ar[rt] * 128 + kc * 32 + quad * 8);
    half8 b0 = wf[(kc * 8 + 2 * wave) * 64 + lane];
    half8 b1 = wf[(kc * 8 + 2 * wave + 1) * 64 + lane];
#pragma unroll
    for (int rt = 0; rt < 4; ++rt) {
      acc[rt][0] = __builtin_amdgcn_mfma_f32_16x16x32_f16(af[rt], b0, acc[rt][0], 0, 0, 0);
      acc[rt][1] = __builtin_amdgcn_mfma_f32_16x16x32_f16(af[rt], b1, acc[rt][1], 0, 0, 0);
    }
  }
  int col = wave * 32 + l16;
#pragma unroll
  for (int rt = 0; rt < 4; ++rt) {
#pragma unroll
    for (int q = 0; q < 4; ++q) {
      int row = rowbase + rt * 16 + quad * 4 + q;
      if (row < N_NODES) {
        _Float16* op = out + (size_t)row * 128;
        op[col] = (_Float16)fmaxf(acc[rt][0][q] + bias[col], 0.f);
        op[col + 16] = (_Float16)fmaxf(acc[rt][1][q] + bias[col + 16], 0.f);
      }
    }
  }
}

// ---------------------------------------------------------------- head layer 2 (one node/thread, fp16 z)
__global__ __launch_bounds__(256) void k_head2(const _Float16* __restrict__ z,
    const float* __restrict__ w2, const float* __restrict__ b2,
    float* __restrict__ out) {
  __shared__ float w[256];
  w[threadIdx.x] = w2[threadIdx.x];
  __syncthreads();
  int n = blockIdx.x * 256 + threadIdx.x;
  if (n >= N_NODES) return;
  const half8* zr = (const half8*)(z + (size_t)n * 128);
  float a0 = 0.f, a1 = 0.f;
#pragma unroll
  for (int kb = 0; kb < 16; ++kb) {
    half8 zv = zr[kb];
#pragma unroll
    for (int q = 0; q < 8; ++q) {
      float zf = (float)zv[q];
      a0 += zf * w[kb * 8 + q];
      a1 += zf * w[128 + kb * 8 + q];
    }
  }
  out[(size_t)n * 2 + 0] = a0 + b2[0];
  out[(size_t)n * 2 + 1] = a1 + b2[1];
}

// ================================================================ launch
extern "C" void kernel_launch(void* const* d_in, const int* in_sizes, int n_in,
                              void* d_out, int out_size, void* d_ws, size_t ws_size,
                              hipStream_t stream) {
  const int*   x_type  = (const int*)d_in[0];
  const int*   x_tok   = (const int*)d_in[1];
  const float* x_small = (const float*)d_in[2];
  const int*   eidx    = (const int*)d_in[3];
  const int*   etype   = (const int*)d_in[4];
  const float* conv_w  = (const float*)d_in[5];
  const float* gwih    = (const float*)d_in[6];
  const float* gwhh    = (const float*)d_in[7];
  const float* gbih    = (const float*)d_in[8];
  const float* gbhh    = (const float*)d_in[9];
  const float* ln_g    = (const float*)d_in[10];
  const float* ln_b    = (const float*)d_in[11];
  const float* hw1     = (const float*)d_in[12];
  const float* hb1     = (const float*)d_in[13];
  const float* hw2     = (const float*)d_in[14];
  const float* hb2     = (const float*)d_in[15];
  float* out = (float*)d_out;

  const size_t NC = (size_t)N_NODES * 128;
  char* W = (char*)d_ws;
  size_t off = 0;
  _Float16* h16 = (_Float16*)(W + off);     off += NC * 2;            // 12.8 MB
  _Float16* S0  = (_Float16*)(W + off);     off += 3 * NC * 2;        // 38.4 MB
  _Float16* S1  = (_Float16*)(W + off);     off += 3 * NC * 2;        // 38.4 MB
  _Float16* zbuf = (_Float16*)(W + off);    off += NC * 2;            // 12.8 MB
  int* counts = (int*)(W + off);            off += (size_t)NT * 4;
  int* ptrv   = (int*)(W + off);            off += (size_t)(NT + 1) * 4;
  int* fill   = (int*)(W + off);            off += (size_t)NT * 4;
  int* bsum   = (int*)(W + off);            off += (NCHUNK2 + 1) * 4;
  int* boff   = (int*)(W + off);            off += (NCHUNK2 + 1) * 4;
  int* csr    = (int*)(W + off);            off += (size_t)N_EDGES * 4;
  _Float16* WPC = (_Float16*)(W + off);     off += (size_t)18 * FS * 2;
  _Float16* WHH = (_Float16*)(W + off);     off += (size_t)6 * FS * 2;
  _Float16* W1F = (_Float16*)(W + off);     off += (size_t)16384 * 2;

  // ---- per-call prep
  k_features<<<(N_NODES * 128 + 255) / 256, 256, 0, stream>>>(h16, x_type, x_tok, x_small);
  hipMemsetAsync(counts, 0, (size_t)NT * 4, stream);
  k_hist<<<(N_EDGES + 255) / 256, 256, 0, stream>>>(eidx, etype, counts);
  k_scan_a<<<NCHUNK2, 256, 0, stream>>>(counts, bsum);
  k_scan_b<<<1, 256, 0, stream>>>(bsum, boff);
  k_scan_c<<<NCHUNK2, 256, 0, stream>>>(counts, boff, ptrv, fill);
  k_place<<<(N_EDGES + 255) / 256, 256, 0, stream>>>(eidx, etype, fill, csr);
  k_prep_comb<<<(18 * 4 * 24 * 512 + 255) / 256, 256, 0, stream>>>(conv_w, gwih, WPC);
  k_prep_whh<<<(6 * 4 * 24 * 512 + 255) / 256, 256, 0, stream>>>(gwhh, WHH);
  k_prep_w1<<<(4 * 8 * 512 + 255) / 256, 256, 0, stream>>>(hw1, W1F);

  // ---- main loop: 2 blocks x 3 steps; fused gather+GRU; ping-pong S0/S1
  for (int b = 0; b < 2; ++b) {
    for (int s = 0; s < 3; ++s) {
      const _Float16* Msrc = (s == 0) ? h16 : ((s == 1) ? S0 : S1);
      size_t mstr = (s == 0) ? 0 : NC;
      _Float16* Sout = (s == 1) ? S1 : S0;
      k_step<<<3 * NB, 512, 0, stream>>>(Msrc, mstr, Sout, ptrv, csr,
          WPC + (size_t)(b * 9 + s) * FS, WHH + (size_t)b * 3 * FS,
          gbih + (size_t)b * 3 * 384, gbhh + (size_t)b * 3 * 384);
    }
    k_ln<<<(N_NODES + 3) / 4, 256, 0, stream>>>(h16, S0, ln_g + b * 128, ln_b + b * 128);
  }
  // ---- head
  k_gemm_head<<<NB, 256, 0, stream>>>(h16, W1F, hb1, zbuf);
  k_head2<<<(N_NODES + 255) / 256, 256, 0, stream>>>(zbuf, hw2, hb2, out);
}

// Round 8
// 825.701 us; speedup vs baseline: 9.9373x; 1.0168x over previous
//
#include <hip/hip_runtime.h>
#include <cstdint>
#include <cstddef>

// Problem constants (match reference)
#define N_NODES 50000
#define N_EDGES 500000
#define NB 782              // ceil(N_NODES/64) row-blocks
#define NT 150000           // 3 * N_NODES (typed CSR)
#define NCHUNK2 586         // ceil(NT/256) scan chunks
#define FS 49152            // frag halfs per [128x384] matrix (4*24*512)
#define PSTR 136            // LDS row stride in halfs (+8 pad -> bank-spread)
#define MAXOFF 12799744u    // (N_NODES-1)*256 byte-offset clamp
// C = 128, STEPS = 3, BLOCKS = 2, NUM_ET = 3

typedef _Float16 half8 __attribute__((ext_vector_type(8)));
typedef _Float16 half2v __attribute__((ext_vector_type(2)));
typedef float floatx4 __attribute__((ext_vector_type(4)));

__device__ __forceinline__ float sigmoid_(float x) { return 1.f / (1.f + __expf(-x)); }
__device__ __forceinline__ float tanh_(float x) {
  float t = __expf(-2.f * fabsf(x));
  float r = (1.f - t) / (1.f + t);
  return copysignf(r, x);
}

// ---------------------------------------------------------------- features (fp16 h)
__global__ __launch_bounds__(256) void k_features(_Float16* __restrict__ h,
    const int* __restrict__ xtype, const int* __restrict__ xtok,
    const float* __restrict__ xs) {
  int idx = blockIdx.x * 256 + threadIdx.x;
  if (idx >= N_NODES * 128) return;
  int n = idx >> 7, c = idx & 127;
  float v;
  if (c < 32) {
    v = (xtype[n] == c) ? 1.f : 0.f;
  } else if (c < 126) {
    int tk = xtok[n];
    tk = tk < 0 ? 0 : (tk > 93 ? 93 : tk);
    v = (tk == (c - 32)) ? 1.f : 0.f;
  } else {
    v = xs[n * 2 + (c - 126)];
  }
  h[idx] = (_Float16)v;
}

// ---------------------------------------------------------------- typed-CSR build
__global__ __launch_bounds__(256) void k_hist(const int* __restrict__ ei,
    const int* __restrict__ et, int* __restrict__ counts) {
  int e = blockIdx.x * 256 + threadIdx.x;
  if (e >= N_EDGES) return;
  int d = ei[N_EDGES + e];
  int ty = et[e] & 3;
  if ((unsigned)d < N_NODES && ty < 3) atomicAdd(&counts[ty * N_NODES + d], 1);
}

__global__ __launch_bounds__(256) void k_scan_a(const int* __restrict__ counts,
    int* __restrict__ bsum) {
  int i = blockIdx.x * 256 + threadIdx.x;
  int v = (i < NT) ? counts[i] : 0;
  int lane = threadIdx.x & 63, wv = threadIdx.x >> 6;
#pragma unroll
  for (int off = 32; off > 0; off >>= 1) v += __shfl_xor(v, off);
  __shared__ int ws[4];
  if (lane == 0) ws[wv] = v;
  __syncthreads();
  if (threadIdx.x == 0) bsum[blockIdx.x] = ws[0] + ws[1] + ws[2] + ws[3];
}

__global__ __launch_bounds__(256) void k_scan_b(const int* __restrict__ bsum,
    int* __restrict__ boff) {
  __shared__ int ws[4];
  __shared__ int run_s;
  if (threadIdx.x == 0) run_s = 0;
  __syncthreads();
  int lane = threadIdx.x & 63, wv = threadIdx.x >> 6;
  for (int base = 0; base < NCHUNK2; base += 256) {
    int i = base + threadIdx.x;
    int v = (i < NCHUNK2) ? bsum[i] : 0;
    int s = v;
#pragma unroll
    for (int off = 1; off < 64; off <<= 1) { int u = __shfl_up(s, off); if (lane >= off) s += u; }
    if (lane == 63) ws[wv] = s;
    __syncthreads();
    int woff = 0;
#pragma unroll
    for (int w = 0; w < 4; ++w) woff += (w < wv) ? ws[w] : 0;
    int run = run_s;
    if (i < NCHUNK2) boff[i] = run + woff + s - v;
    __syncthreads();
    if (threadIdx.x == 255) run_s = run + woff + s;
    __syncthreads();
  }
  if (threadIdx.x == 0) boff[NCHUNK2] = run_s;
}

__global__ __launch_bounds__(256) void k_scan_c(const int* __restrict__ counts,
    const int* __restrict__ boff, int* __restrict__ ptr, int* __restrict__ fill) {
  int i = blockIdx.x * 256 + threadIdx.x;
  int v = (i < NT) ? counts[i] : 0;
  int lane = threadIdx.x & 63, wv = threadIdx.x >> 6;
  int s = v;
#pragma unroll
  for (int off = 1; off < 64; off <<= 1) { int u = __shfl_up(s, off); if (lane >= off) s += u; }
  __shared__ int ws[4];
  if (lane == 63) ws[wv] = s;
  __syncthreads();
  int woff = 0;
#pragma unroll
  for (int w = 0; w < 4; ++w) woff += (w < wv) ? ws[w] : 0;
  int excl = boff[blockIdx.x] + woff + s - v;
  if (i < NT) { ptr[i] = excl; fill[i] = excl; }
  if (blockIdx.x == 0 && threadIdx.x == 0) ptr[NT] = boff[NCHUNK2];
}

// csr stores src row as BYTE offset (src*256) -> no shift/mul in gather
__global__ __launch_bounds__(256) void k_place(const int* __restrict__ ei,
    const int* __restrict__ et, int* __restrict__ fill, int* __restrict__ csr) {
  int e = blockIdx.x * 256 + threadIdx.x;
  if (e >= N_EDGES) return;
  int srcv = ei[e], d = ei[N_EDGES + e], ty = et[e] & 3;
  if ((unsigned)d >= N_NODES || (unsigned)srcv >= N_NODES || ty >= 3) return;
  int pos = atomicAdd(&fill[ty * N_NODES + d], 1);
  if ((unsigned)pos < N_EDGES) csr[pos] = srcv << 8;
}

// ---------------------------------------------------------------- fused weight prep
// B-frag layout (384-col matrices, CT=24):
//   frag[((kc*24+ct)*64 + lane)*8 + j] = W[k = kc*32+(lane>>4)*8+j][n = ct*16+(lane&15)]
// Region 0: Wcomb = conv_w @ wih.T (18 mats). Region 1: whh frags (6). Region 2: w1 frag.
#define PREP_A (18 * 4 * 24 * 512)
#define PREP_B (6 * 4 * 24 * 512)
__global__ __launch_bounds__(256) void k_prep_all(const float* __restrict__ cw,
    const float* __restrict__ wih, const float* __restrict__ whh,
    const float* __restrict__ hw1, _Float16* __restrict__ dcomb,
    _Float16* __restrict__ dwhh, _Float16* __restrict__ dw1) {
  int idx0 = blockIdx.x * 256 + threadIdx.x;
  if (idx0 < PREP_A) {
    int idx = idx0;
    int j = idx & 7, lane = (idx >> 3) & 63;
    int r = idx >> 9;
    int ct = r % 24;
    int r2 = r / 24;
    int kc = r2 & 3, mat = r2 >> 2;
    int bt = mat / 3;
    int k = kc * 32 + ((lane >> 4) & 3) * 8 + j;
    int n = ct * 16 + (lane & 15);
    const float* wrow = cw + ((size_t)mat * 128 + k) * 128;
    const float* irow = wih + ((size_t)bt * 384 + n) * 128;
    float acc = 0.f;
#pragma unroll
    for (int q = 0; q < 128; q += 4) {
      floatx4 a = *(const floatx4*)(wrow + q);
      floatx4 b = *(const floatx4*)(irow + q);
      acc += a[0] * b[0] + a[1] * b[1] + a[2] * b[2] + a[3] * b[3];
    }
    dcomb[idx] = (_Float16)acc;
  } else if (idx0 < PREP_A + PREP_B) {
    int idx = idx0 - PREP_A;
    int j = idx & 7, lane = (idx >> 3) & 63;
    int r = idx >> 9;
    int ct = r % 24;
    int r2 = r / 24;
    int kc = r2 & 3, bt = r2 >> 2;
    int k = kc * 32 + ((lane >> 4) & 3) * 8 + j;
    int n = ct * 16 + (lane & 15);
    dwhh[idx] = (_Float16)whh[((size_t)bt * 384 + n) * 128 + k];
  } else if (idx0 < PREP_A + PREP_B + 16384) {
    int idx = idx0 - PREP_A - PREP_B;
    int j = idx & 7, lane = (idx >> 3) & 63, ct = (idx >> 9) & 7, kc = (idx >> 12) & 3;
    int k = kc * 32 + ((lane >> 4) & 3) * 8 + j;
    int n = ct * 16 + (lane & 15);
    dw1[idx] = (_Float16)hw1[n * 128 + k];
  }
}

// ---------------------------------------------------------------- fused gather + GRU step
// Block = 512 thr (8 waves), one (type, 64-row) tile.
// Phase 0a: stage M rows in LDS (coalesced). Phase 0b: gather — each 16-lane
// group owns TWO rows walked concurrently (2 loads/row/iter -> 4 in flight);
// iterations = max(ceil(cA/2),ceil(cB/2)) over groups, not sum of two maxes.
// Phase 1: MFMA GRU from LDS; epilogue hold-read from LDS-M.
__global__ __launch_bounds__(512, 4) void k_step(
    const _Float16* __restrict__ Mbase, const size_t mstride,
    _Float16* __restrict__ Sout,
    const int* __restrict__ ptr, const int* __restrict__ csr,
    const _Float16* __restrict__ WPC, const _Float16* __restrict__ WHH,
    const float* __restrict__ bi2, const float* __restrict__ bh2) {
  __shared__ __attribute__((aligned(16))) _Float16 Plds[64 * PSTR];
  __shared__ __attribute__((aligned(16))) _Float16 Mlds[64 * PSTR];
  int bid = blockIdx.x;
  int t = bid / NB, blk = bid - t * NB;
  int tid = threadIdx.x;
  int wave = tid >> 6, lane = tid & 63;
  int quad = lane >> 4, l16 = lane & 15;
  int rowbase = blk * 64;
  const size_t NC = (size_t)N_NODES * 128;
  const _Float16* Mp = Mbase + mstride * t;
  const char* Mb = (const char*)Mp;
  _Float16* Sp = Sout + (size_t)t * NC;

  // ---- phase 0a: stage M block rows (64 x 128 fp16) into LDS, coalesced
#pragma unroll
  for (int it = 0; it < 2; ++it) {
    int r = it * 32 + (tid >> 4);
    int c = (tid & 15) * 8;
    int gr = rowbase + r; if (gr >= N_NODES) gr = N_NODES - 1;
    half8 v = *(const half8*)(Mp + (size_t)gr * 128 + c);
    *(half8*)(&Mlds[r * PSTR + c]) = v;
  }

  // ---- phase 0b: gather; group g owns rows nlA = wave*8+g, nlB = nlA+4,
  // walked concurrently (cursors uniform within the 16-lane group).
  const int* ptrT = ptr + t * N_NODES;
  int g = quad;
  int coff = l16 * 16;  // byte offset within row
  int nlA = wave * 8 + g, nlB = nlA + 4;
  int nA = rowbase + nlA, nB = rowbase + nlB;
  int iA = 0, eA = 0, iB = 0, eB = 0;
  if (nA < N_NODES) { iA = ptrT[nA]; eA = ptrT[nA + 1]; }
  if (nB < N_NODES) { iB = ptrT[nB]; eB = ptrT[nB + 1]; }
  if (iA < 0) iA = 0; if (eA > N_EDGES) eA = N_EDGES;   // replay safety
  if (iB < 0) iB = 0; if (eB > N_EDGES) eB = N_EDGES;
  half8 accA = {}, accB = {};
  for (;;) {
    bool a0 = iA < eA, a1 = iA + 1 < eA;
    bool c0 = iB < eB, c1 = iB + 1 < eB;
    if (!__any(a0 || c0)) break;
    if (a0) {
      unsigned off = (unsigned)csr[iA];
      if (off > MAXOFF) off = 0;
      accA += *(const half8*)(Mb + off + coff);
    }
    if (c0) {
      unsigned off = (unsigned)csr[iB];
      if (off > MAXOFF) off = 0;
      accB += *(const half8*)(Mb + off + coff);
    }
    if (a1) {
      unsigned off = (unsigned)csr[iA + 1];
      if (off > MAXOFF) off = 0;
      accA += *(const half8*)(Mb + off + coff);
    }
    if (c1) {
      unsigned off = (unsigned)csr[iB + 1];
      if (off > MAXOFF) off = 0;
      accB += *(const half8*)(Mb + off + coff);
    }
    iA += 2; iB += 2;
  }
  *(half8*)(&Plds[nlA * PSTR + l16 * 8]) = accA;
  *(half8*)(&Plds[nlB * PSTR + l16 * 8]) = accB;
  __syncthreads();

  // ---- phase 1: MFMA GRU. u = wave owns cts {u (r), 8+u (z), 16+u (n)}.
  const half8* wpc = (const half8*)(WPC + (size_t)t * 3 * FS);
  const half8* whh = (const half8*)(WHH + (size_t)t * FS);
  const float* bi = bi2 + (size_t)t * 384;
  const float* bh = bh2 + (size_t)t * 384;
  int u = wave;
  floatx4 zero = {0.f, 0.f, 0.f, 0.f};
  floatx4 aR[4], aZ[4], aNP[4], aNM[4];
#pragma unroll
  for (int rt = 0; rt < 4; ++rt) { aR[rt] = zero; aZ[rt] = zero; aNP[rt] = zero; aNM[rt] = zero; }
#pragma unroll
  for (int kc = 0; kc < 4; ++kc) {   // gi part: P @ Wcomb
    half8 af[4];
#pragma unroll
    for (int rt = 0; rt < 4; ++rt)
      af[rt] = *(const half8*)(&Plds[(rt * 16 + l16) * PSTR + kc * 32 + quad * 8]);
    half8 br = wpc[(kc * 24 + u) * 64 + lane];
    half8 bz = wpc[(kc * 24 + 8 + u) * 64 + lane];
    half8 bn = wpc[(kc * 24 + 16 + u) * 64 + lane];
#pragma unroll
    for (int rt = 0; rt < 4; ++rt) {
      aR[rt] = __builtin_amdgcn_mfma_f32_16x16x32_f16(af[rt], br, aR[rt], 0, 0, 0);
      aZ[rt] = __builtin_amdgcn_mfma_f32_16x16x32_f16(af[rt], bz, aZ[rt], 0, 0, 0);
      aNP[rt] = __builtin_amdgcn_mfma_f32_16x16x32_f16(af[rt], bn, aNP[rt], 0, 0, 0);
    }
  }
#pragma unroll
  for (int kc = 0; kc < 4; ++kc) {   // gh part: M @ whh.T
    half8 af[4];
#pragma unroll
    for (int rt = 0; rt < 4; ++rt)
      af[rt] = *(const half8*)(&Mlds[(rt * 16 + l16) * PSTR + kc * 32 + quad * 8]);
    half8 br = whh[(kc * 24 + u) * 64 + lane];
    half8 bz = whh[(kc * 24 + 8 + u) * 64 + lane];
    half8 bn = whh[(kc * 24 + 16 + u) * 64 + lane];
#pragma unroll
    for (int rt = 0; rt < 4; ++rt) {
      aR[rt] = __builtin_amdgcn_mfma_f32_16x16x32_f16(af[rt], br, aR[rt], 0, 0, 0);
      aZ[rt] = __builtin_amdgcn_mfma_f32_16x16x32_f16(af[rt], bz, aZ[rt], 0, 0, 0);
      aNM[rt] = __builtin_amdgcn_mfma_f32_16x16x32_f16(af[rt], bn, aNM[rt], 0, 0, 0);
    }
  }
  // ---- epilogue (C layout: row = rt*16 + quad*4 + q, col = u*16 + l16)
  int col = u * 16 + l16;
  float br_ = bi[col] + bh[col];
  float bz_ = bi[128 + col] + bh[128 + col];
  float bin = bi[256 + col], bhn = bh[256 + col];
#pragma unroll
  for (int rt = 0; rt < 4; ++rt) {
#pragma unroll
    for (int q = 0; q < 4; ++q) {
      int lr = rt * 16 + quad * 4 + q;
      int row = rowbase + lr;
      if (row < N_NODES) {
        float r = sigmoid_(aR[rt][q] + br_);
        float z = sigmoid_(aZ[rt][q] + bz_);
        float nt = tanh_(aNP[rt][q] + bin + r * (aNM[rt][q] + bhn));
        float hold = (float)Mlds[lr * PSTR + col];
        Sp[(size_t)row * 128 + col] = (_Float16)((1.f - z) * nt + z * hold);
      }
    }
  }
}

// ---------------------------------------------------------------- LayerNorm(h + S0+S1+S2) + ReLU -> h (fp16)
__global__ __launch_bounds__(256) void k_ln(_Float16* __restrict__ h,
    const _Float16* __restrict__ S, const float* __restrict__ gamma,
    const float* __restrict__ beta) {
  int wave = threadIdx.x >> 6, lane = threadIdx.x & 63;
  int n = blockIdx.x * 4 + wave;
  if (n >= N_NODES) return;
  const size_t NC = (size_t)N_NODES * 128;
  size_t base = (size_t)n * 128 + lane * 2;
  half2v hv = *(const half2v*)(h + base);
  half2v s0 = *(const half2v*)(S + base);
  half2v s1 = *(const half2v*)(S + NC + base);
  half2v s2 = *(const half2v*)(S + 2 * NC + base);
  float v0 = (float)hv[0] + (float)s0[0] + (float)s1[0] + (float)s2[0];
  float v1 = (float)hv[1] + (float)s0[1] + (float)s1[1] + (float)s2[1];
  float s = v0 + v1, sq = v0 * v0 + v1 * v1;
#pragma unroll
  for (int off = 32; off > 0; off >>= 1) {
    s += __shfl_xor(s, off);
    sq += __shfl_xor(sq, off);
  }
  float mu = s * 0.0078125f;
  float var = sq * 0.0078125f - mu * mu;
  float rs = rsqrtf(var + 1e-5f);
  float o0 = (v0 - mu) * rs * gamma[lane * 2] + beta[lane * 2];
  float o1 = (v1 - mu) * rs * gamma[lane * 2 + 1] + beta[lane * 2 + 1];
  half2v ov; ov[0] = (_Float16)fmaxf(o0, 0.f); ov[1] = (_Float16)fmaxf(o1, 0.f);
  *(half2v*)(h + base) = ov;
}

// ---------------------------------------------------------------- fused head: out = relu(h@w1.T+b1) @ w2.T + b2
// Block = 256 thr, 64 rows. GEMM part writes z into LDS; then 128 threads do
// the 2-col dot from LDS. Kills the zbuf round-trip.
__global__ __launch_bounds__(256, 4) void k_head(const _Float16* __restrict__ A,
    const _Float16* __restrict__ Wf, const float* __restrict__ bias,
    const float* __restrict__ w2, const float* __restrict__ b2,
    float* __restrict__ out) {
  __shared__ __attribute__((aligned(16))) _Float16 zl[64 * PSTR];
  __shared__ float w2s[256];
  int blk = blockIdx.x;
  int wave = threadIdx.x >> 6, lane = threadIdx.x & 63;
  int quad = lane >> 4, l16 = lane & 15;
  int rowbase = blk * 64;
  if (threadIdx.x < 256) w2s[threadIdx.x] = w2[threadIdx.x];
  const half8* wf = (const half8*)Wf;
  int ar[4];
#pragma unroll
  for (int rt = 0; rt < 4; ++rt) {
    int r = rowbase + rt * 16 + l16;
    ar[rt] = r < N_NODES ? r : N_NODES - 1;
  }
  floatx4 zero = {0.f, 0.f, 0.f, 0.f};
  floatx4 acc[4][2];
#pragma unroll
  for (int rt = 0; rt < 4; ++rt) { acc[rt][0] = zero; acc[rt][1] = zero; }
#pragma unroll
  for (int kc = 0; kc < 4; ++kc) {
    half8 af[4];
#pragma unroll
    for (int rt = 0; rt < 4; ++rt)
      af[rt] = *(const half8*)(A + (size_t)ar[rt] * 128 + kc * 32 + quad * 8);
    half8 b0 = wf[(kc * 8 + 2 * wave) * 64 + lane];
    half8 b1 = wf[(kc * 8 + 2 * wave + 1) * 64 + lane];
#pragma unroll
    for (int rt = 0; rt < 4; ++rt) {
      acc[rt][0] = __builtin_amdgcn_mfma_f32_16x16x32_f16(af[rt], b0, acc[rt][0], 0, 0, 0);
      acc[rt][1] = __builtin_amdgcn_mfma_f32_16x16x32_f16(af[rt], b1, acc[rt][1], 0, 0, 0);
    }
  }
  int col = wave * 32 + l16;
#pragma unroll
  for (int rt = 0; rt < 4; ++rt) {
#pragma unroll
    for (int q = 0; q < 4; ++q) {
      int lr = rt * 16 + quad * 4 + q;
      zl[lr * PSTR + col] = (_Float16)fmaxf(acc[rt][0][q] + bias[col], 0.f);
      zl[lr * PSTR + col + 16] = (_Float16)fmaxf(acc[rt][1][q] + bias[col + 16], 0.f);
    }
  }
  __syncthreads();
  // 128 threads: (row = tid>>1, o = tid&1)
  int tid = threadIdx.x;
  if (tid < 128) {
    int lr = tid >> 1, o = tid & 1;
    int row = rowbase + lr;
    if (row < N_NODES) {
      const float* wr = w2s + o * 128;
      float a = 0.f;
#pragma unroll
      for (int k = 0; k < 128; ++k) a += (float)zl[lr * PSTR + k] * wr[k];
      out[(size_t)row * 2 + o] = a + b2[o];
    }
  }
}

// ================================================================ launch
extern "C" void kernel_launch(void* const* d_in, const int* in_sizes, int n_in,
                              void* d_out, int out_size, void* d_ws, size_t ws_size,
                              hipStream_t stream) {
  const int*   x_type  = (const int*)d_in[0];
  const int*   x_tok   = (const int*)d_in[1];
  const float* x_small = (const float*)d_in[2];
  const int*   eidx    = (const int*)d_in[3];
  const int*   etype   = (const int*)d_in[4];
  const float* conv_w  = (const float*)d_in[5];
  const float* gwih    = (const float*)d_in[6];
  const float* gwhh    = (const float*)d_in[7];
  const float* gbih    = (const float*)d_in[8];
  const float* gbhh    = (const float*)d_in[9];
  const float* ln_g    = (const float*)d_in[10];
  const float* ln_b    = (const float*)d_in[11];
  const float* hw1     = (const float*)d_in[12];
  const float* hb1     = (const float*)d_in[13];
  const float* hw2     = (const float*)d_in[14];
  const float* hb2     = (const float*)d_in[15];
  float* out = (float*)d_out;

  const size_t NC = (size_t)N_NODES * 128;
  char* W = (char*)d_ws;
  size_t off = 0;
  _Float16* h16 = (_Float16*)(W + off);     off += NC * 2;            // 12.8 MB
  _Float16* S0  = (_Float16*)(W + off);     off += 3 * NC * 2;        // 38.4 MB
  _Float16* S1  = (_Float16*)(W + off);     off += 3 * NC * 2;        // 38.4 MB
  int* counts = (int*)(W + off);            off += (size_t)NT * 4;
  int* ptrv   = (int*)(W + off);            off += (size_t)(NT + 1) * 4;
  int* fill   = (int*)(W + off);            off += (size_t)NT * 4;
  int* bsum   = (int*)(W + off);            off += (NCHUNK2 + 1) * 4;
  int* boff   = (int*)(W + off);            off += (NCHUNK2 + 1) * 4;
  int* csr    = (int*)(W + off);            off += (size_t)N_EDGES * 4;
  _Float16* WPC = (_Float16*)(W + off);     off += (size_t)18 * FS * 2;
  _Float16* WHH = (_Float16*)(W + off);     off += (size_t)6 * FS * 2;
  _Float16* W1F = (_Float16*)(W + off);     off += (size_t)16384 * 2;

  // ---- per-call prep
  k_features<<<(N_NODES * 128 + 255) / 256, 256, 0, stream>>>(h16, x_type, x_tok, x_small);
  hipMemsetAsync(counts, 0, (size_t)NT * 4, stream);
  k_hist<<<(N_EDGES + 255) / 256, 256, 0, stream>>>(eidx, etype, counts);
  k_scan_a<<<NCHUNK2, 256, 0, stream>>>(counts, bsum);
  k_scan_b<<<1, 256, 0, stream>>>(bsum, boff);
  k_scan_c<<<NCHUNK2, 256, 0, stream>>>(counts, boff, ptrv, fill);
  k_place<<<(N_EDGES + 255) / 256, 256, 0, stream>>>(eidx, etype, fill, csr);
  k_prep_all<<<(PREP_A + PREP_B + 16384 + 255) / 256, 256, 0, stream>>>(
      conv_w, gwih, gwhh, hw1, WPC, WHH, W1F);

  // ---- main loop: 2 blocks x 3 steps; fused gather+GRU; ping-pong S0/S1
  for (int b = 0; b < 2; ++b) {
    for (int s = 0; s < 3; ++s) {
      const _Float16* Msrc = (s == 0) ? h16 : ((s == 1) ? S0 : S1);
      size_t mstr = (s == 0) ? 0 : NC;
      _Float16* Sout = (s == 1) ? S1 : S0;
      k_step<<<3 * NB, 512, 0, stream>>>(Msrc, mstr, Sout, ptrv, csr,
          WPC + (size_t)(b * 9 + s) * FS, WHH + (size_t)b * 3 * FS,
          gbih + (size_t)b * 3 * 384, gbhh + (size_t)b * 3 * 384);
    }
    k_ln<<<(N_NODES + 3) / 4, 256, 0, stream>>>(h16, S0, ln_g + b * 128, ln_b + b * 128);
  }
  // ---- fused head
  k_head<<<NB, 256, 0, stream>>>(h16, W1F, hb1, hw2, hb2, out);
}

// Round 9
// 724.161 us; speedup vs baseline: 11.3307x; 1.1402x over previous
//
#include <hip/hip_runtime.h>
#include <cstdint>
#include <cstddef>

// Problem constants (match reference)
#define N_NODES 50000
#define N_EDGES 500000
#define NB 782              // ceil(N_NODES/64) row-blocks
#define NT 150000           // 3 * N_NODES (typed CSR)
#define NCHUNK2 586         // ceil(NT/256) scan chunks
#define FS 49152            // frag halfs per [128x384] matrix (4*24*512)
#define PSTR 136            // LDS row stride in halfs (+8 pad -> bank-spread)
#define MAXOFF 12799744u    // (N_NODES-1)*256 byte-offset clamp
#define ECAP 768            // LDS csr-slice capacity (mean 213, 20+ sigma margin)
// C = 128, STEPS = 3, BLOCKS = 2, NUM_ET = 3

typedef _Float16 half8 __attribute__((ext_vector_type(8)));
typedef _Float16 half2v __attribute__((ext_vector_type(2)));
typedef float floatx4 __attribute__((ext_vector_type(4)));

__device__ __forceinline__ float sigmoid_(float x) { return 1.f / (1.f + __expf(-x)); }
__device__ __forceinline__ float tanh_(float x) {
  float t = __expf(-2.f * fabsf(x));
  float r = (1.f - t) / (1.f + t);
  return copysignf(r, x);
}

// ---------------------------------------------------------------- features (fp16 h)
__global__ __launch_bounds__(256) void k_features(_Float16* __restrict__ h,
    const int* __restrict__ xtype, const int* __restrict__ xtok,
    const float* __restrict__ xs) {
  int idx = blockIdx.x * 256 + threadIdx.x;
  if (idx >= N_NODES * 128) return;
  int n = idx >> 7, c = idx & 127;
  float v;
  if (c < 32) {
    v = (xtype[n] == c) ? 1.f : 0.f;
  } else if (c < 126) {
    int tk = xtok[n];
    tk = tk < 0 ? 0 : (tk > 93 ? 93 : tk);
    v = (tk == (c - 32)) ? 1.f : 0.f;
  } else {
    v = xs[n * 2 + (c - 126)];
  }
  h[idx] = (_Float16)v;
}

// ---------------------------------------------------------------- typed-CSR build
__global__ __launch_bounds__(256) void k_hist(const int* __restrict__ ei,
    const int* __restrict__ et, int* __restrict__ counts) {
  int e = blockIdx.x * 256 + threadIdx.x;
  if (e >= N_EDGES) return;
  int d = ei[N_EDGES + e];
  int ty = et[e] & 3;
  if ((unsigned)d < N_NODES && ty < 3) atomicAdd(&counts[ty * N_NODES + d], 1);
}

__global__ __launch_bounds__(256) void k_scan_a(const int* __restrict__ counts,
    int* __restrict__ bsum) {
  int i = blockIdx.x * 256 + threadIdx.x;
  int v = (i < NT) ? counts[i] : 0;
  int lane = threadIdx.x & 63, wv = threadIdx.x >> 6;
#pragma unroll
  for (int off = 32; off > 0; off >>= 1) v += __shfl_xor(v, off);
  __shared__ int ws[4];
  if (lane == 0) ws[wv] = v;
  __syncthreads();
  if (threadIdx.x == 0) bsum[blockIdx.x] = ws[0] + ws[1] + ws[2] + ws[3];
}

__global__ __launch_bounds__(256) void k_scan_b(const int* __restrict__ bsum,
    int* __restrict__ boff) {
  __shared__ int ws[4];
  __shared__ int run_s;
  if (threadIdx.x == 0) run_s = 0;
  __syncthreads();
  int lane = threadIdx.x & 63, wv = threadIdx.x >> 6;
  for (int base = 0; base < NCHUNK2; base += 256) {
    int i = base + threadIdx.x;
    int v = (i < NCHUNK2) ? bsum[i] : 0;
    int s = v;
#pragma unroll
    for (int off = 1; off < 64; off <<= 1) { int u = __shfl_up(s, off); if (lane >= off) s += u; }
    if (lane == 63) ws[wv] = s;
    __syncthreads();
    int woff = 0;
#pragma unroll
    for (int w = 0; w < 4; ++w) woff += (w < wv) ? ws[w] : 0;
    int run = run_s;
    if (i < NCHUNK2) boff[i] = run + woff + s - v;
    __syncthreads();
    if (threadIdx.x == 255) run_s = run + woff + s;
    __syncthreads();
  }
  if (threadIdx.x == 0) boff[NCHUNK2] = run_s;
}

__global__ __launch_bounds__(256) void k_scan_c(const int* __restrict__ counts,
    const int* __restrict__ boff, int* __restrict__ ptr, int* __restrict__ fill) {
  int i = blockIdx.x * 256 + threadIdx.x;
  int v = (i < NT) ? counts[i] : 0;
  int lane = threadIdx.x & 63, wv = threadIdx.x >> 6;
  int s = v;
#pragma unroll
  for (int off = 1; off < 64; off <<= 1) { int u = __shfl_up(s, off); if (lane >= off) s += u; }
  __shared__ int ws[4];
  if (lane == 63) ws[wv] = s;
  __syncthreads();
  int woff = 0;
#pragma unroll
  for (int w = 0; w < 4; ++w) woff += (w < wv) ? ws[w] : 0;
  int excl = boff[blockIdx.x] + woff + s - v;
  if (i < NT) { ptr[i] = excl; fill[i] = excl; }
  if (blockIdx.x == 0 && threadIdx.x == 0) ptr[NT] = boff[NCHUNK2];
}

// csr stores src row as BYTE offset (src*256) -> no shift/mul in gather
__global__ __launch_bounds__(256) void k_place(const int* __restrict__ ei,
    const int* __restrict__ et, int* __restrict__ fill, int* __restrict__ csr) {
  int e = blockIdx.x * 256 + threadIdx.x;
  if (e >= N_EDGES) return;
  int srcv = ei[e], d = ei[N_EDGES + e], ty = et[e] & 3;
  if ((unsigned)d >= N_NODES || (unsigned)srcv >= N_NODES || ty >= 3) return;
  int pos = atomicAdd(&fill[ty * N_NODES + d], 1);
  if ((unsigned)pos < N_EDGES) csr[pos] = srcv << 8;
}

// ---------------------------------------------------------------- weight prep
// B-frag layout (384-col matrices, CT=24):
//   frag[((kc*24+ct)*64 + lane)*8 + j] = W[k = kc*32+(lane>>4)*8+j][n = ct*16+(lane&15)]

// Wcomb[mat] = conv_w[mat] @ wih[bt].T via MFMA, written directly in frag layout.
// grid = 18 mats x 2 row-halves, block = 512 (8 waves); wave u owns cols
// ct = u*3..u*3+2; 64 k-rows per block-half. Direct-frag loads, no LDS.
__global__ __launch_bounds__(512) void k_prep_cmb(const float* __restrict__ cw,
    const float* __restrict__ wih, _Float16* __restrict__ dst) {
  int mat = blockIdx.x >> 1, half = blockIdx.x & 1;
  int bt = mat / 3;
  int u = threadIdx.x >> 6, lane = threadIdx.x & 63;
  int quad = lane >> 4, l16 = lane & 15;
  floatx4 zero = {0.f, 0.f, 0.f, 0.f};
  floatx4 acc[4][3];
#pragma unroll
  for (int rt = 0; rt < 4; ++rt)
#pragma unroll
    for (int cc = 0; cc < 3; ++cc) acc[rt][cc] = zero;
#pragma unroll
  for (int jc = 0; jc < 4; ++jc) {
    half8 af[4], bf[3];
#pragma unroll
    for (int rt = 0; rt < 4; ++rt) {
      int m = half * 64 + rt * 16 + l16;
      const float* ap = cw + ((size_t)mat * 128 + m) * 128 + jc * 32 + quad * 8;
      floatx4 a0 = *(const floatx4*)ap;
      floatx4 a1 = *(const floatx4*)(ap + 4);
#pragma unroll
      for (int i = 0; i < 4; ++i) { af[rt][i] = (_Float16)a0[i]; af[rt][4 + i] = (_Float16)a1[i]; }
    }
#pragma unroll
    for (int cc = 0; cc < 3; ++cc) {
      int n = (u * 3 + cc) * 16 + l16;
      const float* bp = wih + ((size_t)bt * 384 + n) * 128 + jc * 32 + quad * 8;
      floatx4 b0 = *(const floatx4*)bp;
      floatx4 b1 = *(const floatx4*)(bp + 4);
#pragma unroll
      for (int i = 0; i < 4; ++i) { bf[cc][i] = (_Float16)b0[i]; bf[cc][4 + i] = (_Float16)b1[i]; }
    }
#pragma unroll
    for (int rt = 0; rt < 4; ++rt)
#pragma unroll
      for (int cc = 0; cc < 3; ++cc)
        acc[rt][cc] = __builtin_amdgcn_mfma_f32_16x16x32_f16(af[rt], bf[cc], acc[rt][cc], 0, 0, 0);
  }
  // scatter into frag layout: k = half*64 + rt*16 + quad*4 + q, n = ct*16 + l16
#pragma unroll
  for (int rt = 0; rt < 4; ++rt) {
#pragma unroll
    for (int cc = 0; cc < 3; ++cc) {
      int ctg = u * 3 + cc;
#pragma unroll
      for (int q = 0; q < 4; ++q) {
        int k = half * 64 + rt * 16 + quad * 4 + q;
        int kc2 = k >> 5, r5 = k & 31;
        int lane2 = (r5 >> 3) * 16 + l16, j2 = r5 & 7;
        dst[(size_t)mat * FS + (size_t)((kc2 * 24 + ctg) * 64 + lane2) * 8 + j2] =
            (_Float16)acc[rt][cc][q];
      }
    }
  }
}

// whh frags (6 mats) + w1 frag — pure elementwise convert/permute.
#define PREP_B (6 * 4 * 24 * 512)
__global__ __launch_bounds__(256) void k_prep_misc(const float* __restrict__ whh,
    const float* __restrict__ hw1, _Float16* __restrict__ dwhh,
    _Float16* __restrict__ dw1) {
  int idx0 = blockIdx.x * 256 + threadIdx.x;
  if (idx0 < PREP_B) {
    int idx = idx0;
    int j = idx & 7, lane = (idx >> 3) & 63;
    int r = idx >> 9;
    int ct = r % 24;
    int r2 = r / 24;
    int kc = r2 & 3, bt = r2 >> 2;
    int k = kc * 32 + ((lane >> 4) & 3) * 8 + j;
    int n = ct * 16 + (lane & 15);
    dwhh[idx] = (_Float16)whh[((size_t)bt * 384 + n) * 128 + k];
  } else if (idx0 < PREP_B + 16384) {
    int idx = idx0 - PREP_B;
    int j = idx & 7, lane = (idx >> 3) & 63, ct = (idx >> 9) & 7, kc = (idx >> 12) & 3;
    int k = kc * 32 + ((lane >> 4) & 3) * 8 + j;
    int n = ct * 16 + (lane & 15);
    dw1[idx] = (_Float16)hw1[n * 128 + k];
  }
}

// ---------------------------------------------------------------- fused gather + GRU step
// Block = 512 thr (8 waves), one (type, 64-row) tile.
// Phase 0a: stage M rows + this block's ptr slice. Phase 0b: stage the csr
// slice (<= ~300 edges) into LDS with ONE coalesced load. Phase 0c: gather —
// offsets come from LDS, so the 4-wide row-load bursts have NO dependent
// address chain (8 loads in flight per 16-lane group). Phase 1: MFMA GRU.
__global__ __launch_bounds__(512, 4) void k_step(
    const _Float16* __restrict__ Mbase, const size_t mstride,
    _Float16* __restrict__ Sout,
    const int* __restrict__ ptr, const int* __restrict__ csr,
    const _Float16* __restrict__ WPC, const _Float16* __restrict__ WHH,
    const float* __restrict__ bi2, const float* __restrict__ bh2) {
  __shared__ __attribute__((aligned(16))) _Float16 Plds[64 * PSTR];
  __shared__ __attribute__((aligned(16))) _Float16 Mlds[64 * PSTR];
  __shared__ int Elds[ECAP];
  __shared__ int Pt[65];
  int bid = blockIdx.x;
  int t = bid / NB, blk = bid - t * NB;
  int tid = threadIdx.x;
  int wave = tid >> 6, lane = tid & 63;
  int quad = lane >> 4, l16 = lane & 15;
  int rowbase = blk * 64;
  const size_t NC = (size_t)N_NODES * 128;
  const _Float16* Mp = Mbase + mstride * t;
  const char* Mb = (const char*)Mp;
  _Float16* Sp = Sout + (size_t)t * NC;
  const int* ptrT = ptr + t * N_NODES;

  // ---- phase 0a: stage ptr slice + M block rows
  if (tid < 65) {
    int n = rowbase + tid;
    if (n > N_NODES) n = N_NODES;
    int v = ptrT[n];
    if (v < 0) v = 0;
    if (v > N_EDGES) v = N_EDGES;   // replay safety
    Pt[tid] = v;
  }
#pragma unroll
  for (int it = 0; it < 2; ++it) {
    int r = it * 32 + (tid >> 4);
    int c = (tid & 15) * 8;
    int gr = rowbase + r; if (gr >= N_NODES) gr = N_NODES - 1;
    half8 v = *(const half8*)(Mp + (size_t)gr * 128 + c);
    *(half8*)(&Mlds[r * PSTR + c]) = v;
  }
  __syncthreads();

  // ---- phase 0b: stage csr slice (coalesced, one round typically)
  int bse = Pt[0];
  int cnt = Pt[64] - bse;
  if (cnt < 0) cnt = 0;
  for (int i = tid; i < cnt && i < ECAP; i += 512) Elds[i] = csr[bse + i];
  __syncthreads();

  // ---- phase 0c: gather; group g owns rows nlA = wave*8+g, nlB = nlA+4
  int g = quad;
  int coff = l16 * 16;  // byte offset within row
  int nlA = wave * 8 + g, nlB = nlA + 4;
  int iA = Pt[nlA] - bse, eA = Pt[nlA + 1] - bse;
  int iB = Pt[nlB] - bse, eB = Pt[nlB + 1] - bse;
  if (iA < 0) iA = 0; if (eA > cnt) eA = cnt; if (eA < iA) eA = iA;
  if (iB < 0) iB = 0; if (eB > cnt) eB = cnt; if (eB < iB) eB = iB;
  half8 accA = {}, accB = {};
  while (__any(iA < eA || iB < eB)) {
#pragma unroll
    for (int uu = 0; uu < 4; ++uu) {
      if (iA + uu < eA) {
        int ii = iA + uu;
        unsigned off = (unsigned)((ii < ECAP) ? Elds[ii] : csr[bse + ii]);
        if (off > MAXOFF) off = 0;
        accA += *(const half8*)(Mb + off + coff);
      }
      if (iB + uu < eB) {
        int ii = iB + uu;
        unsigned off = (unsigned)((ii < ECAP) ? Elds[ii] : csr[bse + ii]);
        if (off > MAXOFF) off = 0;
        accB += *(const half8*)(Mb + off + coff);
      }
    }
    iA += 4; iB += 4;
  }
  *(half8*)(&Plds[nlA * PSTR + l16 * 8]) = accA;
  *(half8*)(&Plds[nlB * PSTR + l16 * 8]) = accB;
  __syncthreads();

  // ---- phase 1: MFMA GRU. u = wave owns cts {u (r), 8+u (z), 16+u (n)}.
  const half8* wpc = (const half8*)(WPC + (size_t)t * 3 * FS);
  const half8* whh = (const half8*)(WHH + (size_t)t * FS);
  const float* bi = bi2 + (size_t)t * 384;
  const float* bh = bh2 + (size_t)t * 384;
  int u = wave;
  floatx4 zero = {0.f, 0.f, 0.f, 0.f};
  floatx4 aR[4], aZ[4], aNP[4], aNM[4];
#pragma unroll
  for (int rt = 0; rt < 4; ++rt) { aR[rt] = zero; aZ[rt] = zero; aNP[rt] = zero; aNM[rt] = zero; }
#pragma unroll
  for (int kc = 0; kc < 4; ++kc) {   // gi part: P @ Wcomb
    half8 af[4];
#pragma unroll
    for (int rt = 0; rt < 4; ++rt)
      af[rt] = *(const half8*)(&Plds[(rt * 16 + l16) * PSTR + kc * 32 + quad * 8]);
    half8 br = wpc[(kc * 24 + u) * 64 + lane];
    half8 bz = wpc[(kc * 24 + 8 + u) * 64 + lane];
    half8 bn = wpc[(kc * 24 + 16 + u) * 64 + lane];
#pragma unroll
    for (int rt = 0; rt < 4; ++rt) {
      aR[rt] = __builtin_amdgcn_mfma_f32_16x16x32_f16(af[rt], br, aR[rt], 0, 0, 0);
      aZ[rt] = __builtin_amdgcn_mfma_f32_16x16x32_f16(af[rt], bz, aZ[rt], 0, 0, 0);
      aNP[rt] = __builtin_amdgcn_mfma_f32_16x16x32_f16(af[rt], bn, aNP[rt], 0, 0, 0);
    }
  }
#pragma unroll
  for (int kc = 0; kc < 4; ++kc) {   // gh part: M @ whh.T
    half8 af[4];
#pragma unroll
    for (int rt = 0; rt < 4; ++rt)
      af[rt] = *(const half8*)(&Mlds[(rt * 16 + l16) * PSTR + kc * 32 + quad * 8]);
    half8 br = whh[(kc * 24 + u) * 64 + lane];
    half8 bz = whh[(kc * 24 + 8 + u) * 64 + lane];
    half8 bn = whh[(kc * 24 + 16 + u) * 64 + lane];
#pragma unroll
    for (int rt = 0; rt < 4; ++rt) {
      aR[rt] = __builtin_amdgcn_mfma_f32_16x16x32_f16(af[rt], br, aR[rt], 0, 0, 0);
      aZ[rt] = __builtin_amdgcn_mfma_f32_16x16x32_f16(af[rt], bz, aZ[rt], 0, 0, 0);
      aNM[rt] = __builtin_amdgcn_mfma_f32_16x16x32_f16(af[rt], bn, aNM[rt], 0, 0, 0);
    }
  }
  // ---- epilogue (C layout: row = rt*16 + quad*4 + q, col = u*16 + l16)
  int col = u * 16 + l16;
  float br_ = bi[col] + bh[col];
  float bz_ = bi[128 + col] + bh[128 + col];
  float bin = bi[256 + col], bhn = bh[256 + col];
#pragma unroll
  for (int rt = 0; rt < 4; ++rt) {
#pragma unroll
    for (int q = 0; q < 4; ++q) {
      int lr = rt * 16 + quad * 4 + q;
      int row = rowbase + lr;
      if (row < N_NODES) {
        float r = sigmoid_(aR[rt][q] + br_);
        float z = sigmoid_(aZ[rt][q] + bz_);
        float nt = tanh_(aNP[rt][q] + bin + r * (aNM[rt][q] + bhn));
        float hold = (float)Mlds[lr * PSTR + col];
        Sp[(size_t)row * 128 + col] = (_Float16)((1.f - z) * nt + z * hold);
      }
    }
  }
}

// ---------------------------------------------------------------- LayerNorm(h + S0+S1+S2) + ReLU -> h (fp16)
__global__ __launch_bounds__(256) void k_ln(_Float16* __restrict__ h,
    const _Float16* __restrict__ S, const float* __restrict__ gamma,
    const float* __restrict__ beta) {
  int wave = threadIdx.x >> 6, lane = threadIdx.x & 63;
  int n = blockIdx.x * 4 + wave;
  if (n >= N_NODES) return;
  const size_t NC = (size_t)N_NODES * 128;
  size_t base = (size_t)n * 128 + lane * 2;
  half2v hv = *(const half2v*)(h + base);
  half2v s0 = *(const half2v*)(S + base);
  half2v s1 = *(const half2v*)(S + NC + base);
  half2v s2 = *(const half2v*)(S + 2 * NC + base);
  float v0 = (float)hv[0] + (float)s0[0] + (float)s1[0] + (float)s2[0];
  float v1 = (float)hv[1] + (float)s0[1] + (float)s1[1] + (float)s2[1];
  float s = v0 + v1, sq = v0 * v0 + v1 * v1;
#pragma unroll
  for (int off = 32; off > 0; off >>= 1) {
    s += __shfl_xor(s, off);
    sq += __shfl_xor(sq, off);
  }
  float mu = s * 0.0078125f;
  float var = sq * 0.0078125f - mu * mu;
  float rs = rsqrtf(var + 1e-5f);
  float o0 = (v0 - mu) * rs * gamma[lane * 2] + beta[lane * 2];
  float o1 = (v1 - mu) * rs * gamma[lane * 2 + 1] + beta[lane * 2 + 1];
  half2v ov; ov[0] = (_Float16)fmaxf(o0, 0.f); ov[1] = (_Float16)fmaxf(o1, 0.f);
  *(half2v*)(h + base) = ov;
}

// ---------------------------------------------------------------- fused head: out = relu(h@w1.T+b1) @ w2.T + b2
__global__ __launch_bounds__(256, 4) void k_head(const _Float16* __restrict__ A,
    const _Float16* __restrict__ Wf, const float* __restrict__ bias,
    const float* __restrict__ w2, const float* __restrict__ b2,
    float* __restrict__ out) {
  __shared__ __attribute__((aligned(16))) _Float16 zl[64 * PSTR];
  __shared__ float w2s[256];
  int blk = blockIdx.x;
  int wave = threadIdx.x >> 6, lane = threadIdx.x & 63;
  int quad = lane >> 4, l16 = lane & 15;
  int rowbase = blk * 64;
  if (threadIdx.x < 256) w2s[threadIdx.x] = w2[threadIdx.x];
  const half8* wf = (const half8*)Wf;
  int ar[4];
#pragma unroll
  for (int rt = 0; rt < 4; ++rt) {
    int r = rowbase + rt * 16 + l16;
    ar[rt] = r < N_NODES ? r : N_NODES - 1;
  }
  floatx4 zero = {0.f, 0.f, 0.f, 0.f};
  floatx4 acc[4][2];
#pragma unroll
  for (int rt = 0; rt < 4; ++rt) { acc[rt][0] = zero; acc[rt][1] = zero; }
#pragma unroll
  for (int kc = 0; kc < 4; ++kc) {
    half8 af[4];
#pragma unroll
    for (int rt = 0; rt < 4; ++rt)
      af[rt] = *(const half8*)(A + (size_t)ar[rt] * 128 + kc * 32 + quad * 8);
    half8 b0 = wf[(kc * 8 + 2 * wave) * 64 + lane];
    half8 b1 = wf[(kc * 8 + 2 * wave + 1) * 64 + lane];
#pragma unroll
    for (int rt = 0; rt < 4; ++rt) {
      acc[rt][0] = __builtin_amdgcn_mfma_f32_16x16x32_f16(af[rt], b0, acc[rt][0], 0, 0, 0);
      acc[rt][1] = __builtin_amdgcn_mfma_f32_16x16x32_f16(af[rt], b1, acc[rt][1], 0, 0, 0);
    }
  }
  int col = wave * 32 + l16;
#pragma unroll
  for (int rt = 0; rt < 4; ++rt) {
#pragma unroll
    for (int q = 0; q < 4; ++q) {
      int lr = rt * 16 + quad * 4 + q;
      zl[lr * PSTR + col] = (_Float16)fmaxf(acc[rt][0][q] + bias[col], 0.f);
      zl[lr * PSTR + col + 16] = (_Float16)fmaxf(acc[rt][1][q] + bias[col + 16], 0.f);
    }
  }
  __syncthreads();
  int tid = threadIdx.x;
  if (tid < 128) {
    int lr = tid >> 1, o = tid & 1;
    int row = rowbase + lr;
    if (row < N_NODES) {
      const float* wr = w2s + o * 128;
      float a = 0.f;
#pragma unroll
      for (int k = 0; k < 128; ++k) a += (float)zl[lr * PSTR + k] * wr[k];
      out[(size_t)row * 2 + o] = a + b2[o];
    }
  }
}

// ================================================================ launch
extern "C" void kernel_launch(void* const* d_in, const int* in_sizes, int n_in,
                              void* d_out, int out_size, void* d_ws, size_t ws_size,
                              hipStream_t stream) {
  const int*   x_type  = (const int*)d_in[0];
  const int*   x_tok   = (const int*)d_in[1];
  const float* x_small = (const float*)d_in[2];
  const int*   eidx    = (const int*)d_in[3];
  const int*   etype   = (const int*)d_in[4];
  const float* conv_w  = (const float*)d_in[5];
  const float* gwih    = (const float*)d_in[6];
  const float* gwhh    = (const float*)d_in[7];
  const float* gbih    = (const float*)d_in[8];
  const float* gbhh    = (const float*)d_in[9];
  const float* ln_g    = (const float*)d_in[10];
  const float* ln_b    = (const float*)d_in[11];
  const float* hw1     = (const float*)d_in[12];
  const float* hb1     = (const float*)d_in[13];
  const float* hw2     = (const float*)d_in[14];
  const float* hb2     = (const float*)d_in[15];
  float* out = (float*)d_out;

  const size_t NC = (size_t)N_NODES * 128;
  char* W = (char*)d_ws;
  size_t off = 0;
  _Float16* h16 = (_Float16*)(W + off);     off += NC * 2;            // 12.8 MB
  _Float16* S0  = (_Float16*)(W + off);     off += 3 * NC * 2;        // 38.4 MB
  _Float16* S1  = (_Float16*)(W + off);     off += 3 * NC * 2;        // 38.4 MB
  int* counts = (int*)(W + off);            off += (size_t)NT * 4;
  int* ptrv   = (int*)(W + off);            off += (size_t)(NT + 1) * 4;
  int* fill   = (int*)(W + off);            off += (size_t)NT * 4;
  int* bsum   = (int*)(W + off);            off += (NCHUNK2 + 1) * 4;
  int* boff   = (int*)(W + off);            off += (NCHUNK2 + 1) * 4;
  int* csr    = (int*)(W + off);            off += (size_t)N_EDGES * 4;
  _Float16* WPC = (_Float16*)(W + off);     off += (size_t)18 * FS * 2;
  _Float16* WHH = (_Float16*)(W + off);     off += (size_t)6 * FS * 2;
  _Float16* W1F = (_Float16*)(W + off);     off += (size_t)16384 * 2;

  // ---- per-call prep
  k_features<<<(N_NODES * 128 + 255) / 256, 256, 0, stream>>>(h16, x_type, x_tok, x_small);
  hipMemsetAsync(counts, 0, (size_t)NT * 4, stream);
  k_hist<<<(N_EDGES + 255) / 256, 256, 0, stream>>>(eidx, etype, counts);
  k_scan_a<<<NCHUNK2, 256, 0, stream>>>(counts, bsum);
  k_scan_b<<<1, 256, 0, stream>>>(bsum, boff);
  k_scan_c<<<NCHUNK2, 256, 0, stream>>>(counts, boff, ptrv, fill);
  k_place<<<(N_EDGES + 255) / 256, 256, 0, stream>>>(eidx, etype, fill, csr);
  k_prep_cmb<<<36, 512, 0, stream>>>(conv_w, gwih, WPC);
  k_prep_misc<<<(PREP_B + 16384 + 255) / 256, 256, 0, stream>>>(gwhh, hw1, WHH, W1F);

  // ---- main loop: 2 blocks x 3 steps; fused gather+GRU; ping-pong S0/S1
  for (int b = 0; b < 2; ++b) {
    for (int s = 0; s < 3; ++s) {
      const _Float16* Msrc = (s == 0) ? h16 : ((s == 1) ? S0 : S1);
      size_t mstr = (s == 0) ? 0 : NC;
      _Float16* Sout = (s == 1) ? S1 : S0;
      k_step<<<3 * NB, 512, 0, stream>>>(Msrc, mstr, Sout, ptrv, csr,
          WPC + (size_t)(b * 9 + s) * FS, WHH + (size_t)b * 3 * FS,
          gbih + (size_t)b * 3 * 384, gbhh + (size_t)b * 3 * 384);
    }
    k_ln<<<(N_NODES + 3) / 4, 256, 0, stream>>>(h16, S0, ln_g + b * 128, ln_b + b * 128);
  }
  // ---- fused head
  k_head<<<NB, 256, 0, stream>>>(h16, W1F, hb1, hw2, hb2, out);
}

// Round 10
// 681.662 us; speedup vs baseline: 12.0372x; 1.0623x over previous
//
#include <hip/hip_runtime.h>
#include <cstdint>
#include <cstddef>

// Problem constants (match reference)
#define N_NODES 50000
#define N_EDGES 500000
#define NB 782              // ceil(N_NODES/64) row-blocks
#define NT 150000           // 3 * N_NODES (typed CSR)
#define NCHUNK2 586         // ceil(NT/256) scan chunks
#define FS 49152            // frag halfs per [128x384] matrix (4*24*512)
#define PSTR 136            // LDS row stride in halfs (+8 pad -> bank-spread)
#define MAXOFF 12799744u    // (N_NODES-1)*256 byte-offset clamp
#define ECAP 1024           // LDS csr-slice capacity (mean 213; 4.8x margin)
// C = 128, STEPS = 3, BLOCKS = 2, NUM_ET = 3

typedef _Float16 half8 __attribute__((ext_vector_type(8)));
typedef _Float16 half2v __attribute__((ext_vector_type(2)));
typedef float floatx4 __attribute__((ext_vector_type(4)));

__device__ __forceinline__ float sigmoid_(float x) { return 1.f / (1.f + __expf(-x)); }
__device__ __forceinline__ float tanh_(float x) {
  float t = __expf(-2.f * fabsf(x));
  float r = (1.f - t) / (1.f + t);
  return copysignf(r, x);
}

// ---------------------------------------------------------------- features (fp16 h)
__global__ __launch_bounds__(256) void k_features(_Float16* __restrict__ h,
    const int* __restrict__ xtype, const int* __restrict__ xtok,
    const float* __restrict__ xs) {
  int idx = blockIdx.x * 256 + threadIdx.x;
  if (idx >= N_NODES * 128) return;
  int n = idx >> 7, c = idx & 127;
  float v;
  if (c < 32) {
    v = (xtype[n] == c) ? 1.f : 0.f;
  } else if (c < 126) {
    int tk = xtok[n];
    tk = tk < 0 ? 0 : (tk > 93 ? 93 : tk);
    v = (tk == (c - 32)) ? 1.f : 0.f;
  } else {
    v = xs[n * 2 + (c - 126)];
  }
  h[idx] = (_Float16)v;
}

// ---------------------------------------------------------------- typed-CSR build
__global__ __launch_bounds__(256) void k_hist(const int* __restrict__ ei,
    const int* __restrict__ et, int* __restrict__ counts) {
  int e = blockIdx.x * 256 + threadIdx.x;
  if (e >= N_EDGES) return;
  int d = ei[N_EDGES + e];
  int ty = et[e] & 3;
  if ((unsigned)d < N_NODES && ty < 3) atomicAdd(&counts[ty * N_NODES + d], 1);
}

__global__ __launch_bounds__(256) void k_scan_a(const int* __restrict__ counts,
    int* __restrict__ bsum) {
  int i = blockIdx.x * 256 + threadIdx.x;
  int v = (i < NT) ? counts[i] : 0;
  int lane = threadIdx.x & 63, wv = threadIdx.x >> 6;
#pragma unroll
  for (int off = 32; off > 0; off >>= 1) v += __shfl_xor(v, off);
  __shared__ int ws[4];
  if (lane == 0) ws[wv] = v;
  __syncthreads();
  if (threadIdx.x == 0) bsum[blockIdx.x] = ws[0] + ws[1] + ws[2] + ws[3];
}

__global__ __launch_bounds__(256) void k_scan_b(const int* __restrict__ bsum,
    int* __restrict__ boff) {
  __shared__ int ws[4];
  __shared__ int run_s;
  if (threadIdx.x == 0) run_s = 0;
  __syncthreads();
  int lane = threadIdx.x & 63, wv = threadIdx.x >> 6;
  for (int base = 0; base < NCHUNK2; base += 256) {
    int i = base + threadIdx.x;
    int v = (i < NCHUNK2) ? bsum[i] : 0;
    int s = v;
#pragma unroll
    for (int off = 1; off < 64; off <<= 1) { int u = __shfl_up(s, off); if (lane >= off) s += u; }
    if (lane == 63) ws[wv] = s;
    __syncthreads();
    int woff = 0;
#pragma unroll
    for (int w = 0; w < 4; ++w) woff += (w < wv) ? ws[w] : 0;
    int run = run_s;
    if (i < NCHUNK2) boff[i] = run + woff + s - v;
    __syncthreads();
    if (threadIdx.x == 255) run_s = run + woff + s;
    __syncthreads();
  }
  if (threadIdx.x == 0) boff[NCHUNK2] = run_s;
}

__global__ __launch_bounds__(256) void k_scan_c(const int* __restrict__ counts,
    const int* __restrict__ boff, int* __restrict__ ptr, int* __restrict__ fill) {
  int i = blockIdx.x * 256 + threadIdx.x;
  int v = (i < NT) ? counts[i] : 0;
  int lane = threadIdx.x & 63, wv = threadIdx.x >> 6;
  int s = v;
#pragma unroll
  for (int off = 1; off < 64; off <<= 1) { int u = __shfl_up(s, off); if (lane >= off) s += u; }
  __shared__ int ws[4];
  if (lane == 63) ws[wv] = s;
  __syncthreads();
  int woff = 0;
#pragma unroll
  for (int w = 0; w < 4; ++w) woff += (w < wv) ? ws[w] : 0;
  int excl = boff[blockIdx.x] + woff + s - v;
  if (i < NT) { ptr[i] = excl; fill[i] = excl; }
  if (blockIdx.x == 0 && threadIdx.x == 0) ptr[NT] = boff[NCHUNK2];
}

// csr stores src row as BYTE offset (src*256) -> no shift/mul in gather
__global__ __launch_bounds__(256) void k_place(const int* __restrict__ ei,
    const int* __restrict__ et, int* __restrict__ fill, int* __restrict__ csr) {
  int e = blockIdx.x * 256 + threadIdx.x;
  if (e >= N_EDGES) return;
  int srcv = ei[e], d = ei[N_EDGES + e], ty = et[e] & 3;
  if ((unsigned)d >= N_NODES || (unsigned)srcv >= N_NODES || ty >= 3) return;
  int pos = atomicAdd(&fill[ty * N_NODES + d], 1);
  if ((unsigned)pos < N_EDGES) csr[pos] = srcv << 8;
}

// ---------------------------------------------------------------- weight prep
// B-frag layout (384-col matrices, CT=24):
//   frag[((kc*24+ct)*64 + lane)*8 + j] = W[k = kc*32+(lane>>4)*8+j][n = ct*16+(lane&15)]

// Wcomb[mat] = conv_w[mat] @ wih[bt].T via MFMA, written directly in frag layout.
__global__ __launch_bounds__(512) void k_prep_cmb(const float* __restrict__ cw,
    const float* __restrict__ wih, _Float16* __restrict__ dst) {
  int mat = blockIdx.x >> 1, half = blockIdx.x & 1;
  int bt = mat / 3;
  int u = threadIdx.x >> 6, lane = threadIdx.x & 63;
  int quad = lane >> 4, l16 = lane & 15;
  floatx4 zero = {0.f, 0.f, 0.f, 0.f};
  floatx4 acc[4][3];
#pragma unroll
  for (int rt = 0; rt < 4; ++rt)
#pragma unroll
    for (int cc = 0; cc < 3; ++cc) acc[rt][cc] = zero;
#pragma unroll
  for (int jc = 0; jc < 4; ++jc) {
    half8 af[4], bf[3];
#pragma unroll
    for (int rt = 0; rt < 4; ++rt) {
      int m = half * 64 + rt * 16 + l16;
      const float* ap = cw + ((size_t)mat * 128 + m) * 128 + jc * 32 + quad * 8;
      floatx4 a0 = *(const floatx4*)ap;
      floatx4 a1 = *(const floatx4*)(ap + 4);
#pragma unroll
      for (int i = 0; i < 4; ++i) { af[rt][i] = (_Float16)a0[i]; af[rt][4 + i] = (_Float16)a1[i]; }
    }
#pragma unroll
    for (int cc = 0; cc < 3; ++cc) {
      int n = (u * 3 + cc) * 16 + l16;
      const float* bp = wih + ((size_t)bt * 384 + n) * 128 + jc * 32 + quad * 8;
      floatx4 b0 = *(const floatx4*)bp;
      floatx4 b1 = *(const floatx4*)(bp + 4);
#pragma unroll
      for (int i = 0; i < 4; ++i) { bf[cc][i] = (_Float16)b0[i]; bf[cc][4 + i] = (_Float16)b1[i]; }
    }
#pragma unroll
    for (int rt = 0; rt < 4; ++rt)
#pragma unroll
      for (int cc = 0; cc < 3; ++cc)
        acc[rt][cc] = __builtin_amdgcn_mfma_f32_16x16x32_f16(af[rt], bf[cc], acc[rt][cc], 0, 0, 0);
  }
#pragma unroll
  for (int rt = 0; rt < 4; ++rt) {
#pragma unroll
    for (int cc = 0; cc < 3; ++cc) {
      int ctg = u * 3 + cc;
#pragma unroll
      for (int q = 0; q < 4; ++q) {
        int k = half * 64 + rt * 16 + quad * 4 + q;
        int kc2 = k >> 5, r5 = k & 31;
        int lane2 = (r5 >> 3) * 16 + l16, j2 = r5 & 7;
        dst[(size_t)mat * FS + (size_t)((kc2 * 24 + ctg) * 64 + lane2) * 8 + j2] =
            (_Float16)acc[rt][cc][q];
      }
    }
  }
}

// whh frags (6 mats) + w1 frag — pure elementwise convert/permute.
#define PREP_B (6 * 4 * 24 * 512)
__global__ __launch_bounds__(256) void k_prep_misc(const float* __restrict__ whh,
    const float* __restrict__ hw1, _Float16* __restrict__ dwhh,
    _Float16* __restrict__ dw1) {
  int idx0 = blockIdx.x * 256 + threadIdx.x;
  if (idx0 < PREP_B) {
    int idx = idx0;
    int j = idx & 7, lane = (idx >> 3) & 63;
    int r = idx >> 9;
    int ct = r % 24;
    int r2 = r / 24;
    int kc = r2 & 3, bt = r2 >> 2;
    int k = kc * 32 + ((lane >> 4) & 3) * 8 + j;
    int n = ct * 16 + (lane & 15);
    dwhh[idx] = (_Float16)whh[((size_t)bt * 384 + n) * 128 + k];
  } else if (idx0 < PREP_B + 16384) {
    int idx = idx0 - PREP_B;
    int j = idx & 7, lane = (idx >> 3) & 63, ct = (idx >> 9) & 7, kc = (idx >> 12) & 3;
    int k = kc * 32 + ((lane >> 4) & 3) * 8 + j;
    int n = ct * 16 + (lane & 15);
    dw1[idx] = (_Float16)hw1[n * 128 + k];
  }
}

// ---------------------------------------------------------------- fused gather + GRU step
// Block = 512 thr (8 waves), one (type, 64-row) tile.
// bse/cnt via scalar loads; ptr slice pre-relativized+clamped; csr slice
// staged with offsets clamped at stage time -> lean gather loop (LDS offset +
// saddr-form load + 4 pk_adds). Epilogue: results staged in Plds (dead after
// gi-loop), then 2 coalesced dwordx4 stores/thread.
__global__ __launch_bounds__(512, 4) void k_step(
    const _Float16* __restrict__ Mbase, const size_t mstride,
    _Float16* __restrict__ Sout,
    const int* __restrict__ ptr, const int* __restrict__ csr,
    const _Float16* __restrict__ WPC, const _Float16* __restrict__ WHH,
    const float* __restrict__ bi2, const float* __restrict__ bh2) {
  __shared__ __attribute__((aligned(16))) _Float16 Plds[64 * PSTR];
  __shared__ __attribute__((aligned(16))) _Float16 Mlds[64 * PSTR];
  __shared__ int Elds[ECAP];
  __shared__ int Pt[65];
  int bid = blockIdx.x;
  int t = bid / NB, blk = bid - t * NB;
  int tid = threadIdx.x;
  int wave = tid >> 6, lane = tid & 63;
  int quad = lane >> 4, l16 = lane & 15;
  int rowbase = blk * 64;
  const size_t NC = (size_t)N_NODES * 128;
  const _Float16* Mp = Mbase + mstride * t;
  const char* Mb = (const char*)Mp;
  _Float16* Sp = Sout + (size_t)t * NC;
  const int* ptrT = ptr + t * N_NODES;

  // ---- block-uniform bse/cnt (s_load path)
  int rb64 = rowbase + 64; if (rb64 > N_NODES) rb64 = N_NODES;
  int bse = ptrT[rowbase];
  int cend = ptrT[rb64];
  if (bse < 0) bse = 0; if (bse > N_EDGES) bse = N_EDGES;          // replay safety
  if (cend < bse) cend = bse; if (cend > N_EDGES) cend = N_EDGES;
  int cnt = cend - bse; if (cnt > ECAP) cnt = ECAP;

  // ---- stage ptr slice (relative, clamped -> gather needs no checks)
  if (tid < 65) {
    int n = rowbase + tid; if (n > N_NODES) n = N_NODES;
    int v = ptrT[n] - bse;
    if (v < 0) v = 0; if (v > cnt) v = cnt;
    Pt[tid] = v;
  }
  // ---- stage M block rows (64 x 128 fp16), coalesced
#pragma unroll
  for (int it = 0; it < 2; ++it) {
    int r = it * 32 + (tid >> 4);
    int c = (tid & 15) * 8;
    int gr = rowbase + r; if (gr >= N_NODES) gr = N_NODES - 1;
    half8 v = *(const half8*)(Mp + (size_t)gr * 128 + c);
    *(half8*)(&Mlds[r * PSTR + c]) = v;
  }
  // ---- stage csr slice, offsets clamped here (out of the hot loop)
  for (int i = tid; i < cnt; i += 512) {
    unsigned off = (unsigned)csr[bse + i];
    if (off > MAXOFF) off = 0;
    Elds[i] = (int)off;
  }
  __syncthreads();

  // ---- gather: group g owns rows nlA = wave*8+g, nlB = nlA+4 concurrently
  int g = quad;
  unsigned coff = (unsigned)(l16 * 16);  // byte offset within row
  int nlA = wave * 8 + g, nlB = nlA + 4;
  int iA = Pt[nlA], eA = Pt[nlA + 1];
  int iB = Pt[nlB], eB = Pt[nlB + 1];
  half8 accA = {}, accB = {};
  while (__any(iA < eA || iB < eB)) {
#pragma unroll
    for (int uu = 0; uu < 4; ++uu) {
      if (iA + uu < eA) {
        unsigned o = (unsigned)Elds[iA + uu] + coff;
        accA += *(const half8*)(Mb + o);
      }
      if (iB + uu < eB) {
        unsigned o = (unsigned)Elds[iB + uu] + coff;
        accB += *(const half8*)(Mb + o);
      }
    }
    iA += 4; iB += 4;
  }
  *(half8*)(&Plds[nlA * PSTR + l16 * 8]) = accA;
  *(half8*)(&Plds[nlB * PSTR + l16 * 8]) = accB;
  __syncthreads();

  // ---- MFMA GRU. u = wave owns cts {u (r), 8+u (z), 16+u (n)}.
  const half8* wpc = (const half8*)(WPC + (size_t)t * 3 * FS);
  const half8* whh = (const half8*)(WHH + (size_t)t * FS);
  const float* bi = bi2 + (size_t)t * 384;
  const float* bh = bh2 + (size_t)t * 384;
  int u = wave;
  floatx4 zero = {0.f, 0.f, 0.f, 0.f};
  floatx4 aR[4], aZ[4], aNP[4], aNM[4];
#pragma unroll
  for (int rt = 0; rt < 4; ++rt) { aR[rt] = zero; aZ[rt] = zero; aNP[rt] = zero; aNM[rt] = zero; }
#pragma unroll
  for (int kc = 0; kc < 4; ++kc) {   // gi part: P @ Wcomb
    half8 af[4];
#pragma unroll
    for (int rt = 0; rt < 4; ++rt)
      af[rt] = *(const half8*)(&Plds[(rt * 16 + l16) * PSTR + kc * 32 + quad * 8]);
    half8 br = wpc[(kc * 24 + u) * 64 + lane];
    half8 bz = wpc[(kc * 24 + 8 + u) * 64 + lane];
    half8 bn = wpc[(kc * 24 + 16 + u) * 64 + lane];
#pragma unroll
    for (int rt = 0; rt < 4; ++rt) {
      aR[rt] = __builtin_amdgcn_mfma_f32_16x16x32_f16(af[rt], br, aR[rt], 0, 0, 0);
      aZ[rt] = __builtin_amdgcn_mfma_f32_16x16x32_f16(af[rt], bz, aZ[rt], 0, 0, 0);
      aNP[rt] = __builtin_amdgcn_mfma_f32_16x16x32_f16(af[rt], bn, aNP[rt], 0, 0, 0);
    }
  }
#pragma unroll
  for (int kc = 0; kc < 4; ++kc) {   // gh part: M @ whh.T
    half8 af[4];
#pragma unroll
    for (int rt = 0; rt < 4; ++rt)
      af[rt] = *(const half8*)(&Mlds[(rt * 16 + l16) * PSTR + kc * 32 + quad * 8]);
    half8 br = whh[(kc * 24 + u) * 64 + lane];
    half8 bz = whh[(kc * 24 + 8 + u) * 64 + lane];
    half8 bn = whh[(kc * 24 + 16 + u) * 64 + lane];
#pragma unroll
    for (int rt = 0; rt < 4; ++rt) {
      aR[rt] = __builtin_amdgcn_mfma_f32_16x16x32_f16(af[rt], br, aR[rt], 0, 0, 0);
      aZ[rt] = __builtin_amdgcn_mfma_f32_16x16x32_f16(af[rt], bz, aZ[rt], 0, 0, 0);
      aNM[rt] = __builtin_amdgcn_mfma_f32_16x16x32_f16(af[rt], bn, aNM[rt], 0, 0, 0);
    }
  }
  // ---- epilogue: compute into Plds (dead), then coalesced store-out
  __syncthreads();   // all waves past gi-loop -> Plds safe to overwrite
  int col = u * 16 + l16;
  float br_ = bi[col] + bh[col];
  float bz_ = bi[128 + col] + bh[128 + col];
  float bin = bi[256 + col], bhn = bh[256 + col];
#pragma unroll
  for (int rt = 0; rt < 4; ++rt) {
#pragma unroll
    for (int q = 0; q < 4; ++q) {
      int lr = rt * 16 + quad * 4 + q;
      float r = sigmoid_(aR[rt][q] + br_);
      float z = sigmoid_(aZ[rt][q] + bz_);
      float nt = tanh_(aNP[rt][q] + bin + r * (aNM[rt][q] + bhn));
      float hold = (float)Mlds[lr * PSTR + col];
      Plds[lr * PSTR + col] = (_Float16)((1.f - z) * nt + z * hold);
    }
  }
  __syncthreads();
#pragma unroll
  for (int it = 0; it < 2; ++it) {
    int r = it * 32 + (tid >> 4);
    int c = (tid & 15) * 8;
    int row = rowbase + r;
    if (row < N_NODES)
      *(half8*)(Sp + (size_t)row * 128 + c) = *(const half8*)(&Plds[r * PSTR + c]);
  }
}

// ---------------------------------------------------------------- LayerNorm(h + S0+S1+S2) + ReLU -> h (fp16)
__global__ __launch_bounds__(256) void k_ln(_Float16* __restrict__ h,
    const _Float16* __restrict__ S, const float* __restrict__ gamma,
    const float* __restrict__ beta) {
  int wave = threadIdx.x >> 6, lane = threadIdx.x & 63;
  int n = blockIdx.x * 4 + wave;
  if (n >= N_NODES) return;
  const size_t NC = (size_t)N_NODES * 128;
  size_t base = (size_t)n * 128 + lane * 2;
  half2v hv = *(const half2v*)(h + base);
  half2v s0 = *(const half2v*)(S + base);
  half2v s1 = *(const half2v*)(S + NC + base);
  half2v s2 = *(const half2v*)(S + 2 * NC + base);
  float v0 = (float)hv[0] + (float)s0[0] + (float)s1[0] + (float)s2[0];
  float v1 = (float)hv[1] + (float)s0[1] + (float)s1[1] + (float)s2[1];
  float s = v0 + v1, sq = v0 * v0 + v1 * v1;
#pragma unroll
  for (int off = 32; off > 0; off >>= 1) {
    s += __shfl_xor(s, off);
    sq += __shfl_xor(sq, off);
  }
  float mu = s * 0.0078125f;
  float var = sq * 0.0078125f - mu * mu;
  float rs = rsqrtf(var + 1e-5f);
  float o0 = (v0 - mu) * rs * gamma[lane * 2] + beta[lane * 2];
  float o1 = (v1 - mu) * rs * gamma[lane * 2 + 1] + beta[lane * 2 + 1];
  half2v ov; ov[0] = (_Float16)fmaxf(o0, 0.f); ov[1] = (_Float16)fmaxf(o1, 0.f);
  *(half2v*)(h + base) = ov;
}

// ---------------------------------------------------------------- fused head: out = relu(h@w1.T+b1) @ w2.T + b2
__global__ __launch_bounds__(256, 4) void k_head(const _Float16* __restrict__ A,
    const _Float16* __restrict__ Wf, const float* __restrict__ bias,
    const float* __restrict__ w2, const float* __restrict__ b2,
    float* __restrict__ out) {
  __shared__ __attribute__((aligned(16))) _Float16 zl[64 * PSTR];
  __shared__ float w2s[256];
  int blk = blockIdx.x;
  int wave = threadIdx.x >> 6, lane = threadIdx.x & 63;
  int quad = lane >> 4, l16 = lane & 15;
  int rowbase = blk * 64;
  if (threadIdx.x < 256) w2s[threadIdx.x] = w2[threadIdx.x];
  const half8* wf = (const half8*)Wf;
  int ar[4];
#pragma unroll
  for (int rt = 0; rt < 4; ++rt) {
    int r = rowbase + rt * 16 + l16;
    ar[rt] = r < N_NODES ? r : N_NODES - 1;
  }
  floatx4 zero = {0.f, 0.f, 0.f, 0.f};
  floatx4 acc[4][2];
#pragma unroll
  for (int rt = 0; rt < 4; ++rt) { acc[rt][0] = zero; acc[rt][1] = zero; }
#pragma unroll
  for (int kc = 0; kc < 4; ++kc) {
    half8 af[4];
#pragma unroll
    for (int rt = 0; rt < 4; ++rt)
      af[rt] = *(const half8*)(A + (size_t)ar[rt] * 128 + kc * 32 + quad * 8);
    half8 b0 = wf[(kc * 8 + 2 * wave) * 64 + lane];
    half8 b1 = wf[(kc * 8 + 2 * wave + 1) * 64 + lane];
#pragma unroll
    for (int rt = 0; rt < 4; ++rt) {
      acc[rt][0] = __builtin_amdgcn_mfma_f32_16x16x32_f16(af[rt], b0, acc[rt][0], 0, 0, 0);
      acc[rt][1] = __builtin_amdgcn_mfma_f32_16x16x32_f16(af[rt], b1, acc[rt][1], 0, 0, 0);
    }
  }
  int col = wave * 32 + l16;
#pragma unroll
  for (int rt = 0; rt < 4; ++rt) {
#pragma unroll
    for (int q = 0; q < 4; ++q) {
      int lr = rt * 16 + quad * 4 + q;
      zl[lr * PSTR + col] = (_Float16)fmaxf(acc[rt][0][q] + bias[col], 0.f);
      zl[lr * PSTR + col + 16] = (_Float16)fmaxf(acc[rt][1][q] + bias[col + 16], 0.f);
    }
  }
  __syncthreads();
  int tid = threadIdx.x;
  if (tid < 128) {
    int lr = tid >> 1, o = tid & 1;
    int row = rowbase + lr;
    if (row < N_NODES) {
      const float* wr = w2s + o * 128;
      float a = 0.f;
#pragma unroll
      for (int k = 0; k < 128; ++k) a += (float)zl[lr * PSTR + k] * wr[k];
      out[(size_t)row * 2 + o] = a + b2[o];
    }
  }
}

// ================================================================ launch
extern "C" void kernel_launch(void* const* d_in, const int* in_sizes, int n_in,
                              void* d_out, int out_size, void* d_ws, size_t ws_size,
                              hipStream_t stream) {
  const int*   x_type  = (const int*)d_in[0];
  const int*   x_tok   = (const int*)d_in[1];
  const float* x_small = (const float*)d_in[2];
  const int*   eidx    = (const int*)d_in[3];
  const int*   etype   = (const int*)d_in[4];
  const float* conv_w  = (const float*)d_in[5];
  const float* gwih    = (const float*)d_in[6];
  const float* gwhh    = (const float*)d_in[7];
  const float* gbih    = (const float*)d_in[8];
  const float* gbhh    = (const float*)d_in[9];
  const float* ln_g    = (const float*)d_in[10];
  const float* ln_b    = (const float*)d_in[11];
  const float* hw1     = (const float*)d_in[12];
  const float* hb1     = (const float*)d_in[13];
  const float* hw2     = (const float*)d_in[14];
  const float* hb2     = (const float*)d_in[15];
  float* out = (float*)d_out;

  const size_t NC = (size_t)N_NODES * 128;
  char* W = (char*)d_ws;
  size_t off = 0;
  _Float16* h16 = (_Float16*)(W + off);     off += NC * 2;            // 12.8 MB
  _Float16* S0  = (_Float16*)(W + off);     off += 3 * NC * 2;        // 38.4 MB
  _Float16* S1  = (_Float16*)(W + off);     off += 3 * NC * 2;        // 38.4 MB
  int* counts = (int*)(W + off);            off += (size_t)NT * 4;
  int* ptrv   = (int*)(W + off);            off += (size_t)(NT + 1) * 4;
  int* fill   = (int*)(W + off);            off += (size_t)NT * 4;
  int* bsum   = (int*)(W + off);            off += (NCHUNK2 + 1) * 4;
  int* boff   = (int*)(W + off);            off += (NCHUNK2 + 1) * 4;
  int* csr    = (int*)(W + off);            off += (size_t)N_EDGES * 4;
  _Float16* WPC = (_Float16*)(W + off);     off += (size_t)18 * FS * 2;
  _Float16* WHH = (_Float16*)(W + off);     off += (size_t)6 * FS * 2;
  _Float16* W1F = (_Float16*)(W + off);     off += (size_t)16384 * 2;

  // ---- per-call prep
  k_features<<<(N_NODES * 128 + 255) / 256, 256, 0, stream>>>(h16, x_type, x_tok, x_small);
  hipMemsetAsync(counts, 0, (size_t)NT * 4, stream);
  k_hist<<<(N_EDGES + 255) / 256, 256, 0, stream>>>(eidx, etype, counts);
  k_scan_a<<<NCHUNK2, 256, 0, stream>>>(counts, bsum);
  k_scan_b<<<1, 256, 0, stream>>>(bsum, boff);
  k_scan_c<<<NCHUNK2, 256, 0, stream>>>(counts, boff, ptrv, fill);
  k_place<<<(N_EDGES + 255) / 256, 256, 0, stream>>>(eidx, etype, fill, csr);
  k_prep_cmb<<<36, 512, 0, stream>>>(conv_w, gwih, WPC);
  k_prep_misc<<<(PREP_B + 16384 + 255) / 256, 256, 0, stream>>>(gwhh, hw1, WHH, W1F);

  // ---- main loop: 2 blocks x 3 steps; fused gather+GRU; ping-pong S0/S1
  for (int b = 0; b < 2; ++b) {
    for (int s = 0; s < 3; ++s) {
      const _Float16* Msrc = (s == 0) ? h16 : ((s == 1) ? S0 : S1);
      size_t mstr = (s == 0) ? 0 : NC;
      _Float16* Sout = (s == 1) ? S1 : S0;
      k_step<<<3 * NB, 512, 0, stream>>>(Msrc, mstr, Sout, ptrv, csr,
          WPC + (size_t)(b * 9 + s) * FS, WHH + (size_t)b * 3 * FS,
          gbih + (size_t)b * 3 * 384, gbhh + (size_t)b * 3 * 384);
    }
    k_ln<<<(N_NODES + 3) / 4, 256, 0, stream>>>(h16, S0, ln_g + b * 128, ln_b + b * 128);
  }
  // ---- fused head
  k_head<<<NB, 256, 0, stream>>>(h16, W1F, hb1, hw2, hb2, out);
}

// Round 11
// 670.637 us; speedup vs baseline: 12.2350x; 1.0164x over previous
//
#include <hip/hip_runtime.h>
#include <cstdint>
#include <cstddef>

// Problem constants (match reference)
#define N_NODES 50000
#define N_EDGES 500000
#define NB 782              // ceil(N_NODES/64) row-blocks
#define NT 150000           // 3 * N_NODES (typed CSR)
#define NCHUNK2 586         // ceil(NT/256) scan chunks
#define FS 49152            // frag halfs per [128x384] matrix (4*24*512)
#define PSTR 136            // LDS row stride in halfs (+8 pad -> bank-spread)
#define MAXOFF 12799744u    // (N_NODES-1)*256 byte-offset clamp
#define ECAP 1024           // LDS csr-slice capacity (mean 213; 4.8x margin)
// C = 128, STEPS = 3, BLOCKS = 2, NUM_ET = 3

typedef _Float16 half8 __attribute__((ext_vector_type(8)));
typedef _Float16 half2v __attribute__((ext_vector_type(2)));
typedef float floatx4 __attribute__((ext_vector_type(4)));

__device__ __forceinline__ float sigmoid_(float x) { return 1.f / (1.f + __expf(-x)); }
__device__ __forceinline__ float tanh_(float x) {
  float t = __expf(-2.f * fabsf(x));
  float r = (1.f - t) / (1.f + t);
  return copysignf(r, x);
}

// ---------------------------------------------------------------- features + edge histogram (merged)
__global__ __launch_bounds__(256) void k_feat_hist(_Float16* __restrict__ h,
    const int* __restrict__ xtype, const int* __restrict__ xtok,
    const float* __restrict__ xs, const int* __restrict__ ei,
    const int* __restrict__ et, int* __restrict__ counts) {
  int idx = blockIdx.x * 256 + threadIdx.x;
  if (idx < N_NODES * 128) {
    int n = idx >> 7, c = idx & 127;
    float v;
    if (c < 32) {
      v = (xtype[n] == c) ? 1.f : 0.f;
    } else if (c < 126) {
      int tk = xtok[n];
      tk = tk < 0 ? 0 : (tk > 93 ? 93 : tk);
      v = (tk == (c - 32)) ? 1.f : 0.f;
    } else {
      v = xs[n * 2 + (c - 126)];
    }
    h[idx] = (_Float16)v;
  }
  if (idx < N_EDGES) {
    int d = ei[N_EDGES + idx];
    int ty = et[idx] & 3;
    if ((unsigned)d < N_NODES && ty < 3) atomicAdd(&counts[ty * N_NODES + d], 1);
  }
}

// ---------------------------------------------------------------- scan phase A: per-chunk sums
__global__ __launch_bounds__(256) void k_scan_a(const int* __restrict__ counts,
    int* __restrict__ bsum) {
  int i = blockIdx.x * 256 + threadIdx.x;
  int v = (i < NT) ? counts[i] : 0;
  int lane = threadIdx.x & 63, wv = threadIdx.x >> 6;
#pragma unroll
  for (int off = 32; off > 0; off >>= 1) v += __shfl_xor(v, off);
  __shared__ int ws[4];
  if (lane == 0) ws[wv] = v;
  __syncthreads();
  if (threadIdx.x == 0) bsum[blockIdx.x] = ws[0] + ws[1] + ws[2] + ws[3];
}

// ---------------------------------------------------------------- scan phase C: block computes own
// boffset from bsum (redundant per-block prefix; kills the middle kernel), then element scan.
__global__ __launch_bounds__(256) void k_scan_c(const int* __restrict__ counts,
    const int* __restrict__ bsum, int* __restrict__ ptr, int* __restrict__ fill) {
  __shared__ int wsum2[4];
  __shared__ int ws[4];
  int lane = threadIdx.x & 63, wv = threadIdx.x >> 6;
  // boffset = sum of bsum[j < blockIdx]
  int acc = 0;
  for (int j = threadIdx.x; j < blockIdx.x; j += 256) acc += bsum[j];
#pragma unroll
  for (int off = 32; off > 0; off >>= 1) acc += __shfl_xor(acc, off);
  if (lane == 0) wsum2[wv] = acc;
  __syncthreads();
  int boffset = wsum2[0] + wsum2[1] + wsum2[2] + wsum2[3];
  // element scan
  int i = blockIdx.x * 256 + threadIdx.x;
  int v = (i < NT) ? counts[i] : 0;
  int s = v;
#pragma unroll
  for (int off = 1; off < 64; off <<= 1) { int u = __shfl_up(s, off); if (lane >= off) s += u; }
  if (lane == 63) ws[wv] = s;
  __syncthreads();
  int woff = 0;
#pragma unroll
  for (int w = 0; w < 4; ++w) woff += (w < wv) ? ws[w] : 0;
  int excl = boffset + woff + s - v;
  if (i < NT) { ptr[i] = excl; fill[i] = excl; }
  if (blockIdx.x == NCHUNK2 - 1 && threadIdx.x == 0)
    ptr[NT] = boffset + bsum[NCHUNK2 - 1];
}

// csr stores src row as BYTE offset (src*256) -> no shift/mul in gather
__global__ __launch_bounds__(256) void k_place(const int* __restrict__ ei,
    const int* __restrict__ et, int* __restrict__ fill, int* __restrict__ csr) {
  int e = blockIdx.x * 256 + threadIdx.x;
  if (e >= N_EDGES) return;
  int srcv = ei[e], d = ei[N_EDGES + e], ty = et[e] & 3;
  if ((unsigned)d >= N_NODES || (unsigned)srcv >= N_NODES || ty >= 3) return;
  int pos = atomicAdd(&fill[ty * N_NODES + d], 1);
  if ((unsigned)pos < N_EDGES) csr[pos] = srcv << 8;
}

// ---------------------------------------------------------------- merged weight prep
// Blocks 0..35: Wcomb[mat] = conv_w[mat] @ wih[bt].T via MFMA into frag layout.
// Blocks 36+: whh frags (6 mats) + w1 frag, elementwise permute/convert.
#define PREP_B (6 * 4 * 24 * 512)
#define PREP_MISC_BLOCKS ((PREP_B + 16384 + 511) / 512)
__global__ __launch_bounds__(512) void k_prep(const float* __restrict__ cw,
    const float* __restrict__ wih, const float* __restrict__ whh,
    const float* __restrict__ hw1, _Float16* __restrict__ dcomb,
    _Float16* __restrict__ dwhh, _Float16* __restrict__ dw1) {
  if (blockIdx.x < 36) {
    int mat = blockIdx.x >> 1, half = blockIdx.x & 1;
    int bt = mat / 3;
    int u = threadIdx.x >> 6, lane = threadIdx.x & 63;
    int quad = lane >> 4, l16 = lane & 15;
    floatx4 zero = {0.f, 0.f, 0.f, 0.f};
    floatx4 acc[4][3];
#pragma unroll
    for (int rt = 0; rt < 4; ++rt)
#pragma unroll
      for (int cc = 0; cc < 3; ++cc) acc[rt][cc] = zero;
#pragma unroll
    for (int jc = 0; jc < 4; ++jc) {
      half8 af[4], bf[3];
#pragma unroll
      for (int rt = 0; rt < 4; ++rt) {
        int m = half * 64 + rt * 16 + l16;
        const float* ap = cw + ((size_t)mat * 128 + m) * 128 + jc * 32 + quad * 8;
        floatx4 a0 = *(const floatx4*)ap;
        floatx4 a1 = *(const floatx4*)(ap + 4);
#pragma unroll
        for (int i = 0; i < 4; ++i) { af[rt][i] = (_Float16)a0[i]; af[rt][4 + i] = (_Float16)a1[i]; }
      }
#pragma unroll
      for (int cc = 0; cc < 3; ++cc) {
        int n = (u * 3 + cc) * 16 + l16;
        const float* bp = wih + ((size_t)bt * 384 + n) * 128 + jc * 32 + quad * 8;
        floatx4 b0 = *(const floatx4*)bp;
        floatx4 b1 = *(const floatx4*)(bp + 4);
#pragma unroll
        for (int i = 0; i < 4; ++i) { bf[cc][i] = (_Float16)b0[i]; bf[cc][4 + i] = (_Float16)b1[i]; }
      }
#pragma unroll
      for (int rt = 0; rt < 4; ++rt)
#pragma unroll
        for (int cc = 0; cc < 3; ++cc)
          acc[rt][cc] = __builtin_amdgcn_mfma_f32_16x16x32_f16(af[rt], bf[cc], acc[rt][cc], 0, 0, 0);
    }
#pragma unroll
    for (int rt = 0; rt < 4; ++rt) {
#pragma unroll
      for (int cc = 0; cc < 3; ++cc) {
        int ctg = u * 3 + cc;
#pragma unroll
        for (int q = 0; q < 4; ++q) {
          int k = half * 64 + rt * 16 + quad * 4 + q;
          int kc2 = k >> 5, r5 = k & 31;
          int lane2 = (r5 >> 3) * 16 + l16, j2 = r5 & 7;
          dcomb[(size_t)mat * FS + (size_t)((kc2 * 24 + ctg) * 64 + lane2) * 8 + j2] =
              (_Float16)acc[rt][cc][q];
        }
      }
    }
  } else {
    int idx0 = (blockIdx.x - 36) * 512 + threadIdx.x;
    if (idx0 < PREP_B) {
      int idx = idx0;
      int j = idx & 7, lane = (idx >> 3) & 63;
      int r = idx >> 9;
      int ct = r % 24;
      int r2 = r / 24;
      int kc = r2 & 3, bt = r2 >> 2;
      int k = kc * 32 + ((lane >> 4) & 3) * 8 + j;
      int n = ct * 16 + (lane & 15);
      dwhh[idx] = (_Float16)whh[((size_t)bt * 384 + n) * 128 + k];
    } else if (idx0 < PREP_B + 16384) {
      int idx = idx0 - PREP_B;
      int j = idx & 7, lane = (idx >> 3) & 63, ct = (idx >> 9) & 7, kc = (idx >> 12) & 3;
      int k = kc * 32 + ((lane >> 4) & 3) * 8 + j;
      int n = ct * 16 + (lane & 15);
      dw1[idx] = (_Float16)hw1[n * 128 + k];
    }
  }
}

// ---------------------------------------------------------------- fused gather + GRU step
__global__ __launch_bounds__(512, 4) void k_step(
    const _Float16* __restrict__ Mbase, const size_t mstride,
    _Float16* __restrict__ Sout,
    const int* __restrict__ ptr, const int* __restrict__ csr,
    const _Float16* __restrict__ WPC, const _Float16* __restrict__ WHH,
    const float* __restrict__ bi2, const float* __restrict__ bh2) {
  __shared__ __attribute__((aligned(16))) _Float16 Plds[64 * PSTR];
  __shared__ __attribute__((aligned(16))) _Float16 Mlds[64 * PSTR];
  __shared__ int Elds[ECAP];
  __shared__ int Pt[65];
  int bid = blockIdx.x;
  int t = bid / NB, blk = bid - t * NB;
  int tid = threadIdx.x;
  int wave = tid >> 6, lane = tid & 63;
  int quad = lane >> 4, l16 = lane & 15;
  int rowbase = blk * 64;
  const size_t NC = (size_t)N_NODES * 128;
  const _Float16* Mp = Mbase + mstride * t;
  const char* Mb = (const char*)Mp;
  _Float16* Sp = Sout + (size_t)t * NC;
  const int* ptrT = ptr + t * N_NODES;

  // ---- block-uniform bse/cnt (s_load path)
  int rb64 = rowbase + 64; if (rb64 > N_NODES) rb64 = N_NODES;
  int bse = ptrT[rowbase];
  int cend = ptrT[rb64];
  if (bse < 0) bse = 0; if (bse > N_EDGES) bse = N_EDGES;          // replay safety
  if (cend < bse) cend = bse; if (cend > N_EDGES) cend = N_EDGES;
  int cnt = cend - bse; if (cnt > ECAP) cnt = ECAP;

  // ---- stage ptr slice (relative, clamped)
  if (tid < 65) {
    int n = rowbase + tid; if (n > N_NODES) n = N_NODES;
    int v = ptrT[n] - bse;
    if (v < 0) v = 0; if (v > cnt) v = cnt;
    Pt[tid] = v;
  }
  // ---- stage M block rows (64 x 128 fp16), coalesced
#pragma unroll
  for (int it = 0; it < 2; ++it) {
    int r = it * 32 + (tid >> 4);
    int c = (tid & 15) * 8;
    int gr = rowbase + r; if (gr >= N_NODES) gr = N_NODES - 1;
    half8 v = *(const half8*)(Mp + (size_t)gr * 128 + c);
    *(half8*)(&Mlds[r * PSTR + c]) = v;
  }
  // ---- stage csr slice, offsets clamped here
  for (int i = tid; i < cnt; i += 512) {
    unsigned off = (unsigned)csr[bse + i];
    if (off > MAXOFF) off = 0;
    Elds[i] = (int)off;
  }
  __syncthreads();

  // ---- gather: group g owns rows nlA = wave*8+g, nlB = nlA+4; counted loop
  int g = quad;
  unsigned coff = (unsigned)(l16 * 16);
  int nlA = wave * 8 + g, nlB = nlA + 4;
  int iA = Pt[nlA], eA = Pt[nlA + 1];
  int iB = Pt[nlB], eB = Pt[nlB + 1];
  int need = eA - iA;
  int nb = eB - iB; if (nb > need) need = nb;
  int m1 = __shfl_xor(need, 16); if (m1 > need) need = m1;
  int m2 = __shfl_xor(need, 32); if (m2 > need) need = m2;
  int trips = (need + 3) >> 2;
  half8 accA = {}, accB = {};
  for (int it = 0; it < trips; ++it) {
#pragma unroll
    for (int uu = 0; uu < 4; ++uu) {
      if (iA + uu < eA) {
        unsigned o = (unsigned)Elds[iA + uu] + coff;
        accA += *(const half8*)(Mb + o);
      }
      if (iB + uu < eB) {
        unsigned o = (unsigned)Elds[iB + uu] + coff;
        accB += *(const half8*)(Mb + o);
      }
    }
    iA += 4; iB += 4;
  }
  *(half8*)(&Plds[nlA * PSTR + l16 * 8]) = accA;
  *(half8*)(&Plds[nlB * PSTR + l16 * 8]) = accB;
  __syncthreads();

  // ---- MFMA GRU. u = wave owns cts {u (r), 8+u (z), 16+u (n)}.
  const half8* wpc = (const half8*)(WPC + (size_t)t * 3 * FS);
  const half8* whh = (const half8*)(WHH + (size_t)t * FS);
  const float* bi = bi2 + (size_t)t * 384;
  const float* bh = bh2 + (size_t)t * 384;
  int u = wave;
  floatx4 zero = {0.f, 0.f, 0.f, 0.f};
  floatx4 aR[4], aZ[4], aNP[4], aNM[4];
#pragma unroll
  for (int rt = 0; rt < 4; ++rt) { aR[rt] = zero; aZ[rt] = zero; aNP[rt] = zero; aNM[rt] = zero; }
#pragma unroll
  for (int kc = 0; kc < 4; ++kc) {   // gi part: P @ Wcomb
    half8 af[4];
#pragma unroll
    for (int rt = 0; rt < 4; ++rt)
      af[rt] = *(const half8*)(&Plds[(rt * 16 + l16) * PSTR + kc * 32 + quad * 8]);
    half8 br = wpc[(kc * 24 + u) * 64 + lane];
    half8 bz = wpc[(kc * 24 + 8 + u) * 64 + lane];
    half8 bn = wpc[(kc * 24 + 16 + u) * 64 + lane];
#pragma unroll
    for (int rt = 0; rt < 4; ++rt) {
      aR[rt] = __builtin_amdgcn_mfma_f32_16x16x32_f16(af[rt], br, aR[rt], 0, 0, 0);
      aZ[rt] = __builtin_amdgcn_mfma_f32_16x16x32_f16(af[rt], bz, aZ[rt], 0, 0, 0);
      aNP[rt] = __builtin_amdgcn_mfma_f32_16x16x32_f16(af[rt], bn, aNP[rt], 0, 0, 0);
    }
  }
#pragma unroll
  for (int kc = 0; kc < 4; ++kc) {   // gh part: M @ whh.T
    half8 af[4];
#pragma unroll
    for (int rt = 0; rt < 4; ++rt)
      af[rt] = *(const half8*)(&Mlds[(rt * 16 + l16) * PSTR + kc * 32 + quad * 8]);
    half8 br = whh[(kc * 24 + u) * 64 + lane];
    half8 bz = whh[(kc * 24 + 8 + u) * 64 + lane];
    half8 bn = whh[(kc * 24 + 16 + u) * 64 + lane];
#pragma unroll
    for (int rt = 0; rt < 4; ++rt) {
      aR[rt] = __builtin_amdgcn_mfma_f32_16x16x32_f16(af[rt], br, aR[rt], 0, 0, 0);
      aZ[rt] = __builtin_amdgcn_mfma_f32_16x16x32_f16(af[rt], bz, aZ[rt], 0, 0, 0);
      aNM[rt] = __builtin_amdgcn_mfma_f32_16x16x32_f16(af[rt], bn, aNM[rt], 0, 0, 0);
    }
  }
  // ---- epilogue: compute into Plds (dead), then coalesced store-out
  __syncthreads();
  int col = u * 16 + l16;
  float br_ = bi[col] + bh[col];
  float bz_ = bi[128 + col] + bh[128 + col];
  float bin = bi[256 + col], bhn = bh[256 + col];
#pragma unroll
  for (int rt = 0; rt < 4; ++rt) {
#pragma unroll
    for (int q = 0; q < 4; ++q) {
      int lr = rt * 16 + quad * 4 + q;
      float r = sigmoid_(aR[rt][q] + br_);
      float z = sigmoid_(aZ[rt][q] + bz_);
      float nt = tanh_(aNP[rt][q] + bin + r * (aNM[rt][q] + bhn));
      float hold = (float)Mlds[lr * PSTR + col];
      Plds[lr * PSTR + col] = (_Float16)((1.f - z) * nt + z * hold);
    }
  }
  __syncthreads();
#pragma unroll
  for (int it = 0; it < 2; ++it) {
    int r = it * 32 + (tid >> 4);
    int c = (tid & 15) * 8;
    int row = rowbase + r;
    if (row < N_NODES)
      *(half8*)(Sp + (size_t)row * 128 + c) = *(const half8*)(&Plds[r * PSTR + c]);
  }
}

// ---------------------------------------------------------------- LayerNorm (vectorized): 16-lane
// group per row, half8 loads, xor-reduce within 16 lanes. h = relu(LN(h + S0+S1+S2)).
__global__ __launch_bounds__(256) void k_ln16(_Float16* __restrict__ h,
    const _Float16* __restrict__ S, const float* __restrict__ gamma,
    const float* __restrict__ beta) {
  int wave = threadIdx.x >> 6, lane = threadIdx.x & 63;
  int g = lane >> 4, l16 = lane & 15;
  int row = blockIdx.x * 16 + wave * 4 + g;
  if (row >= N_NODES) return;
  const size_t NC = (size_t)N_NODES * 128;
  size_t base = (size_t)row * 128 + l16 * 8;
  half8 hv = *(const half8*)(h + base);
  half8 s0 = *(const half8*)(S + base);
  half8 s1 = *(const half8*)(S + NC + base);
  half8 s2 = *(const half8*)(S + 2 * NC + base);
  float v[8];
  float s = 0.f, sq = 0.f;
#pragma unroll
  for (int i = 0; i < 8; ++i) {
    v[i] = (float)hv[i] + (float)s0[i] + (float)s1[i] + (float)s2[i];
    s += v[i]; sq += v[i] * v[i];
  }
#pragma unroll
  for (int off = 1; off < 16; off <<= 1) {
    s += __shfl_xor(s, off);
    sq += __shfl_xor(sq, off);
  }
  float mu = s * 0.0078125f;
  float var = sq * 0.0078125f - mu * mu;
  float rs = rsqrtf(var + 1e-5f);
  half8 ov;
#pragma unroll
  for (int i = 0; i < 8; ++i) {
    float o = (v[i] - mu) * rs * gamma[l16 * 8 + i] + beta[l16 * 8 + i];
    ov[i] = (_Float16)fmaxf(o, 0.f);
  }
  *(half8*)(h + base) = ov;
}

// ---------------------------------------------------------------- fused LN + head:
// out = relu(LN(h+S) @ w1.T + b1) @ w2.T + b2. LN'd rows staged in LDS, MFMA from LDS.
__global__ __launch_bounds__(256, 4) void k_head(const _Float16* __restrict__ h,
    const _Float16* __restrict__ S, const float* __restrict__ gamma,
    const float* __restrict__ beta, const _Float16* __restrict__ Wf,
    const float* __restrict__ bias, const float* __restrict__ w2,
    const float* __restrict__ b2, float* __restrict__ out) {
  __shared__ __attribute__((aligned(16))) _Float16 zA[64 * PSTR];  // LN'd input rows
  __shared__ __attribute__((aligned(16))) _Float16 zB[64 * PSTR];  // z = relu(gemm)
  __shared__ float w2s[256];
  int wave = threadIdx.x >> 6, lane = threadIdx.x & 63;
  int quad = lane >> 4, l16 = lane & 15;
  int rowbase = blockIdx.x * 64;
  const size_t NC = (size_t)N_NODES * 128;
  w2s[threadIdx.x] = w2[threadIdx.x];
  // ---- LN stage: 16 rows/pass (4 waves x 4 groups), 4 passes
#pragma unroll
  for (int pass = 0; pass < 4; ++pass) {
    int rl = pass * 16 + wave * 4 + quad;
    int row = rowbase + rl; if (row >= N_NODES) row = N_NODES - 1;
    size_t base = (size_t)row * 128 + l16 * 8;
    half8 hv = *(const half8*)(h + base);
    half8 s0 = *(const half8*)(S + base);
    half8 s1 = *(const half8*)(S + NC + base);
    half8 s2 = *(const half8*)(S + 2 * NC + base);
    float v[8];
    float s = 0.f, sq = 0.f;
#pragma unroll
    for (int i = 0; i < 8; ++i) {
      v[i] = (float)hv[i] + (float)s0[i] + (float)s1[i] + (float)s2[i];
      s += v[i]; sq += v[i] * v[i];
    }
#pragma unroll
    for (int off = 1; off < 16; off <<= 1) {
      s += __shfl_xor(s, off);
      sq += __shfl_xor(sq, off);
    }
    float mu = s * 0.0078125f;
    float var = sq * 0.0078125f - mu * mu;
    float rs = rsqrtf(var + 1e-5f);
    half8 ov;
#pragma unroll
    for (int i = 0; i < 8; ++i) {
      float o = (v[i] - mu) * rs * gamma[l16 * 8 + i] + beta[l16 * 8 + i];
      ov[i] = (_Float16)fmaxf(o, 0.f);
    }
    *(half8*)(&zA[rl * PSTR + l16 * 8]) = ov;
  }
  __syncthreads();
  // ---- GEMM: wave owns 32 cols
  const half8* wf = (const half8*)Wf;
  floatx4 zero = {0.f, 0.f, 0.f, 0.f};
  floatx4 acc[4][2];
#pragma unroll
  for (int rt = 0; rt < 4; ++rt) { acc[rt][0] = zero; acc[rt][1] = zero; }
#pragma unroll
  for (int kc = 0; kc < 4; ++kc) {
    half8 af[4];
#pragma unroll
    for (int rt = 0; rt < 4; ++rt)
      af[rt] = *(const half8*)(&zA[(rt * 16 + l16) * PSTR + kc * 32 + quad * 8]);
    half8 b0 = wf[(kc * 8 + 2 * wave) * 64 + lane];
    half8 b1 = wf[(kc * 8 + 2 * wave + 1) * 64 + lane];
#pragma unroll
    for (int rt = 0; rt < 4; ++rt) {
      acc[rt][0] = __builtin_amdgcn_mfma_f32_16x16x32_f16(af[rt], b0, acc[rt][0], 0, 0, 0);
      acc[rt][1] = __builtin_amdgcn_mfma_f32_16x16x32_f16(af[rt], b1, acc[rt][1], 0, 0, 0);
    }
  }
  int col = wave * 32 + l16;
#pragma unroll
  for (int rt = 0; rt < 4; ++rt) {
#pragma unroll
    for (int q = 0; q < 4; ++q) {
      int lr = rt * 16 + quad * 4 + q;
      zB[lr * PSTR + col] = (_Float16)fmaxf(acc[rt][0][q] + bias[col], 0.f);
      zB[lr * PSTR + col + 16] = (_Float16)fmaxf(acc[rt][1][q] + bias[col + 16], 0.f);
    }
  }
  __syncthreads();
  int tid = threadIdx.x;
  if (tid < 128) {
    int lr = tid >> 1, o = tid & 1;
    int row = rowbase + lr;
    if (row < N_NODES) {
      const float* wr = w2s + o * 128;
      float a = 0.f;
#pragma unroll
      for (int k = 0; k < 128; ++k) a += (float)zB[lr * PSTR + k] * wr[k];
      out[(size_t)row * 2 + o] = a + b2[o];
    }
  }
}

// ================================================================ launch
extern "C" void kernel_launch(void* const* d_in, const int* in_sizes, int n_in,
                              void* d_out, int out_size, void* d_ws, size_t ws_size,
                              hipStream_t stream) {
  const int*   x_type  = (const int*)d_in[0];
  const int*   x_tok   = (const int*)d_in[1];
  const float* x_small = (const float*)d_in[2];
  const int*   eidx    = (const int*)d_in[3];
  const int*   etype   = (const int*)d_in[4];
  const float* conv_w  = (const float*)d_in[5];
  const float* gwih    = (const float*)d_in[6];
  const float* gwhh    = (const float*)d_in[7];
  const float* gbih    = (const float*)d_in[8];
  const float* gbhh    = (const float*)d_in[9];
  const float* ln_g    = (const float*)d_in[10];
  const float* ln_b    = (const float*)d_in[11];
  const float* hw1     = (const float*)d_in[12];
  const float* hb1     = (const float*)d_in[13];
  const float* hw2     = (const float*)d_in[14];
  const float* hb2     = (const float*)d_in[15];
  float* out = (float*)d_out;

  const size_t NC = (size_t)N_NODES * 128;
  char* W = (char*)d_ws;
  size_t off = 0;
  _Float16* h16 = (_Float16*)(W + off);     off += NC * 2;            // 12.8 MB
  _Float16* S0  = (_Float16*)(W + off);     off += 3 * NC * 2;        // 38.4 MB
  _Float16* S1  = (_Float16*)(W + off);     off += 3 * NC * 2;        // 38.4 MB
  int* counts = (int*)(W + off);            off += (size_t)NT * 4;
  int* ptrv   = (int*)(W + off);            off += (size_t)(NT + 1) * 4;
  int* fill   = (int*)(W + off);            off += (size_t)NT * 4;
  int* bsum   = (int*)(W + off);            off += (NCHUNK2 + 1) * 4;
  int* csr    = (int*)(W + off);            off += (size_t)N_EDGES * 4;
  _Float16* WPC = (_Float16*)(W + off);     off += (size_t)18 * FS * 2;
  _Float16* WHH = (_Float16*)(W + off);     off += (size_t)6 * FS * 2;
  _Float16* W1F = (_Float16*)(W + off);     off += (size_t)16384 * 2;

  // ---- per-call prep (14 dispatches total incl. memset)
  hipMemsetAsync(counts, 0, (size_t)NT * 4, stream);
  k_feat_hist<<<(N_NODES * 128 + 255) / 256, 256, 0, stream>>>(
      h16, x_type, x_tok, x_small, eidx, etype, counts);
  k_scan_a<<<NCHUNK2, 256, 0, stream>>>(counts, bsum);
  k_scan_c<<<NCHUNK2, 256, 0, stream>>>(counts, bsum, ptrv, fill);
  k_place<<<(N_EDGES + 255) / 256, 256, 0, stream>>>(eidx, etype, fill, csr);
  k_prep<<<36 + PREP_MISC_BLOCKS, 512, 0, stream>>>(
      conv_w, gwih, gwhh, hw1, WPC, WHH, W1F);

  // ---- main loop: 2 blocks x 3 steps; fused gather+GRU; ping-pong S0/S1
  for (int b = 0; b < 2; ++b) {
    for (int s = 0; s < 3; ++s) {
      const _Float16* Msrc = (s == 0) ? h16 : ((s == 1) ? S0 : S1);
      size_t mstr = (s == 0) ? 0 : NC;
      _Float16* Sout = (s == 1) ? S1 : S0;
      k_step<<<3 * NB, 512, 0, stream>>>(Msrc, mstr, Sout, ptrv, csr,
          WPC + (size_t)(b * 9 + s) * FS, WHH + (size_t)b * 3 * FS,
          gbih + (size_t)b * 3 * 384, gbhh + (size_t)b * 3 * 384);
    }
    if (b == 0)
      k_ln16<<<(N_NODES + 15) / 16, 256, 0, stream>>>(h16, S0, ln_g, ln_b);
  }
  // ---- fused LN(b=1) + head
  k_head<<<NB, 256, 0, stream>>>(h16, S0, ln_g + 128, ln_b + 128,
                                 W1F, hb1, hw2, hb2, out);
}